// Round 6
// baseline (1532.161 us; speedup 1.0000x reference)
//
#include <hip/hip_runtime.h>

#define N_NODES 100000
#define N_EDGES 1600000
#define N_GRAPHS 128
#define NHID 128
#define NLAYER 4
#define BN_EPS 1e-5f

#define SCAN_ITEMS 1024
#define SCAN_NB ((N_NODES + SCAN_ITEMS - 1) / SCAN_ITEMS)   // 98

__device__ __forceinline__ float4 ld4(const float* p){ return *(const float4*)p; }
__device__ __forceinline__ void st4(float* p, float4 v){ *(float4*)p = v; }

// ---------------- CSR build ----------------

__global__ void k_hist(const int* __restrict__ dst, int* __restrict__ counts){
    int e = blockIdx.x * 256 + threadIdx.x;
    if (e < N_EDGES) atomicAdd(&counts[dst[e]], 1);
}

__global__ void k_scan_partial(const int* __restrict__ counts, int* __restrict__ partial){
    __shared__ int s[256];
    int t = threadIdx.x;
    int base = blockIdx.x * SCAN_ITEMS + t * 4;
    int v = 0;
    #pragma unroll
    for (int k = 0; k < 4; k++) if (base + k < N_NODES) v += counts[base + k];
    s[t] = v;
    __syncthreads();
    for (int o = 128; o > 0; o >>= 1){
        if (t < o) s[t] += s[t + o];
        __syncthreads();
    }
    if (t == 0) partial[blockIdx.x] = s[0];
}

__global__ void k_scan_top(int* __restrict__ partial, int nb, int* __restrict__ row_ptr){
    __shared__ int s[128];
    int t = threadIdx.x;
    int v = (t < nb) ? partial[t] : 0;
    s[t] = v;
    __syncthreads();
    for (int d = 1; d < 128; d <<= 1){
        int add = (t >= d) ? s[t - d] : 0;
        __syncthreads();
        s[t] += add;
        __syncthreads();
    }
    if (t < nb) partial[t] = s[t] - v;           // exclusive
    if (t == 0) row_ptr[N_NODES] = N_EDGES;
}

__global__ void k_scan_final(const int* __restrict__ counts, const int* __restrict__ partial,
                             int* __restrict__ row_ptr){
    __shared__ int s[256];
    int t = threadIdx.x;
    int base = blockIdx.x * SCAN_ITEMS + t * 4;
    int v[4]; int tsum = 0;
    #pragma unroll
    for (int k = 0; k < 4; k++){ v[k] = (base + k < N_NODES) ? counts[base + k] : 0; tsum += v[k]; }
    s[t] = tsum;
    __syncthreads();
    for (int d = 1; d < 256; d <<= 1){
        int add = (t >= d) ? s[t - d] : 0;
        __syncthreads();
        s[t] += add;
        __syncthreads();
    }
    int off = partial[blockIdx.x] + s[t] - tsum;  // exclusive prefix for this thread
    #pragma unroll
    for (int k = 0; k < 4; k++){
        if (base + k < N_NODES) row_ptr[base + k] = off;
        off += v[k];
    }
}

// fill CSR payload: ONE packed word per edge -> src(17b) | attr(5b)<<17 | x_idx(7b)<<22
__global__ void k_fill(const int* __restrict__ eidx, const int* __restrict__ eattr,
                       const int* __restrict__ x_idx,
                       int* __restrict__ cursor, unsigned* __restrict__ pack){
    int e = blockIdx.x * 256 + threadIdx.x;
    if (e >= N_EDGES) return;
    int d = eidx[N_EDGES + e];
    int s = eidx[e];
    int a = eattr[e];
    int xi = x_idx[s];                               // <100, L2-resident table
    int pos = atomicAdd(&cursor[d], 1);
    pack[pos] = (unsigned)s | ((unsigned)a << 17) | ((unsigned)xi << 22);
}

// ---------------- layer-0 message memo table: combo[i*20+a][c] = relu(ne[i][c]+ee0[a][c]) ----

__global__ void k_combo(const float* __restrict__ node_emb, const float* __restrict__ edge_emb0,
                        float* __restrict__ combo){
    int i = blockIdx.x * 256 + threadIdx.x;          // over 2000*128
    if (i >= 2000 * NHID) return;
    int row = i >> 7, c = i & 127;
    int ni = row / 20, a = row - ni * 20;
    combo[i] = fmaxf(node_emb[ni * NHID + c] + edge_emb0[a * NHID + c], 0.f);
}

// ---------------- node embedding init ----------------

__global__ void k_initx(const int* __restrict__ x_idx, const float* __restrict__ node_emb,
                        float4* __restrict__ x4){
    int i = blockIdx.x * 256 + threadIdx.x;          // over N*32 float4s
    if (i >= N_NODES * 32) return;
    int n = i >> 5, c = i & 31;
    int id = x_idx[n];
    x4[i] = ((const float4*)node_emb)[id * 32 + c];
}

// ---------------- aggregation (layers 1-3): h0[n] = x[n] + sum relu(x[src]+emb[attr]) ------

__global__ __launch_bounds__(256) void k_agg(const float* __restrict__ x,
                      const int* __restrict__ row_ptr,
                      const unsigned* __restrict__ pack, const float* __restrict__ emb_l,
                      float2* __restrict__ h0){
    int gid = blockIdx.x * 256 + threadIdx.x;        // grid exactly N_NODES*64/256
    int node = gid >> 6;
    int lane = threadIdx.x & 63;                     // 2 channels per lane
    const float2* x2 = (const float2*)x;
    const float2* e2 = (const float2*)emb_l;
    float2 acc = x2[node * 64 + lane];
    int beg = row_ptr[node], end = row_ptr[node + 1];
    int i = beg;
    for (; i + 3 < end; i += 4){
        unsigned p0 = pack[i], p1 = pack[i+1], p2 = pack[i+2], p3 = pack[i+3];
        float2 a0 = x2[(p0 & 0x1FFFFu) * 64 + lane];
        float2 a1 = x2[(p1 & 0x1FFFFu) * 64 + lane];
        float2 a2 = x2[(p2 & 0x1FFFFu) * 64 + lane];
        float2 a3 = x2[(p3 & 0x1FFFFu) * 64 + lane];
        float2 b0 = e2[((p0 >> 17) & 31u) * 64 + lane];
        float2 b1 = e2[((p1 >> 17) & 31u) * 64 + lane];
        float2 b2 = e2[((p2 >> 17) & 31u) * 64 + lane];
        float2 b3 = e2[((p3 >> 17) & 31u) * 64 + lane];
        acc.x += (fmaxf(a0.x + b0.x, 0.f) + fmaxf(a1.x + b1.x, 0.f))
               + (fmaxf(a2.x + b2.x, 0.f) + fmaxf(a3.x + b3.x, 0.f));
        acc.y += (fmaxf(a0.y + b0.y, 0.f) + fmaxf(a1.y + b1.y, 0.f))
               + (fmaxf(a2.y + b2.y, 0.f) + fmaxf(a3.y + b3.y, 0.f));
    }
    for (; i < end; i++){
        unsigned p = pack[i];
        float2 xv = x2[(p & 0x1FFFFu) * 64 + lane];
        float2 ev = e2[((p >> 17) & 31u) * 64 + lane];
        acc.x += fmaxf(xv.x + ev.x, 0.f);
        acc.y += fmaxf(xv.y + ev.y, 0.f);
    }
    h0[node * 64 + lane] = acc;
}

// ---------------- aggregation (layer 0): messages from 1 MB memo table (L2-resident) -------

__global__ __launch_bounds__(256) void k_agg0(const float* __restrict__ x,
                      const int* __restrict__ row_ptr,
                      const unsigned* __restrict__ pack,
                      const float* __restrict__ combo,
                      float2* __restrict__ h0){
    int gid = blockIdx.x * 256 + threadIdx.x;
    int node = gid >> 6;
    int lane = threadIdx.x & 63;
    const float2* x2 = (const float2*)x;
    const float2* c2 = (const float2*)combo;
    float2 acc = x2[node * 64 + lane];
    int beg = row_ptr[node], end = row_ptr[node + 1];
    int i = beg;
    for (; i + 3 < end; i += 4){
        unsigned p0 = pack[i], p1 = pack[i+1], p2 = pack[i+2], p3 = pack[i+3];
        int ci0 = (int)((p0 >> 22) & 127u) * 20 + (int)((p0 >> 17) & 31u);
        int ci1 = (int)((p1 >> 22) & 127u) * 20 + (int)((p1 >> 17) & 31u);
        int ci2 = (int)((p2 >> 22) & 127u) * 20 + (int)((p2 >> 17) & 31u);
        int ci3 = (int)((p3 >> 22) & 127u) * 20 + (int)((p3 >> 17) & 31u);
        float2 m0 = c2[ci0 * 64 + lane];
        float2 m1 = c2[ci1 * 64 + lane];
        float2 m2 = c2[ci2 * 64 + lane];
        float2 m3 = c2[ci3 * 64 + lane];
        acc.x += (m0.x + m1.x) + (m2.x + m3.x);
        acc.y += (m0.y + m1.y) + (m2.y + m3.y);
    }
    for (; i < end; i++){
        unsigned p = pack[i];
        int ci = (int)((p >> 22) & 127u) * 20 + (int)((p >> 17) & 31u);
        float2 m = c2[ci * 64 + lane];
        acc.x += m.x;
        acc.y += m.y;
    }
    h0[node * 64 + lane] = acc;
}

// ---- GEMM building block: C_tile(128x128) = A(128xK=128) @ W(128x128), LDS = 34 KB ----
// __launch_bounds__(256,4): cap VGPR at 128 -> 4 blocks/CU (LDS 4x34=136 <= 160 KB).
// In-place over A is safe: each block reads only its own 128-row panel.

template<int RELU_OUT, int DO_STATS>
__global__ __launch_bounds__(256, 4) void k_gemm(const float* __restrict__ A,
                                                 const float* __restrict__ W,
                                                 float* __restrict__ out,
                                                 float* __restrict__ stats_l){
    __shared__ float As[128][36];    // 18 KB
    __shared__ float Bs[32][128];    // 16 KB (reused as stats scratch)
    const int tid = threadIdx.x;
    const int rt = tid & 15;
    const int ct = tid >> 4;
    const int row0 = blockIdx.x * 128;

    float acc[8][8];
    #pragma unroll
    for (int i = 0; i < 8; i++)
        #pragma unroll
        for (int j = 0; j < 8; j++) acc[i][j] = 0.f;

    for (int kc = 0; kc < 4; kc++){
        __syncthreads();
        #pragma unroll
        for (int q = 0; q < 4; q++){
            int f = tid + 256 * q;                  // 0..1023 float4s of A chunk
            int r = f >> 3, kq = f & 7;
            int gr = row0 + r;
            float4 v = make_float4(0.f, 0.f, 0.f, 0.f);
            if (gr < N_NODES) v = ld4(A + gr * NHID + kc * 32 + kq * 4);
            st4(&As[r][kq * 4], v);
        }
        #pragma unroll
        for (int q = 0; q < 4; q++){
            int f = tid + 256 * q;                  // 0..1023 float4s of W chunk
            int r = f >> 5, c4 = f & 31;
            st4(&Bs[r][c4 * 4], ld4(W + (kc * 32 + r) * NHID + c4 * 4));
        }
        __syncthreads();
        #pragma unroll
        for (int g = 0; g < 8; g++){                // groups of 4 k
            float av[8][4];
            #pragma unroll
            for (int i = 0; i < 8; i++){
                float4 t = ld4(&As[rt + 16 * i][g * 4]);
                av[i][0] = t.x; av[i][1] = t.y; av[i][2] = t.z; av[i][3] = t.w;
            }
            #pragma unroll
            for (int q = 0; q < 4; q++){
                float4 b0 = ld4(&Bs[g * 4 + q][ct * 8]);
                float4 b1 = ld4(&Bs[g * 4 + q][ct * 8 + 4]);
                float bv[8] = {b0.x, b0.y, b0.z, b0.w, b1.x, b1.y, b1.z, b1.w};
                #pragma unroll
                for (int i = 0; i < 8; i++)
                    #pragma unroll
                    for (int j = 0; j < 8; j++)
                        acc[i][j] = fmaf(av[i][q], bv[j], acc[i][j]);
            }
        }
    }

    if (RELU_OUT){
        #pragma unroll
        for (int i = 0; i < 8; i++)
            #pragma unroll
            for (int j = 0; j < 8; j++) acc[i][j] = fmaxf(acc[i][j], 0.f);
    }
    #pragma unroll
    for (int i = 0; i < 8; i++){
        int gr = row0 + rt + 16 * i;
        if (gr < N_NODES){
            st4(out + gr * NHID + ct * 8,
                make_float4(acc[i][0], acc[i][1], acc[i][2], acc[i][3]));
            st4(out + gr * NHID + ct * 8 + 4,
                make_float4(acc[i][4], acc[i][5], acc[i][6], acc[i][7]));
        }
    }

    if (DO_STATS){
        // padded rows contribute exactly 0 to both sums (acc stays 0) -> no masking
        __syncthreads();                 // all Bs reads complete
        float* red = &Bs[0][0];          // [16][128] sums
        float* red2 = &As[0][0];         // [16][128] sumsq
        #pragma unroll
        for (int j = 0; j < 8; j++){
            float s = 0.f, q = 0.f;
            #pragma unroll
            for (int i = 0; i < 8; i++){ float v = acc[i][j]; s += v; q += v * v; }
            red[rt * 128 + ct * 8 + j] = s;
            red2[rt * 128 + ct * 8 + j] = q;
        }
        __syncthreads();
        if (tid < 128){
            float s = 0.f, q = 0.f;
            #pragma unroll
            for (int r2 = 0; r2 < 16; r2++){
                s += red[r2 * 128 + tid];
                q += red2[r2 * 128 + tid];
            }
            atomicAdd(&stats_l[tid], s);
            atomicAdd(&stats_l[128 + tid], q);
        }
    }
}

// -------- normalize + relu + residual, BN coefs recomputed per-thread from stats --------
// (identical arithmetic/order as the old k_coef -> bit-identical results; kills 4 dispatches)

__global__ void k_norm(const float4* __restrict__ h2, float4* __restrict__ x,
                       const float* __restrict__ stats_l,
                       const float* __restrict__ gamma, const float* __restrict__ beta){
    int i = blockIdx.x * 256 + threadIdx.x;
    if (i >= N_NODES * 32) return;
    int g = (i & 31);                                // float4 group 0..31
    float4 sv = ((const float4*)stats_l)[g];
    float4 qv = ((const float4*)(stats_l + 128))[g];
    float4 gm = ((const float4*)gamma)[g];
    float4 bt = ((const float4*)beta)[g];
    float4 ca, cb;
    {
        float mu, var;
        mu = sv.x * (1.f / N_NODES); var = qv.x * (1.f / N_NODES) - mu * mu;
        ca.x = gm.x * rsqrtf(var + BN_EPS); cb.x = bt.x - mu * ca.x;
        mu = sv.y * (1.f / N_NODES); var = qv.y * (1.f / N_NODES) - mu * mu;
        ca.y = gm.y * rsqrtf(var + BN_EPS); cb.y = bt.y - mu * ca.y;
        mu = sv.z * (1.f / N_NODES); var = qv.z * (1.f / N_NODES) - mu * mu;
        ca.z = gm.z * rsqrtf(var + BN_EPS); cb.z = bt.z - mu * ca.z;
        mu = sv.w * (1.f / N_NODES); var = qv.w * (1.f / N_NODES) - mu * mu;
        ca.w = gm.w * rsqrtf(var + BN_EPS); cb.w = bt.w - mu * ca.w;
    }
    float4 h = h2[i];
    float4 xv = x[i];
    float4 r;
    r.x = fmaxf(fmaf(h.x, ca.x, cb.x), 0.f) + xv.x;
    r.y = fmaxf(fmaf(h.y, ca.y, cb.y), 0.f) + xv.y;
    r.z = fmaxf(fmaf(h.z, ca.z, cb.z), 0.f) + xv.z;
    r.w = fmaxf(fmaf(h.w, ca.w, cb.w), 0.f) + xv.w;
    x[i] = r;
}

// ---------------- pooling: one block per graph (batch is sorted) ----------------

__global__ void k_pool(const float* __restrict__ x, const int* __restrict__ batch,
                       float* __restrict__ gbuf){
    int g = blockIdx.x;
    int lo = 0, hi = N_NODES;
    while (lo < hi){ int mid = (lo + hi) >> 1; if (batch[mid] < g) lo = mid + 1; else hi = mid; }
    int start = lo;
    hi = N_NODES;
    while (lo < hi){ int mid = (lo + hi) >> 1; if (batch[mid] < g + 1) lo = mid + 1; else hi = mid; }
    int end = lo;
    int c = threadIdx.x & 127;
    int half = threadIdx.x >> 7;
    float acc = 0.f;
    for (int n = start + half; n < end; n += 2) acc += x[n * NHID + c];
    __shared__ float s[256];
    s[threadIdx.x] = acc;
    __syncthreads();
    if (threadIdx.x < 128) gbuf[g * NHID + threadIdx.x] = s[threadIdx.x] + s[threadIdx.x + 128];
}

// ---------------- output head ----------------

__global__ __launch_bounds__(128) void k_head1(const float* __restrict__ gbuf,
                                               const float* __restrict__ w1,
                                               const float* __restrict__ b1,
                                               float* __restrict__ o1){
    __shared__ float gs[128];
    int i = blockIdx.x;                  // graph row
    int j = threadIdx.x;                 // output column
    gs[j] = gbuf[i * NHID + j];
    __syncthreads();
    float acc = 0.f;
    #pragma unroll 8
    for (int k = 0; k < 128; k++)
        acc = fmaf(gs[k], w1[k * NHID + j], acc);   // coalesced across j
    o1[i * NHID + j] = acc + b1[j];
}

__global__ __launch_bounds__(128) void k_head2(const float* __restrict__ o1,
                                               const float* __restrict__ gamma,
                                               const float* __restrict__ beta,
                                               const float* __restrict__ w2,
                                               const float* __restrict__ b2,
                                               float* __restrict__ out){
    __shared__ float s_o1[128][129];     // padded
    __shared__ float sa[128], sb[128];
    int t = threadIdx.x;
    float s = 0.f, q = 0.f;
    for (int r = 0; r < 128; r++){
        float v = o1[r * NHID + t];      // coalesced
        s_o1[r][t] = v;
        s += v; q += v * v;
    }
    float mu = s * (1.f / 128.f);
    float rs = rsqrtf(q * (1.f / 128.f) - mu * mu + BN_EPS);
    float a = gamma[t] * rs;
    sa[t] = a;
    sb[t] = beta[t] - mu * a;
    __syncthreads();
    float a2 = 0.f;
    #pragma unroll 8
    for (int j = 0; j < 128; j++){
        float v = fmaf(s_o1[t][j], sa[j], sb[j]);
        a2 += fmaxf(v, 0.f) * w2[j];
    }
    out[t] = a2 + b2[0];
}

// ---------------- launch ----------------

extern "C" void kernel_launch(void* const* d_in, const int* in_sizes, int n_in,
                              void* d_out, int out_size, void* d_ws, size_t ws_size,
                              hipStream_t stream){
    const int*   x_idx    = (const int*)d_in[0];
    const int*   eidx     = (const int*)d_in[1];
    const int*   eattr    = (const int*)d_in[2];
    const int*   batch    = (const int*)d_in[3];
    const float* node_emb = (const float*)d_in[4];
    const float* edge_emb = (const float*)d_in[5];
    const float* conv_w1  = (const float*)d_in[6];
    const float* conv_w2  = (const float*)d_in[7];
    const float* bn_gamma = (const float*)d_in[8];
    const float* bn_beta  = (const float*)d_in[9];
    const float* out_w1   = (const float*)d_in[10];
    const float* out_b1   = (const float*)d_in[11];
    const float* out_bng  = (const float*)d_in[12];
    const float* out_bnb  = (const float*)d_in[13];
    const float* out_w2   = (const float*)d_in[14];
    const float* out_b2   = (const float*)d_in[15];
    float* out = (float*)d_out;

    char* base = (char*)d_ws;
    size_t off = 0;
    auto alloc = [&](size_t bytes) -> char* {
        char* r = base + off;
        off = (off + bytes + 255) & ~(size_t)255;
        return r;
    };
    float*    xbuf    = (float*)alloc((size_t)N_NODES * NHID * 4);   // 51.2 MB
    float*    h0buf   = (float*)alloc((size_t)N_NODES * NHID * 4);   // 51.2 MB
    int*      row_ptr = (int*)alloc((size_t)(N_NODES + 1) * 4);
    int*      cursor  = (int*)alloc((size_t)N_NODES * 4);
    int*      counts  = (int*)alloc((size_t)N_NODES * 4);
    int*      partial = (int*)alloc(512 * 4);
    unsigned* pack    = (unsigned*)alloc((size_t)N_EDGES * 4);       // 6.4 MB
    float*    combo   = (float*)alloc((size_t)2000 * NHID * 4);      // 1.0 MB
    float*    stats   = (float*)alloc(NLAYER * 256 * 4);
    float*    gbuf    = (float*)alloc((size_t)N_GRAPHS * NHID * 4);
    float*    o1buf   = (float*)alloc((size_t)N_GRAPHS * NHID * 4);
    (void)ws_size; (void)in_sizes; (void)n_in; (void)out_size;

    hipMemsetAsync(counts, 0, (size_t)N_NODES * 4, stream);
    hipMemsetAsync(stats, 0, NLAYER * 256 * 4, stream);

    // CSR build (edges grouped by dst), once per call, reused across 4 layers
    k_hist<<<N_EDGES / 256, 256, 0, stream>>>(eidx + N_EDGES, counts);
    k_scan_partial<<<SCAN_NB, 256, 0, stream>>>(counts, partial);
    k_scan_top<<<1, 128, 0, stream>>>(partial, SCAN_NB, row_ptr);
    k_scan_final<<<SCAN_NB, 256, 0, stream>>>(counts, partial, row_ptr);
    hipMemcpyAsync(cursor, row_ptr, (size_t)N_NODES * 4, hipMemcpyDeviceToDevice, stream);
    k_fill<<<N_EDGES / 256, 256, 0, stream>>>(eidx, eattr, x_idx, cursor, pack);

    // layer-0 message memo table (exact same arithmetic, memoized)
    k_combo<<<(2000 * NHID) / 256, 256, 0, stream>>>(node_emb, edge_emb, combo);

    k_initx<<<(N_NODES * 32) / 256, 256, 0, stream>>>(x_idx, node_emb, (float4*)xbuf);

    const int gemm_grid = (N_NODES + 127) / 128;     // 782
    for (int l = 0; l < NLAYER; l++){
        if (l == 0){
            k_agg0<<<(N_NODES * 64) / 256, 256, 0, stream>>>(
                xbuf, row_ptr, pack, combo, (float2*)h0buf);
        } else {
            k_agg<<<(N_NODES * 64) / 256, 256, 0, stream>>>(
                xbuf, row_ptr, pack, edge_emb + (size_t)l * 20 * NHID, (float2*)h0buf);
        }
        // t = relu(h0 @ w1)   (in place)
        k_gemm<1, 0><<<gemm_grid, 256, 0, stream>>>(
            h0buf, conv_w1 + (size_t)l * NHID * NHID, h0buf, nullptr);
        // h2 = t @ w2 (+ BN stats)   (in place)
        k_gemm<0, 1><<<gemm_grid, 256, 0, stream>>>(
            h0buf, conv_w2 + (size_t)l * NHID * NHID, h0buf, stats + l * 256);
        k_norm<<<(N_NODES * 32) / 256, 256, 0, stream>>>(
            (const float4*)h0buf, (float4*)xbuf, stats + l * 256,
            bn_gamma + l * NHID, bn_beta + l * NHID);
    }

    k_pool<<<N_GRAPHS, 256, 0, stream>>>(xbuf, batch, gbuf);
    k_head1<<<N_GRAPHS, 128, 0, stream>>>(gbuf, out_w1, out_b1, o1buf);
    k_head2<<<1, 128, 0, stream>>>(o1buf, out_bng, out_bnb, out_w2, out_b2, out);
}

// Round 7
// 1231.479 us; speedup vs baseline: 1.2442x; 1.2442x over previous
//
#include <hip/hip_runtime.h>

#define N_NODES 100000
#define N_EDGES 1600000
#define N_GRAPHS 128
#define NHID 128
#define NLAYER 4
#define BN_EPS 1e-5f

#define SCAN_ITEMS 1024
#define SCAN_NB ((N_NODES + SCAN_ITEMS - 1) / SCAN_ITEMS)   // 98

__device__ __forceinline__ float4 ld4(const float* p){ return *(const float4*)p; }
__device__ __forceinline__ void st4(float* p, float4 v){ *(float4*)p = v; }

typedef __attribute__((ext_vector_type(8))) short short8v;   // 8 bf16 = 4 VGPR
typedef __attribute__((ext_vector_type(4))) float f32x4;     // MFMA acc

// split fp32 -> bf16 hi (truncate) + bf16 lo (truncate of residual)
__device__ __forceinline__ void bsplit(float a, unsigned short& h, unsigned short& l){
    unsigned ab = __float_as_uint(a);
    h = (unsigned short)(ab >> 16);
    float hf = __uint_as_float((unsigned)h << 16);
    l = (unsigned short)(__float_as_uint(a - hf) >> 16);
}

// ---------------- CSR build ----------------

__global__ void k_hist(const int* __restrict__ dst, int* __restrict__ counts){
    int e = blockIdx.x * 256 + threadIdx.x;
    if (e < N_EDGES) atomicAdd(&counts[dst[e]], 1);
}

__global__ void k_scan_partial(const int* __restrict__ counts, int* __restrict__ partial){
    __shared__ int s[256];
    int t = threadIdx.x;
    int base = blockIdx.x * SCAN_ITEMS + t * 4;
    int v = 0;
    #pragma unroll
    for (int k = 0; k < 4; k++) if (base + k < N_NODES) v += counts[base + k];
    s[t] = v;
    __syncthreads();
    for (int o = 128; o > 0; o >>= 1){
        if (t < o) s[t] += s[t + o];
        __syncthreads();
    }
    if (t == 0) partial[blockIdx.x] = s[0];
}

__global__ void k_scan_top(int* __restrict__ partial, int nb, int* __restrict__ row_ptr){
    __shared__ int s[128];
    int t = threadIdx.x;
    int v = (t < nb) ? partial[t] : 0;
    s[t] = v;
    __syncthreads();
    for (int d = 1; d < 128; d <<= 1){
        int add = (t >= d) ? s[t - d] : 0;
        __syncthreads();
        s[t] += add;
        __syncthreads();
    }
    if (t < nb) partial[t] = s[t] - v;           // exclusive
    if (t == 0) row_ptr[N_NODES] = N_EDGES;
}

__global__ void k_scan_final(const int* __restrict__ counts, const int* __restrict__ partial,
                             int* __restrict__ row_ptr){
    __shared__ int s[256];
    int t = threadIdx.x;
    int base = blockIdx.x * SCAN_ITEMS + t * 4;
    int v[4]; int tsum = 0;
    #pragma unroll
    for (int k = 0; k < 4; k++){ v[k] = (base + k < N_NODES) ? counts[base + k] : 0; tsum += v[k]; }
    s[t] = tsum;
    __syncthreads();
    for (int d = 1; d < 256; d <<= 1){
        int add = (t >= d) ? s[t - d] : 0;
        __syncthreads();
        s[t] += add;
        __syncthreads();
    }
    int off = partial[blockIdx.x] + s[t] - tsum;  // exclusive prefix for this thread
    #pragma unroll
    for (int k = 0; k < 4; k++){
        if (base + k < N_NODES) row_ptr[base + k] = off;
        off += v[k];
    }
}

// fill CSR payload: ONE packed word per edge -> src(17b) | attr(5b)<<17 | x_idx(7b)<<22
__global__ void k_fill(const int* __restrict__ eidx, const int* __restrict__ eattr,
                       const int* __restrict__ x_idx,
                       int* __restrict__ cursor, unsigned* __restrict__ pack){
    int e = blockIdx.x * 256 + threadIdx.x;
    if (e >= N_EDGES) return;
    int d = eidx[N_EDGES + e];
    int s = eidx[e];
    int a = eattr[e];
    int xi = x_idx[s];
    int pos = atomicAdd(&cursor[d], 1);
    pack[pos] = (unsigned)s | ((unsigned)a << 17) | ((unsigned)xi << 22);
}

// ---------------- layer-0 message memo table ----------------

__global__ void k_combo(const float* __restrict__ node_emb, const float* __restrict__ edge_emb0,
                        float* __restrict__ combo){
    int i = blockIdx.x * 256 + threadIdx.x;          // over 2000*128
    if (i >= 2000 * NHID) return;
    int row = i >> 7, c = i & 127;
    int ni = row / 20, a = row - ni * 20;
    combo[i] = fmaxf(node_emb[ni * NHID + c] + edge_emb0[a * NHID + c], 0.f);
}

// ---------------- W^T split tables: [which][layer][col][k] bf16 hi/lo ----------------

__global__ void k_wsplit(const float* __restrict__ w1, const float* __restrict__ w2,
                         unsigned short* __restrict__ wth, unsigned short* __restrict__ wtl){
    int i = blockIdx.x * 256 + threadIdx.x;          // 2*4*128*128 = 131072
    int which = i >> 16;
    int m = (i >> 14) & 3;
    int r = i & 16383;
    int k = r >> 7, c = r & 127;
    float v = (which ? w2 : w1)[m * 16384 + k * 128 + c];
    unsigned short h, l;
    bsplit(v, h, l);
    int o = ((which * 4 + m) * 128 + c) * 128 + k;   // transposed: [col][k]
    wth[o] = h; wtl[o] = l;
}

// ---------------- node embedding init ----------------

__global__ void k_initx(const int* __restrict__ x_idx, const float* __restrict__ node_emb,
                        float4* __restrict__ x4){
    int i = blockIdx.x * 256 + threadIdx.x;          // over N*32 float4s
    if (i >= N_NODES * 32) return;
    int n = i >> 5, c = i & 31;
    int id = x_idx[n];
    x4[i] = ((const float4*)node_emb)[id * 32 + c];
}

// ---------------- aggregation (layers 1-3) ----------------

__global__ __launch_bounds__(256) void k_agg(const float* __restrict__ x,
                      const int* __restrict__ row_ptr,
                      const unsigned* __restrict__ pack, const float* __restrict__ emb_l,
                      float2* __restrict__ h0){
    int gid = blockIdx.x * 256 + threadIdx.x;
    int node = gid >> 6;
    int lane = threadIdx.x & 63;
    const float2* x2 = (const float2*)x;
    const float2* e2 = (const float2*)emb_l;
    float2 acc = x2[node * 64 + lane];
    int beg = row_ptr[node], end = row_ptr[node + 1];
    int i = beg;
    for (; i + 3 < end; i += 4){
        unsigned p0 = pack[i], p1 = pack[i+1], p2 = pack[i+2], p3 = pack[i+3];
        float2 a0 = x2[(p0 & 0x1FFFFu) * 64 + lane];
        float2 a1 = x2[(p1 & 0x1FFFFu) * 64 + lane];
        float2 a2 = x2[(p2 & 0x1FFFFu) * 64 + lane];
        float2 a3 = x2[(p3 & 0x1FFFFu) * 64 + lane];
        float2 b0 = e2[((p0 >> 17) & 31u) * 64 + lane];
        float2 b1 = e2[((p1 >> 17) & 31u) * 64 + lane];
        float2 b2 = e2[((p2 >> 17) & 31u) * 64 + lane];
        float2 b3 = e2[((p3 >> 17) & 31u) * 64 + lane];
        acc.x += (fmaxf(a0.x + b0.x, 0.f) + fmaxf(a1.x + b1.x, 0.f))
               + (fmaxf(a2.x + b2.x, 0.f) + fmaxf(a3.x + b3.x, 0.f));
        acc.y += (fmaxf(a0.y + b0.y, 0.f) + fmaxf(a1.y + b1.y, 0.f))
               + (fmaxf(a2.y + b2.y, 0.f) + fmaxf(a3.y + b3.y, 0.f));
    }
    for (; i < end; i++){
        unsigned p = pack[i];
        float2 xv = x2[(p & 0x1FFFFu) * 64 + lane];
        float2 ev = e2[((p >> 17) & 31u) * 64 + lane];
        acc.x += fmaxf(xv.x + ev.x, 0.f);
        acc.y += fmaxf(xv.y + ev.y, 0.f);
    }
    h0[node * 64 + lane] = acc;
}

// ---------------- aggregation (layer 0): memo table ----------------

__global__ __launch_bounds__(256) void k_agg0(const float* __restrict__ x,
                      const int* __restrict__ row_ptr,
                      const unsigned* __restrict__ pack,
                      const float* __restrict__ combo,
                      float2* __restrict__ h0){
    int gid = blockIdx.x * 256 + threadIdx.x;
    int node = gid >> 6;
    int lane = threadIdx.x & 63;
    const float2* x2 = (const float2*)x;
    const float2* c2 = (const float2*)combo;
    float2 acc = x2[node * 64 + lane];
    int beg = row_ptr[node], end = row_ptr[node + 1];
    int i = beg;
    for (; i + 3 < end; i += 4){
        unsigned p0 = pack[i], p1 = pack[i+1], p2 = pack[i+2], p3 = pack[i+3];
        int ci0 = (int)((p0 >> 22) & 127u) * 20 + (int)((p0 >> 17) & 31u);
        int ci1 = (int)((p1 >> 22) & 127u) * 20 + (int)((p1 >> 17) & 31u);
        int ci2 = (int)((p2 >> 22) & 127u) * 20 + (int)((p2 >> 17) & 31u);
        int ci3 = (int)((p3 >> 22) & 127u) * 20 + (int)((p3 >> 17) & 31u);
        float2 m0 = c2[ci0 * 64 + lane];
        float2 m1 = c2[ci1 * 64 + lane];
        float2 m2 = c2[ci2 * 64 + lane];
        float2 m3 = c2[ci3 * 64 + lane];
        acc.x += (m0.x + m1.x) + (m2.x + m3.x);
        acc.y += (m0.y + m1.y) + (m2.y + m3.y);
    }
    for (; i < end; i++){
        unsigned p = pack[i];
        int ci = (int)((p >> 22) & 127u) * 20 + (int)((p >> 17) & 31u);
        float2 m = c2[ci * 64 + lane];
        acc.x += m.x;
        acc.y += m.y;
    }
    h0[node * 64 + lane] = acc;
}

// ---- split-bf16 MFMA GEMM: C(128x128) = A(128x128) @ W, via Ah@Wh + Ah@Wl + Al@Wh ----
// A fp32 row-major, staged per 32-k chunk as bf16 hi/lo; W^T precomputed bf16 hi/lo [col][k].
// Error vs fp32: dropped Al@Wl ~ 2^-18 relative. In-place over A safe (own panel only).
// LDS 40 KB -> 4 blocks/CU. Fragment layout per HW-verified m89/m92 mapping.

template<int RELU_OUT, int DO_STATS>
__global__ __launch_bounds__(256) void k_mfma(const float* __restrict__ A,
                                              const unsigned short* __restrict__ Wth,
                                              const unsigned short* __restrict__ Wtl,
                                              float* __restrict__ out,
                                              float* __restrict__ stats_l){
    __shared__ unsigned short Ah[128][40], Al[128][40];   // 80 B pitch: 2-way banks only
    __shared__ unsigned short Bh[128][40], Bl[128][40];   // W^T chunk [col][k]
    const int tid = threadIdx.x;
    const int w = tid >> 6;          // wave 0..3 -> rows [w*32, w*32+32)
    const int l = tid & 63;
    const int lr = l & 15;           // fragment row/col index
    const int lk = l >> 4;           // k-group
    const int row0 = blockIdx.x * 128;

    f32x4 acc[2][8];
    #pragma unroll
    for (int m = 0; m < 2; m++)
        #pragma unroll
        for (int n = 0; n < 8; n++) acc[m][n] = (f32x4)(0.f);

    for (int kc = 0; kc < 4; kc++){
        __syncthreads();
        // stage A chunk: 128 rows x 32 k fp32 -> bf16 hi/lo
        #pragma unroll
        for (int q = 0; q < 4; q++){
            int f = tid + 256 * q;                 // 1024 float4s
            int r = f >> 3, kq = f & 7;
            int gr = row0 + r;
            float4 v = make_float4(0.f, 0.f, 0.f, 0.f);
            if (gr < N_NODES) v = ld4(A + (size_t)gr * NHID + kc * 32 + kq * 4);
            unsigned short h0,l0,h1,l1,h2,l2,h3,l3;
            bsplit(v.x, h0, l0); bsplit(v.y, h1, l1);
            bsplit(v.z, h2, l2); bsplit(v.w, h3, l3);
            *(ushort4*)&Ah[r][kq * 4] = make_ushort4(h0, h1, h2, h3);
            *(ushort4*)&Al[r][kq * 4] = make_ushort4(l0, l1, l2, l3);
        }
        // stage W^T chunk: 128 cols x 32 k bf16 hi/lo (already transposed in global)
        #pragma unroll
        for (int q = 0; q < 2; q++){
            int f = tid + 256 * q;                 // 512 16B loads
            int c = f >> 2, kq = f & 3;
            size_t gi = (size_t)c * 128 + kc * 32 + kq * 8;
            *(uint4*)&Bh[c][kq * 8] = *(const uint4*)(Wth + gi);
            *(uint4*)&Bl[c][kq * 8] = *(const uint4*)(Wtl + gi);
        }
        __syncthreads();
        // fragments: A row = w*32 + m*16 + lr, k = lk*8..+8 (contiguous)
        short8v pah[2], pal[2];
        #pragma unroll
        for (int m = 0; m < 2; m++){
            pah[m] = *(const short8v*)&Ah[w * 32 + m * 16 + lr][lk * 8];
            pal[m] = *(const short8v*)&Al[w * 32 + m * 16 + lr][lk * 8];
        }
        #pragma unroll
        for (int n = 0; n < 8; n++){
            short8v pbh = *(const short8v*)&Bh[n * 16 + lr][lk * 8];
            short8v pbl = *(const short8v*)&Bl[n * 16 + lr][lk * 8];
            #pragma unroll
            for (int m = 0; m < 2; m++){
                acc[m][n] = __builtin_amdgcn_mfma_f32_16x16x32_bf16(pal[m], pbh, acc[m][n], 0, 0, 0);
                acc[m][n] = __builtin_amdgcn_mfma_f32_16x16x32_bf16(pah[m], pbl, acc[m][n], 0, 0, 0);
                acc[m][n] = __builtin_amdgcn_mfma_f32_16x16x32_bf16(pah[m], pbh, acc[m][n], 0, 0, 0);
            }
        }
    }

    if (RELU_OUT){
        #pragma unroll
        for (int m = 0; m < 2; m++)
            #pragma unroll
            for (int n = 0; n < 8; n++)
                #pragma unroll
                for (int j = 0; j < 4; j++) acc[m][n][j] = fmaxf(acc[m][n][j], 0.f);
    }
    // store: C row = row0 + w*32 + m*16 + lk*4 + j, col = n*16 + lr
    #pragma unroll
    for (int m = 0; m < 2; m++)
        #pragma unroll
        for (int j = 0; j < 4; j++){
            int gr = row0 + w * 32 + m * 16 + lk * 4 + j;
            if (gr < N_NODES){
                #pragma unroll
                for (int n = 0; n < 8; n++)
                    out[(size_t)gr * NHID + n * 16 + lr] = acc[m][n][j];
            }
        }

    if (DO_STATS){
        __syncthreads();                       // all LDS frag reads complete
        float* red  = (float*)&Ah[0][0];       // [16][128] col sums  (8 KB, fits in Ah)
        float* red2 = (float*)&Bh[0][0];       // [16][128] col sumsq
        #pragma unroll
        for (int n = 0; n < 8; n++){
            float s = 0.f, q = 0.f;
            #pragma unroll
            for (int m = 0; m < 2; m++)
                #pragma unroll
                for (int j = 0; j < 4; j++){ float v = acc[m][n][j]; s += v; q += v * v; }
            red [(w * 4 + lk) * 128 + n * 16 + lr] = s;
            red2[(w * 4 + lk) * 128 + n * 16 + lr] = q;
        }
        __syncthreads();
        if (tid < 128){
            float s = 0.f, q = 0.f;
            #pragma unroll
            for (int r2 = 0; r2 < 16; r2++){
                s += red[r2 * 128 + tid];
                q += red2[r2 * 128 + tid];
            }
            atomicAdd(&stats_l[tid], s);
            atomicAdd(&stats_l[128 + tid], q);
        }
    }
}

// -------- normalize + relu + residual, BN coefs recomputed per-thread from stats --------

__global__ void k_norm(const float4* __restrict__ h2, float4* __restrict__ x,
                       const float* __restrict__ stats_l,
                       const float* __restrict__ gamma, const float* __restrict__ beta){
    int i = blockIdx.x * 256 + threadIdx.x;
    if (i >= N_NODES * 32) return;
    int g = (i & 31);
    float4 sv = ((const float4*)stats_l)[g];
    float4 qv = ((const float4*)(stats_l + 128))[g];
    float4 gm = ((const float4*)gamma)[g];
    float4 bt = ((const float4*)beta)[g];
    float4 ca, cb;
    {
        float mu, var;
        mu = sv.x * (1.f / N_NODES); var = qv.x * (1.f / N_NODES) - mu * mu;
        ca.x = gm.x * rsqrtf(var + BN_EPS); cb.x = bt.x - mu * ca.x;
        mu = sv.y * (1.f / N_NODES); var = qv.y * (1.f / N_NODES) - mu * mu;
        ca.y = gm.y * rsqrtf(var + BN_EPS); cb.y = bt.y - mu * ca.y;
        mu = sv.z * (1.f / N_NODES); var = qv.z * (1.f / N_NODES) - mu * mu;
        ca.z = gm.z * rsqrtf(var + BN_EPS); cb.z = bt.z - mu * ca.z;
        mu = sv.w * (1.f / N_NODES); var = qv.w * (1.f / N_NODES) - mu * mu;
        ca.w = gm.w * rsqrtf(var + BN_EPS); cb.w = bt.w - mu * ca.w;
    }
    float4 h = h2[i];
    float4 xv = x[i];
    float4 r;
    r.x = fmaxf(fmaf(h.x, ca.x, cb.x), 0.f) + xv.x;
    r.y = fmaxf(fmaf(h.y, ca.y, cb.y), 0.f) + xv.y;
    r.z = fmaxf(fmaf(h.z, ca.z, cb.z), 0.f) + xv.z;
    r.w = fmaxf(fmaf(h.w, ca.w, cb.w), 0.f) + xv.w;
    x[i] = r;
}

// ---------------- pooling ----------------

__global__ void k_pool(const float* __restrict__ x, const int* __restrict__ batch,
                       float* __restrict__ gbuf){
    int g = blockIdx.x;
    int lo = 0, hi = N_NODES;
    while (lo < hi){ int mid = (lo + hi) >> 1; if (batch[mid] < g) lo = mid + 1; else hi = mid; }
    int start = lo;
    hi = N_NODES;
    while (lo < hi){ int mid = (lo + hi) >> 1; if (batch[mid] < g + 1) lo = mid + 1; else hi = mid; }
    int end = lo;
    int c = threadIdx.x & 127;
    int half = threadIdx.x >> 7;
    float acc = 0.f;
    for (int n = start + half; n < end; n += 2) acc += x[n * NHID + c];
    __shared__ float s[256];
    s[threadIdx.x] = acc;
    __syncthreads();
    if (threadIdx.x < 128) gbuf[g * NHID + threadIdx.x] = s[threadIdx.x] + s[threadIdx.x + 128];
}

// ---------------- output head ----------------

__global__ __launch_bounds__(128) void k_head1(const float* __restrict__ gbuf,
                                               const float* __restrict__ w1,
                                               const float* __restrict__ b1,
                                               float* __restrict__ o1){
    __shared__ float gs[128];
    int i = blockIdx.x;
    int j = threadIdx.x;
    gs[j] = gbuf[i * NHID + j];
    __syncthreads();
    float acc = 0.f;
    #pragma unroll 8
    for (int k = 0; k < 128; k++)
        acc = fmaf(gs[k], w1[k * NHID + j], acc);
    o1[i * NHID + j] = acc + b1[j];
}

__global__ __launch_bounds__(128) void k_head2(const float* __restrict__ o1,
                                               const float* __restrict__ gamma,
                                               const float* __restrict__ beta,
                                               const float* __restrict__ w2,
                                               const float* __restrict__ b2,
                                               float* __restrict__ out){
    __shared__ float s_o1[128][129];
    __shared__ float sa[128], sb[128];
    int t = threadIdx.x;
    float s = 0.f, q = 0.f;
    for (int r = 0; r < 128; r++){
        float v = o1[r * NHID + t];
        s_o1[r][t] = v;
        s += v; q += v * v;
    }
    float mu = s * (1.f / 128.f);
    float rs = rsqrtf(q * (1.f / 128.f) - mu * mu + BN_EPS);
    float a = gamma[t] * rs;
    sa[t] = a;
    sb[t] = beta[t] - mu * a;
    __syncthreads();
    float a2 = 0.f;
    #pragma unroll 8
    for (int j = 0; j < 128; j++){
        float v = fmaf(s_o1[t][j], sa[j], sb[j]);
        a2 += fmaxf(v, 0.f) * w2[j];
    }
    out[t] = a2 + b2[0];
}

// ---------------- launch ----------------

extern "C" void kernel_launch(void* const* d_in, const int* in_sizes, int n_in,
                              void* d_out, int out_size, void* d_ws, size_t ws_size,
                              hipStream_t stream){
    const int*   x_idx    = (const int*)d_in[0];
    const int*   eidx     = (const int*)d_in[1];
    const int*   eattr    = (const int*)d_in[2];
    const int*   batch    = (const int*)d_in[3];
    const float* node_emb = (const float*)d_in[4];
    const float* edge_emb = (const float*)d_in[5];
    const float* conv_w1  = (const float*)d_in[6];
    const float* conv_w2  = (const float*)d_in[7];
    const float* bn_gamma = (const float*)d_in[8];
    const float* bn_beta  = (const float*)d_in[9];
    const float* out_w1   = (const float*)d_in[10];
    const float* out_b1   = (const float*)d_in[11];
    const float* out_bng  = (const float*)d_in[12];
    const float* out_bnb  = (const float*)d_in[13];
    const float* out_w2   = (const float*)d_in[14];
    const float* out_b2   = (const float*)d_in[15];
    float* out = (float*)d_out;

    char* base = (char*)d_ws;
    size_t off = 0;
    auto alloc = [&](size_t bytes) -> char* {
        char* r = base + off;
        off = (off + bytes + 255) & ~(size_t)255;
        return r;
    };
    float*          xbuf    = (float*)alloc((size_t)N_NODES * NHID * 4);   // 51.2 MB
    float*          h0buf   = (float*)alloc((size_t)N_NODES * NHID * 4);   // 51.2 MB
    int*            row_ptr = (int*)alloc((size_t)(N_NODES + 1) * 4);
    int*            cursor  = (int*)alloc((size_t)N_NODES * 4);
    int*            counts  = (int*)alloc((size_t)N_NODES * 4);
    int*            partial = (int*)alloc(512 * 4);
    unsigned*       pack    = (unsigned*)alloc((size_t)N_EDGES * 4);       // 6.4 MB
    float*          combo   = (float*)alloc((size_t)2000 * NHID * 4);      // 1.0 MB
    unsigned short* wth     = (unsigned short*)alloc((size_t)8 * 16384 * 2); // 256 KB
    unsigned short* wtl     = (unsigned short*)alloc((size_t)8 * 16384 * 2); // 256 KB
    float*          stats   = (float*)alloc(NLAYER * 256 * 4);
    float*          gbuf    = (float*)alloc((size_t)N_GRAPHS * NHID * 4);
    float*          o1buf   = (float*)alloc((size_t)N_GRAPHS * NHID * 4);
    (void)ws_size; (void)in_sizes; (void)n_in; (void)out_size;

    hipMemsetAsync(counts, 0, (size_t)N_NODES * 4, stream);
    hipMemsetAsync(stats, 0, NLAYER * 256 * 4, stream);

    // CSR build (edges grouped by dst), once per call, reused across 4 layers
    k_hist<<<N_EDGES / 256, 256, 0, stream>>>(eidx + N_EDGES, counts);
    k_scan_partial<<<SCAN_NB, 256, 0, stream>>>(counts, partial);
    k_scan_top<<<1, 128, 0, stream>>>(partial, SCAN_NB, row_ptr);
    k_scan_final<<<SCAN_NB, 256, 0, stream>>>(counts, partial, row_ptr);
    hipMemcpyAsync(cursor, row_ptr, (size_t)N_NODES * 4, hipMemcpyDeviceToDevice, stream);
    k_fill<<<N_EDGES / 256, 256, 0, stream>>>(eidx, eattr, x_idx, cursor, pack);

    // per-call precomputes
    k_combo<<<(2000 * NHID) / 256, 256, 0, stream>>>(node_emb, edge_emb, combo);
    k_wsplit<<<131072 / 256, 256, 0, stream>>>(conv_w1, conv_w2, wth, wtl);
    k_initx<<<(N_NODES * 32) / 256, 256, 0, stream>>>(x_idx, node_emb, (float4*)xbuf);

    const int gemm_grid = (N_NODES + 127) / 128;     // 782
    for (int l = 0; l < NLAYER; l++){
        if (l == 0){
            k_agg0<<<(N_NODES * 64) / 256, 256, 0, stream>>>(
                xbuf, row_ptr, pack, combo, (float2*)h0buf);
        } else {
            k_agg<<<(N_NODES * 64) / 256, 256, 0, stream>>>(
                xbuf, row_ptr, pack, edge_emb + (size_t)l * 20 * NHID, (float2*)h0buf);
        }
        // t = relu(h0 @ w1)   (in place, split-bf16 MFMA)
        k_mfma<1, 0><<<gemm_grid, 256, 0, stream>>>(
            h0buf, wth + (size_t)l * 16384, wtl + (size_t)l * 16384, h0buf, nullptr);
        // h2 = t @ w2 (+ BN stats)   (in place)
        k_mfma<0, 1><<<gemm_grid, 256, 0, stream>>>(
            h0buf, wth + (size_t)(4 + l) * 16384, wtl + (size_t)(4 + l) * 16384,
            h0buf, stats + l * 256);
        k_norm<<<(N_NODES * 32) / 256, 256, 0, stream>>>(
            (const float4*)h0buf, (float4*)xbuf, stats + l * 256,
            bn_gamma + l * NHID, bn_beta + l * NHID);
    }

    k_pool<<<N_GRAPHS, 256, 0, stream>>>(xbuf, batch, gbuf);
    k_head1<<<N_GRAPHS, 128, 0, stream>>>(gbuf, out_w1, out_b1, o1buf);
    k_head2<<<1, 128, 0, stream>>>(o1buf, out_bng, out_bnb, out_w2, out_b2, out);
}

// Round 8
// 1158.399 us; speedup vs baseline: 1.3227x; 1.0631x over previous
//
#include <hip/hip_runtime.h>

#define N_NODES 100000
#define N_EDGES 1600000
#define N_GRAPHS 128
#define NHID 128
#define NLAYER 4
#define BN_EPS 1e-5f

#define SCAN_ITEMS 1024
#define SCAN_NB ((N_NODES + SCAN_ITEMS - 1) / SCAN_ITEMS)   // 98

__device__ __forceinline__ float4 ld4(const float* p){ return *(const float4*)p; }
__device__ __forceinline__ void st4(float* p, float4 v){ *(float4*)p = v; }

typedef __attribute__((ext_vector_type(8))) short short8v;   // 8 bf16 = 4 VGPR
typedef __attribute__((ext_vector_type(4))) float f32x4;     // MFMA acc

// split fp32 -> bf16 hi (truncate) + bf16 lo (truncate of residual)
__device__ __forceinline__ void bsplit(float a, unsigned short& h, unsigned short& l){
    unsigned ab = __float_as_uint(a);
    h = (unsigned short)(ab >> 16);
    float hf = __uint_as_float((unsigned)h << 16);
    l = (unsigned short)(__float_as_uint(a - hf) >> 16);
}

// fp32 -> bf16 round-to-nearest-even
__device__ __forceinline__ unsigned short brne(float a){
    unsigned ab = __float_as_uint(a);
    return (unsigned short)((ab + 0x7FFFu + ((ab >> 16) & 1u)) >> 16);
}
__device__ __forceinline__ float b2f(unsigned short b){
    return __uint_as_float((unsigned)b << 16);
}

// ---------------- CSR build ----------------

__global__ void k_hist(const int* __restrict__ dst, int* __restrict__ counts){
    int e = blockIdx.x * 256 + threadIdx.x;
    if (e < N_EDGES) atomicAdd(&counts[dst[e]], 1);
}

__global__ void k_scan_partial(const int* __restrict__ counts, int* __restrict__ partial){
    __shared__ int s[256];
    int t = threadIdx.x;
    int base = blockIdx.x * SCAN_ITEMS + t * 4;
    int v = 0;
    #pragma unroll
    for (int k = 0; k < 4; k++) if (base + k < N_NODES) v += counts[base + k];
    s[t] = v;
    __syncthreads();
    for (int o = 128; o > 0; o >>= 1){
        if (t < o) s[t] += s[t + o];
        __syncthreads();
    }
    if (t == 0) partial[blockIdx.x] = s[0];
}

__global__ void k_scan_top(int* __restrict__ partial, int nb, int* __restrict__ row_ptr){
    __shared__ int s[128];
    int t = threadIdx.x;
    int v = (t < nb) ? partial[t] : 0;
    s[t] = v;
    __syncthreads();
    for (int d = 1; d < 128; d <<= 1){
        int add = (t >= d) ? s[t - d] : 0;
        __syncthreads();
        s[t] += add;
        __syncthreads();
    }
    if (t < nb) partial[t] = s[t] - v;           // exclusive
    if (t == 0) row_ptr[N_NODES] = N_EDGES;
}

__global__ void k_scan_final(const int* __restrict__ counts, const int* __restrict__ partial,
                             int* __restrict__ row_ptr){
    __shared__ int s[256];
    int t = threadIdx.x;
    int base = blockIdx.x * SCAN_ITEMS + t * 4;
    int v[4]; int tsum = 0;
    #pragma unroll
    for (int k = 0; k < 4; k++){ v[k] = (base + k < N_NODES) ? counts[base + k] : 0; tsum += v[k]; }
    s[t] = tsum;
    __syncthreads();
    for (int d = 1; d < 256; d <<= 1){
        int add = (t >= d) ? s[t - d] : 0;
        __syncthreads();
        s[t] += add;
        __syncthreads();
    }
    int off = partial[blockIdx.x] + s[t] - tsum;  // exclusive prefix for this thread
    #pragma unroll
    for (int k = 0; k < 4; k++){
        if (base + k < N_NODES) row_ptr[base + k] = off;
        off += v[k];
    }
}

// fill CSR payload: ONE packed word per edge -> src(17b) | attr(5b)<<17 | x_idx(7b)<<22
__global__ void k_fill(const int* __restrict__ eidx, const int* __restrict__ eattr,
                       const int* __restrict__ x_idx,
                       int* __restrict__ cursor, unsigned* __restrict__ pack){
    int e = blockIdx.x * 256 + threadIdx.x;
    if (e >= N_EDGES) return;
    int d = eidx[N_EDGES + e];
    int s = eidx[e];
    int a = eattr[e];
    int xi = x_idx[s];
    int pos = atomicAdd(&cursor[d], 1);
    pack[pos] = (unsigned)s | ((unsigned)a << 17) | ((unsigned)xi << 22);
}

// ---------------- layer-0 message memo table ----------------

__global__ void k_combo(const float* __restrict__ node_emb, const float* __restrict__ edge_emb0,
                        float* __restrict__ combo){
    int i = blockIdx.x * 256 + threadIdx.x;          // over 2000*128
    if (i >= 2000 * NHID) return;
    int row = i >> 7, c = i & 127;
    int ni = row / 20, a = row - ni * 20;
    combo[i] = fmaxf(node_emb[ni * NHID + c] + edge_emb0[a * NHID + c], 0.f);
}

// ---------------- W^T split tables: [which][layer][col][k] bf16 hi/lo ----------------

__global__ void k_wsplit(const float* __restrict__ w1, const float* __restrict__ w2,
                         unsigned short* __restrict__ wth, unsigned short* __restrict__ wtl){
    int i = blockIdx.x * 256 + threadIdx.x;          // 2*4*128*128 = 131072
    int which = i >> 16;
    int m = (i >> 14) & 3;
    int r = i & 16383;
    int k = r >> 7, c = r & 127;
    float v = (which ? w2 : w1)[m * 16384 + k * 128 + c];
    unsigned short h, l;
    bsplit(v, h, l);
    int o = ((which * 4 + m) * 128 + c) * 128 + k;   // transposed: [col][k]
    wth[o] = h; wtl[o] = l;
}

// ---------------- node embedding init ----------------

__global__ void k_initx(const int* __restrict__ x_idx, const float* __restrict__ node_emb,
                        float4* __restrict__ x4){
    int i = blockIdx.x * 256 + threadIdx.x;          // over N*32 float4s
    if (i >= N_NODES * 32) return;
    int n = i >> 5, c = i & 31;
    int id = x_idx[n];
    x4[i] = ((const float4*)node_emb)[id * 32 + c];
}

// ----- aggregation (layers 1-3): h0[n] = x[n] + sum relu(bf16(x[src]) + emb[attr]) -----
// x[src] gathered from the bf16 shadow copy (256 B/edge, ~L2-resident); self-term fp32 exact.

__global__ __launch_bounds__(256) void k_agg(const float* __restrict__ x,
                      const ushort2* __restrict__ xb,
                      const int* __restrict__ row_ptr,
                      const unsigned* __restrict__ pack, const float* __restrict__ emb_l,
                      float2* __restrict__ h0){
    int gid = blockIdx.x * 256 + threadIdx.x;
    int node = gid >> 6;
    int lane = threadIdx.x & 63;
    const float2* x2 = (const float2*)x;
    const float2* e2 = (const float2*)emb_l;
    float2 acc = x2[node * 64 + lane];
    int beg = row_ptr[node], end = row_ptr[node + 1];
    int i = beg;
    for (; i + 3 < end; i += 4){
        unsigned p0 = pack[i], p1 = pack[i+1], p2 = pack[i+2], p3 = pack[i+3];
        ushort2 g0 = xb[(p0 & 0x1FFFFu) * 64 + lane];
        ushort2 g1 = xb[(p1 & 0x1FFFFu) * 64 + lane];
        ushort2 g2 = xb[(p2 & 0x1FFFFu) * 64 + lane];
        ushort2 g3 = xb[(p3 & 0x1FFFFu) * 64 + lane];
        float2 b0 = e2[((p0 >> 17) & 31u) * 64 + lane];
        float2 b1 = e2[((p1 >> 17) & 31u) * 64 + lane];
        float2 b2 = e2[((p2 >> 17) & 31u) * 64 + lane];
        float2 b3 = e2[((p3 >> 17) & 31u) * 64 + lane];
        acc.x += (fmaxf(b2f(g0.x) + b0.x, 0.f) + fmaxf(b2f(g1.x) + b1.x, 0.f))
               + (fmaxf(b2f(g2.x) + b2.x, 0.f) + fmaxf(b2f(g3.x) + b3.x, 0.f));
        acc.y += (fmaxf(b2f(g0.y) + b0.y, 0.f) + fmaxf(b2f(g1.y) + b1.y, 0.f))
               + (fmaxf(b2f(g2.y) + b2.y, 0.f) + fmaxf(b2f(g3.y) + b3.y, 0.f));
    }
    for (; i < end; i++){
        unsigned p = pack[i];
        ushort2 g = xb[(p & 0x1FFFFu) * 64 + lane];
        float2 ev = e2[((p >> 17) & 31u) * 64 + lane];
        acc.x += fmaxf(b2f(g.x) + ev.x, 0.f);
        acc.y += fmaxf(b2f(g.y) + ev.y, 0.f);
    }
    h0[node * 64 + lane] = acc;
}

// ---------------- aggregation (layer 0): memo table ----------------

__global__ __launch_bounds__(256) void k_agg0(const float* __restrict__ x,
                      const int* __restrict__ row_ptr,
                      const unsigned* __restrict__ pack,
                      const float* __restrict__ combo,
                      float2* __restrict__ h0){
    int gid = blockIdx.x * 256 + threadIdx.x;
    int node = gid >> 6;
    int lane = threadIdx.x & 63;
    const float2* x2 = (const float2*)x;
    const float2* c2 = (const float2*)combo;
    float2 acc = x2[node * 64 + lane];
    int beg = row_ptr[node], end = row_ptr[node + 1];
    int i = beg;
    for (; i + 3 < end; i += 4){
        unsigned p0 = pack[i], p1 = pack[i+1], p2 = pack[i+2], p3 = pack[i+3];
        int ci0 = (int)((p0 >> 22) & 127u) * 20 + (int)((p0 >> 17) & 31u);
        int ci1 = (int)((p1 >> 22) & 127u) * 20 + (int)((p1 >> 17) & 31u);
        int ci2 = (int)((p2 >> 22) & 127u) * 20 + (int)((p2 >> 17) & 31u);
        int ci3 = (int)((p3 >> 22) & 127u) * 20 + (int)((p3 >> 17) & 31u);
        float2 m0 = c2[ci0 * 64 + lane];
        float2 m1 = c2[ci1 * 64 + lane];
        float2 m2 = c2[ci2 * 64 + lane];
        float2 m3 = c2[ci3 * 64 + lane];
        acc.x += (m0.x + m1.x) + (m2.x + m3.x);
        acc.y += (m0.y + m1.y) + (m2.y + m3.y);
    }
    for (; i < end; i++){
        unsigned p = pack[i];
        int ci = (int)((p >> 22) & 127u) * 20 + (int)((p >> 17) & 31u);
        float2 m = c2[ci * 64 + lane];
        acc.x += m.x;
        acc.y += m.y;
    }
    h0[node * 64 + lane] = acc;
}

// ---- split-bf16 MFMA GEMM: C(128x128) = A(128x128) @ W, via Ah@Wh + Ah@Wl + Al@Wh ----

template<int RELU_OUT, int DO_STATS>
__global__ __launch_bounds__(256) void k_mfma(const float* __restrict__ A,
                                              const unsigned short* __restrict__ Wth,
                                              const unsigned short* __restrict__ Wtl,
                                              float* __restrict__ out,
                                              float* __restrict__ stats_l){
    __shared__ unsigned short Ah[128][40], Al[128][40];   // 80 B pitch: 2-way banks only
    __shared__ unsigned short Bh[128][40], Bl[128][40];   // W^T chunk [col][k]
    const int tid = threadIdx.x;
    const int w = tid >> 6;          // wave 0..3 -> rows [w*32, w*32+32)
    const int l = tid & 63;
    const int lr = l & 15;           // fragment row/col index
    const int lk = l >> 4;           // k-group
    const int row0 = blockIdx.x * 128;

    f32x4 acc[2][8];
    #pragma unroll
    for (int m = 0; m < 2; m++)
        #pragma unroll
        for (int n = 0; n < 8; n++) acc[m][n] = (f32x4)(0.f);

    for (int kc = 0; kc < 4; kc++){
        __syncthreads();
        // stage A chunk: 128 rows x 32 k fp32 -> bf16 hi/lo
        #pragma unroll
        for (int q = 0; q < 4; q++){
            int f = tid + 256 * q;                 // 1024 float4s
            int r = f >> 3, kq = f & 7;
            int gr = row0 + r;
            float4 v = make_float4(0.f, 0.f, 0.f, 0.f);
            if (gr < N_NODES) v = ld4(A + (size_t)gr * NHID + kc * 32 + kq * 4);
            unsigned short h0,l0,h1,l1,h2,l2,h3,l3;
            bsplit(v.x, h0, l0); bsplit(v.y, h1, l1);
            bsplit(v.z, h2, l2); bsplit(v.w, h3, l3);
            *(ushort4*)&Ah[r][kq * 4] = make_ushort4(h0, h1, h2, h3);
            *(ushort4*)&Al[r][kq * 4] = make_ushort4(l0, l1, l2, l3);
        }
        // stage W^T chunk: 128 cols x 32 k bf16 hi/lo (already transposed in global)
        #pragma unroll
        for (int q = 0; q < 2; q++){
            int f = tid + 256 * q;                 // 512 16B loads
            int c = f >> 2, kq = f & 3;
            size_t gi = (size_t)c * 128 + kc * 32 + kq * 8;
            *(uint4*)&Bh[c][kq * 8] = *(const uint4*)(Wth + gi);
            *(uint4*)&Bl[c][kq * 8] = *(const uint4*)(Wtl + gi);
        }
        __syncthreads();
        // fragments: A row = w*32 + m*16 + lr, k = lk*8..+8 (contiguous)
        short8v pah[2], pal[2];
        #pragma unroll
        for (int m = 0; m < 2; m++){
            pah[m] = *(const short8v*)&Ah[w * 32 + m * 16 + lr][lk * 8];
            pal[m] = *(const short8v*)&Al[w * 32 + m * 16 + lr][lk * 8];
        }
        #pragma unroll
        for (int n = 0; n < 8; n++){
            short8v pbh = *(const short8v*)&Bh[n * 16 + lr][lk * 8];
            short8v pbl = *(const short8v*)&Bl[n * 16 + lr][lk * 8];
            #pragma unroll
            for (int m = 0; m < 2; m++){
                acc[m][n] = __builtin_amdgcn_mfma_f32_16x16x32_bf16(pal[m], pbh, acc[m][n], 0, 0, 0);
                acc[m][n] = __builtin_amdgcn_mfma_f32_16x16x32_bf16(pah[m], pbl, acc[m][n], 0, 0, 0);
                acc[m][n] = __builtin_amdgcn_mfma_f32_16x16x32_bf16(pah[m], pbh, acc[m][n], 0, 0, 0);
            }
        }
    }

    if (RELU_OUT){
        #pragma unroll
        for (int m = 0; m < 2; m++)
            #pragma unroll
            for (int n = 0; n < 8; n++)
                #pragma unroll
                for (int j = 0; j < 4; j++) acc[m][n][j] = fmaxf(acc[m][n][j], 0.f);
    }
    // store: C row = row0 + w*32 + m*16 + lk*4 + j, col = n*16 + lr
    #pragma unroll
    for (int m = 0; m < 2; m++)
        #pragma unroll
        for (int j = 0; j < 4; j++){
            int gr = row0 + w * 32 + m * 16 + lk * 4 + j;
            if (gr < N_NODES){
                #pragma unroll
                for (int n = 0; n < 8; n++)
                    out[(size_t)gr * NHID + n * 16 + lr] = acc[m][n][j];
            }
        }

    if (DO_STATS){
        __syncthreads();                       // all LDS frag reads complete
        float* red  = (float*)&Ah[0][0];       // [16][128] col sums
        float* red2 = (float*)&Bh[0][0];       // [16][128] col sumsq
        #pragma unroll
        for (int n = 0; n < 8; n++){
            float s = 0.f, q = 0.f;
            #pragma unroll
            for (int m = 0; m < 2; m++)
                #pragma unroll
                for (int j = 0; j < 4; j++){ float v = acc[m][n][j]; s += v; q += v * v; }
            red [(w * 4 + lk) * 128 + n * 16 + lr] = s;
            red2[(w * 4 + lk) * 128 + n * 16 + lr] = q;
        }
        __syncthreads();
        if (tid < 128){
            float s = 0.f, q = 0.f;
            #pragma unroll
            for (int r2 = 0; r2 < 16; r2++){
                s += red[r2 * 128 + tid];
                q += red2[r2 * 128 + tid];
            }
            atomicAdd(&stats_l[tid], s);
            atomicAdd(&stats_l[128 + tid], q);
        }
    }
}

// -------- normalize + relu + residual; also emit bf16 shadow copy of x for gathers --------

__global__ void k_norm(const float4* __restrict__ h2, float4* __restrict__ x,
                       ushort4* __restrict__ xb,
                       const float* __restrict__ stats_l,
                       const float* __restrict__ gamma, const float* __restrict__ beta){
    int i = blockIdx.x * 256 + threadIdx.x;
    if (i >= N_NODES * 32) return;
    int g = (i & 31);
    float4 sv = ((const float4*)stats_l)[g];
    float4 qv = ((const float4*)(stats_l + 128))[g];
    float4 gm = ((const float4*)gamma)[g];
    float4 bt = ((const float4*)beta)[g];
    float4 ca, cb;
    {
        float mu, var;
        mu = sv.x * (1.f / N_NODES); var = qv.x * (1.f / N_NODES) - mu * mu;
        ca.x = gm.x * rsqrtf(var + BN_EPS); cb.x = bt.x - mu * ca.x;
        mu = sv.y * (1.f / N_NODES); var = qv.y * (1.f / N_NODES) - mu * mu;
        ca.y = gm.y * rsqrtf(var + BN_EPS); cb.y = bt.y - mu * ca.y;
        mu = sv.z * (1.f / N_NODES); var = qv.z * (1.f / N_NODES) - mu * mu;
        ca.z = gm.z * rsqrtf(var + BN_EPS); cb.z = bt.z - mu * ca.z;
        mu = sv.w * (1.f / N_NODES); var = qv.w * (1.f / N_NODES) - mu * mu;
        ca.w = gm.w * rsqrtf(var + BN_EPS); cb.w = bt.w - mu * ca.w;
    }
    float4 h = h2[i];
    float4 xv = x[i];
    float4 r;
    r.x = fmaxf(fmaf(h.x, ca.x, cb.x), 0.f) + xv.x;
    r.y = fmaxf(fmaf(h.y, ca.y, cb.y), 0.f) + xv.y;
    r.z = fmaxf(fmaf(h.z, ca.z, cb.z), 0.f) + xv.z;
    r.w = fmaxf(fmaf(h.w, ca.w, cb.w), 0.f) + xv.w;
    x[i] = r;
    xb[i] = make_ushort4(brne(r.x), brne(r.y), brne(r.z), brne(r.w));
}

// ---------------- pooling ----------------

__global__ void k_pool(const float* __restrict__ x, const int* __restrict__ batch,
                       float* __restrict__ gbuf){
    int g = blockIdx.x;
    int lo = 0, hi = N_NODES;
    while (lo < hi){ int mid = (lo + hi) >> 1; if (batch[mid] < g) lo = mid + 1; else hi = mid; }
    int start = lo;
    hi = N_NODES;
    while (lo < hi){ int mid = (lo + hi) >> 1; if (batch[mid] < g + 1) lo = mid + 1; else hi = mid; }
    int end = lo;
    int c = threadIdx.x & 127;
    int half = threadIdx.x >> 7;
    float acc = 0.f;
    for (int n = start + half; n < end; n += 2) acc += x[n * NHID + c];
    __shared__ float s[256];
    s[threadIdx.x] = acc;
    __syncthreads();
    if (threadIdx.x < 128) gbuf[g * NHID + threadIdx.x] = s[threadIdx.x] + s[threadIdx.x + 128];
}

// ---------------- output head ----------------

__global__ __launch_bounds__(128) void k_head1(const float* __restrict__ gbuf,
                                               const float* __restrict__ w1,
                                               const float* __restrict__ b1,
                                               float* __restrict__ o1){
    __shared__ float gs[128];
    int i = blockIdx.x;
    int j = threadIdx.x;
    gs[j] = gbuf[i * NHID + j];
    __syncthreads();
    float acc = 0.f;
    #pragma unroll 8
    for (int k = 0; k < 128; k++)
        acc = fmaf(gs[k], w1[k * NHID + j], acc);
    o1[i * NHID + j] = acc + b1[j];
}

__global__ __launch_bounds__(128) void k_head2(const float* __restrict__ o1,
                                               const float* __restrict__ gamma,
                                               const float* __restrict__ beta,
                                               const float* __restrict__ w2,
                                               const float* __restrict__ b2,
                                               float* __restrict__ out){
    __shared__ float s_o1[128][129];
    __shared__ float sa[128], sb[128];
    int t = threadIdx.x;
    float s = 0.f, q = 0.f;
    for (int r = 0; r < 128; r++){
        float v = o1[r * NHID + t];
        s_o1[r][t] = v;
        s += v; q += v * v;
    }
    float mu = s * (1.f / 128.f);
    float rs = rsqrtf(q * (1.f / 128.f) - mu * mu + BN_EPS);
    float a = gamma[t] * rs;
    sa[t] = a;
    sb[t] = beta[t] - mu * a;
    __syncthreads();
    float a2 = 0.f;
    #pragma unroll 8
    for (int j = 0; j < 128; j++){
        float v = fmaf(s_o1[t][j], sa[j], sb[j]);
        a2 += fmaxf(v, 0.f) * w2[j];
    }
    out[t] = a2 + b2[0];
}

// ---------------- launch ----------------

extern "C" void kernel_launch(void* const* d_in, const int* in_sizes, int n_in,
                              void* d_out, int out_size, void* d_ws, size_t ws_size,
                              hipStream_t stream){
    const int*   x_idx    = (const int*)d_in[0];
    const int*   eidx     = (const int*)d_in[1];
    const int*   eattr    = (const int*)d_in[2];
    const int*   batch    = (const int*)d_in[3];
    const float* node_emb = (const float*)d_in[4];
    const float* edge_emb = (const float*)d_in[5];
    const float* conv_w1  = (const float*)d_in[6];
    const float* conv_w2  = (const float*)d_in[7];
    const float* bn_gamma = (const float*)d_in[8];
    const float* bn_beta  = (const float*)d_in[9];
    const float* out_w1   = (const float*)d_in[10];
    const float* out_b1   = (const float*)d_in[11];
    const float* out_bng  = (const float*)d_in[12];
    const float* out_bnb  = (const float*)d_in[13];
    const float* out_w2   = (const float*)d_in[14];
    const float* out_b2   = (const float*)d_in[15];
    float* out = (float*)d_out;

    char* base = (char*)d_ws;
    size_t off = 0;
    auto alloc = [&](size_t bytes) -> char* {
        char* r = base + off;
        off = (off + bytes + 255) & ~(size_t)255;
        return r;
    };
    float*          xbuf    = (float*)alloc((size_t)N_NODES * NHID * 4);   // 51.2 MB
    float*          h0buf   = (float*)alloc((size_t)N_NODES * NHID * 4);   // 51.2 MB
    unsigned short* xbf     = (unsigned short*)alloc((size_t)N_NODES * NHID * 2); // 25.6 MB
    int*            row_ptr = (int*)alloc((size_t)(N_NODES + 1) * 4);
    int*            cursor  = (int*)alloc((size_t)N_NODES * 4);
    int*            counts  = (int*)alloc((size_t)N_NODES * 4);
    int*            partial = (int*)alloc(512 * 4);
    unsigned*       pack    = (unsigned*)alloc((size_t)N_EDGES * 4);       // 6.4 MB
    float*          combo   = (float*)alloc((size_t)2000 * NHID * 4);      // 1.0 MB
    unsigned short* wth     = (unsigned short*)alloc((size_t)8 * 16384 * 2); // 256 KB
    unsigned short* wtl     = (unsigned short*)alloc((size_t)8 * 16384 * 2); // 256 KB
    float*          stats   = (float*)alloc(NLAYER * 256 * 4);
    float*          gbuf    = (float*)alloc((size_t)N_GRAPHS * NHID * 4);
    float*          o1buf   = (float*)alloc((size_t)N_GRAPHS * NHID * 4);
    (void)ws_size; (void)in_sizes; (void)n_in; (void)out_size;

    hipMemsetAsync(counts, 0, (size_t)N_NODES * 4, stream);
    hipMemsetAsync(stats, 0, NLAYER * 256 * 4, stream);

    // CSR build (edges grouped by dst), once per call, reused across 4 layers
    k_hist<<<N_EDGES / 256, 256, 0, stream>>>(eidx + N_EDGES, counts);
    k_scan_partial<<<SCAN_NB, 256, 0, stream>>>(counts, partial);
    k_scan_top<<<1, 128, 0, stream>>>(partial, SCAN_NB, row_ptr);
    k_scan_final<<<SCAN_NB, 256, 0, stream>>>(counts, partial, row_ptr);
    hipMemcpyAsync(cursor, row_ptr, (size_t)N_NODES * 4, hipMemcpyDeviceToDevice, stream);
    k_fill<<<N_EDGES / 256, 256, 0, stream>>>(eidx, eattr, x_idx, cursor, pack);

    // per-call precomputes
    k_combo<<<(2000 * NHID) / 256, 256, 0, stream>>>(node_emb, edge_emb, combo);
    k_wsplit<<<131072 / 256, 256, 0, stream>>>(conv_w1, conv_w2, wth, wtl);
    k_initx<<<(N_NODES * 32) / 256, 256, 0, stream>>>(x_idx, node_emb, (float4*)xbuf);

    const int gemm_grid = (N_NODES + 127) / 128;     // 782
    for (int l = 0; l < NLAYER; l++){
        if (l == 0){
            k_agg0<<<(N_NODES * 64) / 256, 256, 0, stream>>>(
                xbuf, row_ptr, pack, combo, (float2*)h0buf);
        } else {
            k_agg<<<(N_NODES * 64) / 256, 256, 0, stream>>>(
                xbuf, (const ushort2*)xbf, row_ptr, pack,
                edge_emb + (size_t)l * 20 * NHID, (float2*)h0buf);
        }
        // t = relu(h0 @ w1)   (in place, split-bf16 MFMA)
        k_mfma<1, 0><<<gemm_grid, 256, 0, stream>>>(
            h0buf, wth + (size_t)l * 16384, wtl + (size_t)l * 16384, h0buf, nullptr);
        // h2 = t @ w2 (+ BN stats)   (in place)
        k_mfma<0, 1><<<gemm_grid, 256, 0, stream>>>(
            h0buf, wth + (size_t)(4 + l) * 16384, wtl + (size_t)(4 + l) * 16384,
            h0buf, stats + l * 256);
        k_norm<<<(N_NODES * 32) / 256, 256, 0, stream>>>(
            (const float4*)h0buf, (float4*)xbuf, (ushort4*)xbf, stats + l * 256,
            bn_gamma + l * NHID, bn_beta + l * NHID);
    }

    k_pool<<<N_GRAPHS, 256, 0, stream>>>(xbuf, batch, gbuf);
    k_head1<<<N_GRAPHS, 128, 0, stream>>>(gbuf, out_w1, out_b1, o1buf);
    k_head2<<<1, 128, 0, stream>>>(o1buf, out_bng, out_bnb, out_w2, out_b2, out);
}

// Round 9
// 1103.090 us; speedup vs baseline: 1.3890x; 1.0501x over previous
//
#include <hip/hip_runtime.h>

#define N_NODES 100000
#define N_EDGES 1600000
#define N_GRAPHS 128
#define NHID 128
#define NLAYER 4
#define BN_EPS 1e-5f

#define SCAN_ITEMS 1024
#define SCAN_NB ((N_NODES + SCAN_ITEMS - 1) / SCAN_ITEMS)   // 98

#define FILL_CHUNK 8192
#define FILL_NB ((N_NODES + 255) / 256)                      // 391 coarse buckets (256 nodes)

__device__ __forceinline__ float4 ld4(const float* p){ return *(const float4*)p; }
__device__ __forceinline__ void st4(float* p, float4 v){ *(float4*)p = v; }

typedef __attribute__((ext_vector_type(8))) short short8v;   // 8 bf16 = 4 VGPR
typedef __attribute__((ext_vector_type(4))) float f32x4;     // MFMA acc

// split fp32 -> bf16 hi (truncate) + bf16 lo (truncate of residual)
__device__ __forceinline__ void bsplit(float a, unsigned short& h, unsigned short& l){
    unsigned ab = __float_as_uint(a);
    h = (unsigned short)(ab >> 16);
    float hf = __uint_as_float((unsigned)h << 16);
    l = (unsigned short)(__float_as_uint(a - hf) >> 16);
}

// fp32 -> bf16 round-to-nearest-even
__device__ __forceinline__ unsigned short brne(float a){
    unsigned ab = __float_as_uint(a);
    return (unsigned short)((ab + 0x7FFFu + ((ab >> 16) & 1u)) >> 16);
}
__device__ __forceinline__ float b2f(unsigned short b){
    return __uint_as_float((unsigned)b << 16);
}

// ---------------- CSR build ----------------

__global__ void k_hist(const int* __restrict__ dst, int* __restrict__ counts){
    int e = blockIdx.x * 256 + threadIdx.x;
    if (e < N_EDGES) atomicAdd(&counts[dst[e]], 1);
}

__global__ void k_scan_partial(const int* __restrict__ counts, int* __restrict__ partial){
    __shared__ int s[256];
    int t = threadIdx.x;
    int base = blockIdx.x * SCAN_ITEMS + t * 4;
    int v = 0;
    #pragma unroll
    for (int k = 0; k < 4; k++) if (base + k < N_NODES) v += counts[base + k];
    s[t] = v;
    __syncthreads();
    for (int o = 128; o > 0; o >>= 1){
        if (t < o) s[t] += s[t + o];
        __syncthreads();
    }
    if (t == 0) partial[blockIdx.x] = s[0];
}

__global__ void k_scan_top(int* __restrict__ partial, int nb, int* __restrict__ row_ptr){
    __shared__ int s[128];
    int t = threadIdx.x;
    int v = (t < nb) ? partial[t] : 0;
    s[t] = v;
    __syncthreads();
    for (int d = 1; d < 128; d <<= 1){
        int add = (t >= d) ? s[t - d] : 0;
        __syncthreads();
        s[t] += add;
        __syncthreads();
    }
    if (t < nb) partial[t] = s[t] - v;           // exclusive
    if (t == 0) row_ptr[N_NODES] = N_EDGES;
}

__global__ void k_scan_final(const int* __restrict__ counts, const int* __restrict__ partial,
                             int* __restrict__ row_ptr){
    __shared__ int s[256];
    int t = threadIdx.x;
    int base = blockIdx.x * SCAN_ITEMS + t * 4;
    int v[4]; int tsum = 0;
    #pragma unroll
    for (int k = 0; k < 4; k++){ v[k] = (base + k < N_NODES) ? counts[base + k] : 0; tsum += v[k]; }
    s[t] = tsum;
    __syncthreads();
    for (int d = 1; d < 256; d <<= 1){
        int add = (t >= d) ? s[t - d] : 0;
        __syncthreads();
        s[t] += add;
        __syncthreads();
    }
    int off = partial[blockIdx.x] + s[t] - tsum;  // exclusive prefix for this thread
    #pragma unroll
    for (int k = 0; k < 4; k++){
        if (base + k < N_NODES) row_ptr[base + k] = off;
        off += v[k];
    }
}

// bucket cursors init from row_ptr at 256-node granularity
__global__ void k_binit(const int* __restrict__ row_ptr, int* __restrict__ bcur){
    int b = blockIdx.x * 256 + threadIdx.x;
    if (b < FILL_NB) bcur[b] = row_ptr[b * 256];
}

// pass A: LDS-binned coarse bucket sort -> tmp {packword, dst}, run-length XCD-local writes
__global__ __launch_bounds__(256) void k_fillA(const int* __restrict__ eidx,
                        const int* __restrict__ eattr, const int* __restrict__ x_idx,
                        int* __restrict__ bcur, uint2* __restrict__ tmp){
    __shared__ int cnt[FILL_NB];
    __shared__ int lstart[FILL_NB];
    __shared__ int lcur[FILL_NB];
    __shared__ int gbase[FILL_NB];
    __shared__ uint2 stage[FILL_CHUNK];              // 64 KB
    int t = threadIdx.x;
    int e0 = blockIdx.x * FILL_CHUNK;
    int n = min(FILL_CHUNK, N_EDGES - e0);
    for (int i = t; i < FILL_NB; i += 256) cnt[i] = 0;
    __syncthreads();
    for (int i = t; i < n; i += 256)
        atomicAdd(&cnt[(unsigned)eidx[N_EDGES + e0 + i] >> 8], 1);
    __syncthreads();
    if (t == 0){
        int run = 0;
        for (int b = 0; b < FILL_NB; b++){ lstart[b] = run; run += cnt[b]; }
    }
    __syncthreads();
    for (int i = t; i < FILL_NB; i += 256) lcur[i] = lstart[i];
    __syncthreads();
    for (int i = t; i < n; i += 256){
        int e = e0 + i;
        int d = eidx[N_EDGES + e];
        int s = eidx[e];
        int a = eattr[e];
        int xi = x_idx[s];
        unsigned w = (unsigned)s | ((unsigned)a << 17) | ((unsigned)xi << 22);
        int pos = atomicAdd(&lcur[d >> 8], 1);
        stage[pos] = make_uint2(w, (unsigned)d);
    }
    __syncthreads();
    for (int b = t; b < FILL_NB; b += 256)
        if (cnt[b] > 0) gbase[b] = atomicAdd(&bcur[b], cnt[b]);
    __syncthreads();
    for (int i = t; i < n; i += 256){
        uint2 v = stage[i];
        int b = (int)(v.y >> 8);
        tmp[gbase[b] + (i - lstart[b])] = v;
    }
}

// pass B: one block per coarse bucket; fine scatter within the bucket's own CSR window
__global__ __launch_bounds__(256) void k_fillB(const uint2* __restrict__ tmp,
                        const int* __restrict__ row_ptr,
                        int* __restrict__ cursor, unsigned* __restrict__ pack){
    int b = blockIdx.x;
    int start = row_ptr[b * 256];
    int end   = row_ptr[min((b + 1) * 256, N_NODES)];
    for (int p = start + (int)threadIdx.x; p < end; p += 256){
        uint2 v = tmp[p];
        int pos = atomicAdd(&cursor[v.y], 1);
        pack[pos] = v.x;
    }
}

// ---------------- layer-0 message memo table ----------------

__global__ void k_combo(const float* __restrict__ node_emb, const float* __restrict__ edge_emb0,
                        float* __restrict__ combo){
    int i = blockIdx.x * 256 + threadIdx.x;          // over 2000*128
    if (i >= 2000 * NHID) return;
    int row = i >> 7, c = i & 127;
    int ni = row / 20, a = row - ni * 20;
    combo[i] = fmaxf(node_emb[ni * NHID + c] + edge_emb0[a * NHID + c], 0.f);
}

// ---------------- W^T split tables: [which][layer][col][k] bf16 hi/lo ----------------

__global__ void k_wsplit(const float* __restrict__ w1, const float* __restrict__ w2,
                         unsigned short* __restrict__ wth, unsigned short* __restrict__ wtl){
    int i = blockIdx.x * 256 + threadIdx.x;          // 2*4*128*128 = 131072
    int which = i >> 16;
    int m = (i >> 14) & 3;
    int r = i & 16383;
    int k = r >> 7, c = r & 127;
    float v = (which ? w2 : w1)[m * 16384 + k * 128 + c];
    unsigned short h, l;
    bsplit(v, h, l);
    int o = ((which * 4 + m) * 128 + c) * 128 + k;   // transposed: [col][k]
    wth[o] = h; wtl[o] = l;
}

// ---------------- node embedding init ----------------

__global__ void k_initx(const int* __restrict__ x_idx, const float* __restrict__ node_emb,
                        float4* __restrict__ x4){
    int i = blockIdx.x * 256 + threadIdx.x;          // over N*32 float4s
    if (i >= N_NODES * 32) return;
    int n = i >> 5, c = i & 31;
    int id = x_idx[n];
    x4[i] = ((const float4*)node_emb)[id * 32 + c];
}

// ----- aggregation (layers 1-3): h0[n] = x[n] + sum relu(bf16(x[src]) + emb[attr]) -----

__global__ __launch_bounds__(256) void k_agg(const float* __restrict__ x,
                      const ushort2* __restrict__ xb,
                      const int* __restrict__ row_ptr,
                      const unsigned* __restrict__ pack, const float* __restrict__ emb_l,
                      float2* __restrict__ h0){
    int gid = blockIdx.x * 256 + threadIdx.x;
    int node = gid >> 6;
    int lane = threadIdx.x & 63;
    const float2* x2 = (const float2*)x;
    const float2* e2 = (const float2*)emb_l;
    float2 acc = x2[node * 64 + lane];
    int beg = row_ptr[node], end = row_ptr[node + 1];
    int i = beg;
    for (; i + 3 < end; i += 4){
        unsigned p0 = pack[i], p1 = pack[i+1], p2 = pack[i+2], p3 = pack[i+3];
        ushort2 g0 = xb[(p0 & 0x1FFFFu) * 64 + lane];
        ushort2 g1 = xb[(p1 & 0x1FFFFu) * 64 + lane];
        ushort2 g2 = xb[(p2 & 0x1FFFFu) * 64 + lane];
        ushort2 g3 = xb[(p3 & 0x1FFFFu) * 64 + lane];
        float2 b0 = e2[((p0 >> 17) & 31u) * 64 + lane];
        float2 b1 = e2[((p1 >> 17) & 31u) * 64 + lane];
        float2 b2 = e2[((p2 >> 17) & 31u) * 64 + lane];
        float2 b3 = e2[((p3 >> 17) & 31u) * 64 + lane];
        acc.x += (fmaxf(b2f(g0.x) + b0.x, 0.f) + fmaxf(b2f(g1.x) + b1.x, 0.f))
               + (fmaxf(b2f(g2.x) + b2.x, 0.f) + fmaxf(b2f(g3.x) + b3.x, 0.f));
        acc.y += (fmaxf(b2f(g0.y) + b0.y, 0.f) + fmaxf(b2f(g1.y) + b1.y, 0.f))
               + (fmaxf(b2f(g2.y) + b2.y, 0.f) + fmaxf(b2f(g3.y) + b3.y, 0.f));
    }
    for (; i < end; i++){
        unsigned p = pack[i];
        ushort2 g = xb[(p & 0x1FFFFu) * 64 + lane];
        float2 ev = e2[((p >> 17) & 31u) * 64 + lane];
        acc.x += fmaxf(b2f(g.x) + ev.x, 0.f);
        acc.y += fmaxf(b2f(g.y) + ev.y, 0.f);
    }
    h0[node * 64 + lane] = acc;
}

// ---------------- aggregation (layer 0): memo table ----------------

__global__ __launch_bounds__(256) void k_agg0(const float* __restrict__ x,
                      const int* __restrict__ row_ptr,
                      const unsigned* __restrict__ pack,
                      const float* __restrict__ combo,
                      float2* __restrict__ h0){
    int gid = blockIdx.x * 256 + threadIdx.x;
    int node = gid >> 6;
    int lane = threadIdx.x & 63;
    const float2* x2 = (const float2*)x;
    const float2* c2 = (const float2*)combo;
    float2 acc = x2[node * 64 + lane];
    int beg = row_ptr[node], end = row_ptr[node + 1];
    int i = beg;
    for (; i + 3 < end; i += 4){
        unsigned p0 = pack[i], p1 = pack[i+1], p2 = pack[i+2], p3 = pack[i+3];
        int ci0 = (int)((p0 >> 22) & 127u) * 20 + (int)((p0 >> 17) & 31u);
        int ci1 = (int)((p1 >> 22) & 127u) * 20 + (int)((p1 >> 17) & 31u);
        int ci2 = (int)((p2 >> 22) & 127u) * 20 + (int)((p2 >> 17) & 31u);
        int ci3 = (int)((p3 >> 22) & 127u) * 20 + (int)((p3 >> 17) & 31u);
        float2 m0 = c2[ci0 * 64 + lane];
        float2 m1 = c2[ci1 * 64 + lane];
        float2 m2 = c2[ci2 * 64 + lane];
        float2 m3 = c2[ci3 * 64 + lane];
        acc.x += (m0.x + m1.x) + (m2.x + m3.x);
        acc.y += (m0.y + m1.y) + (m2.y + m3.y);
    }
    for (; i < end; i++){
        unsigned p = pack[i];
        int ci = (int)((p >> 22) & 127u) * 20 + (int)((p >> 17) & 31u);
        float2 m = c2[ci * 64 + lane];
        acc.x += m.x;
        acc.y += m.y;
    }
    h0[node * 64 + lane] = acc;
}

// ---- split-bf16 MFMA GEMM: C(128x128) = A(128x128) @ W, via Ah@Wh + Ah@Wl + Al@Wh ----

template<int RELU_OUT, int DO_STATS>
__global__ __launch_bounds__(256) void k_mfma(const float* __restrict__ A,
                                              const unsigned short* __restrict__ Wth,
                                              const unsigned short* __restrict__ Wtl,
                                              float* __restrict__ out,
                                              float* __restrict__ stats_l){
    __shared__ unsigned short Ah[128][40], Al[128][40];   // 80 B pitch: 2-way banks only
    __shared__ unsigned short Bh[128][40], Bl[128][40];   // W^T chunk [col][k]
    const int tid = threadIdx.x;
    const int w = tid >> 6;          // wave 0..3 -> rows [w*32, w*32+32)
    const int l = tid & 63;
    const int lr = l & 15;           // fragment row/col index
    const int lk = l >> 4;           // k-group
    const int row0 = blockIdx.x * 128;

    f32x4 acc[2][8];
    #pragma unroll
    for (int m = 0; m < 2; m++)
        #pragma unroll
        for (int n = 0; n < 8; n++) acc[m][n] = (f32x4)(0.f);

    for (int kc = 0; kc < 4; kc++){
        __syncthreads();
        // stage A chunk: 128 rows x 32 k fp32 -> bf16 hi/lo
        #pragma unroll
        for (int q = 0; q < 4; q++){
            int f = tid + 256 * q;                 // 1024 float4s
            int r = f >> 3, kq = f & 7;
            int gr = row0 + r;
            float4 v = make_float4(0.f, 0.f, 0.f, 0.f);
            if (gr < N_NODES) v = ld4(A + (size_t)gr * NHID + kc * 32 + kq * 4);
            unsigned short h0,l0,h1,l1,h2,l2,h3,l3;
            bsplit(v.x, h0, l0); bsplit(v.y, h1, l1);
            bsplit(v.z, h2, l2); bsplit(v.w, h3, l3);
            *(ushort4*)&Ah[r][kq * 4] = make_ushort4(h0, h1, h2, h3);
            *(ushort4*)&Al[r][kq * 4] = make_ushort4(l0, l1, l2, l3);
        }
        // stage W^T chunk: 128 cols x 32 k bf16 hi/lo (already transposed in global)
        #pragma unroll
        for (int q = 0; q < 2; q++){
            int f = tid + 256 * q;                 // 512 16B loads
            int c = f >> 2, kq = f & 3;
            size_t gi = (size_t)c * 128 + kc * 32 + kq * 8;
            *(uint4*)&Bh[c][kq * 8] = *(const uint4*)(Wth + gi);
            *(uint4*)&Bl[c][kq * 8] = *(const uint4*)(Wtl + gi);
        }
        __syncthreads();
        // fragments: A row = w*32 + m*16 + lr, k = lk*8..+8 (contiguous)
        short8v pah[2], pal[2];
        #pragma unroll
        for (int m = 0; m < 2; m++){
            pah[m] = *(const short8v*)&Ah[w * 32 + m * 16 + lr][lk * 8];
            pal[m] = *(const short8v*)&Al[w * 32 + m * 16 + lr][lk * 8];
        }
        #pragma unroll
        for (int n = 0; n < 8; n++){
            short8v pbh = *(const short8v*)&Bh[n * 16 + lr][lk * 8];
            short8v pbl = *(const short8v*)&Bl[n * 16 + lr][lk * 8];
            #pragma unroll
            for (int m = 0; m < 2; m++){
                acc[m][n] = __builtin_amdgcn_mfma_f32_16x16x32_bf16(pal[m], pbh, acc[m][n], 0, 0, 0);
                acc[m][n] = __builtin_amdgcn_mfma_f32_16x16x32_bf16(pah[m], pbl, acc[m][n], 0, 0, 0);
                acc[m][n] = __builtin_amdgcn_mfma_f32_16x16x32_bf16(pah[m], pbh, acc[m][n], 0, 0, 0);
            }
        }
    }

    if (RELU_OUT){
        #pragma unroll
        for (int m = 0; m < 2; m++)
            #pragma unroll
            for (int n = 0; n < 8; n++)
                #pragma unroll
                for (int j = 0; j < 4; j++) acc[m][n][j] = fmaxf(acc[m][n][j], 0.f);
    }
    // store: C row = row0 + w*32 + m*16 + lk*4 + j, col = n*16 + lr
    #pragma unroll
    for (int m = 0; m < 2; m++)
        #pragma unroll
        for (int j = 0; j < 4; j++){
            int gr = row0 + w * 32 + m * 16 + lk * 4 + j;
            if (gr < N_NODES){
                #pragma unroll
                for (int n = 0; n < 8; n++)
                    out[(size_t)gr * NHID + n * 16 + lr] = acc[m][n][j];
            }
        }

    if (DO_STATS){
        __syncthreads();                       // all LDS frag reads complete
        float* red  = (float*)&Ah[0][0];       // [16][128] col sums
        float* red2 = (float*)&Bh[0][0];       // [16][128] col sumsq
        #pragma unroll
        for (int n = 0; n < 8; n++){
            float s = 0.f, q = 0.f;
            #pragma unroll
            for (int m = 0; m < 2; m++)
                #pragma unroll
                for (int j = 0; j < 4; j++){ float v = acc[m][n][j]; s += v; q += v * v; }
            red [(w * 4 + lk) * 128 + n * 16 + lr] = s;
            red2[(w * 4 + lk) * 128 + n * 16 + lr] = q;
        }
        __syncthreads();
        if (tid < 128){
            float s = 0.f, q = 0.f;
            #pragma unroll
            for (int r2 = 0; r2 < 16; r2++){
                s += red[r2 * 128 + tid];
                q += red2[r2 * 128 + tid];
            }
            atomicAdd(&stats_l[tid], s);
            atomicAdd(&stats_l[128 + tid], q);
        }
    }
}

// -------- normalize + relu + residual; also emit bf16 shadow copy of x for gathers --------

__global__ void k_norm(const float4* __restrict__ h2, float4* __restrict__ x,
                       ushort4* __restrict__ xb,
                       const float* __restrict__ stats_l,
                       const float* __restrict__ gamma, const float* __restrict__ beta){
    int i = blockIdx.x * 256 + threadIdx.x;
    if (i >= N_NODES * 32) return;
    int g = (i & 31);
    float4 sv = ((const float4*)stats_l)[g];
    float4 qv = ((const float4*)(stats_l + 128))[g];
    float4 gm = ((const float4*)gamma)[g];
    float4 bt = ((const float4*)beta)[g];
    float4 ca, cb;
    {
        float mu, var;
        mu = sv.x * (1.f / N_NODES); var = qv.x * (1.f / N_NODES) - mu * mu;
        ca.x = gm.x * rsqrtf(var + BN_EPS); cb.x = bt.x - mu * ca.x;
        mu = sv.y * (1.f / N_NODES); var = qv.y * (1.f / N_NODES) - mu * mu;
        ca.y = gm.y * rsqrtf(var + BN_EPS); cb.y = bt.y - mu * ca.y;
        mu = sv.z * (1.f / N_NODES); var = qv.z * (1.f / N_NODES) - mu * mu;
        ca.z = gm.z * rsqrtf(var + BN_EPS); cb.z = bt.z - mu * ca.z;
        mu = sv.w * (1.f / N_NODES); var = qv.w * (1.f / N_NODES) - mu * mu;
        ca.w = gm.w * rsqrtf(var + BN_EPS); cb.w = bt.w - mu * ca.w;
    }
    float4 h = h2[i];
    float4 xv = x[i];
    float4 r;
    r.x = fmaxf(fmaf(h.x, ca.x, cb.x), 0.f) + xv.x;
    r.y = fmaxf(fmaf(h.y, ca.y, cb.y), 0.f) + xv.y;
    r.z = fmaxf(fmaf(h.z, ca.z, cb.z), 0.f) + xv.z;
    r.w = fmaxf(fmaf(h.w, ca.w, cb.w), 0.f) + xv.w;
    x[i] = r;
    xb[i] = make_ushort4(brne(r.x), brne(r.y), brne(r.z), brne(r.w));
}

// ---------------- pooling ----------------

__global__ void k_pool(const float* __restrict__ x, const int* __restrict__ batch,
                       float* __restrict__ gbuf){
    int g = blockIdx.x;
    int lo = 0, hi = N_NODES;
    while (lo < hi){ int mid = (lo + hi) >> 1; if (batch[mid] < g) lo = mid + 1; else hi = mid; }
    int start = lo;
    hi = N_NODES;
    while (lo < hi){ int mid = (lo + hi) >> 1; if (batch[mid] < g + 1) lo = mid + 1; else hi = mid; }
    int end = lo;
    int c = threadIdx.x & 127;
    int half = threadIdx.x >> 7;
    float acc = 0.f;
    for (int n = start + half; n < end; n += 2) acc += x[n * NHID + c];
    __shared__ float s[256];
    s[threadIdx.x] = acc;
    __syncthreads();
    if (threadIdx.x < 128) gbuf[g * NHID + threadIdx.x] = s[threadIdx.x] + s[threadIdx.x + 128];
}

// ---------------- output head ----------------

__global__ __launch_bounds__(128) void k_head1(const float* __restrict__ gbuf,
                                               const float* __restrict__ w1,
                                               const float* __restrict__ b1,
                                               float* __restrict__ o1){
    __shared__ float gs[128];
    int i = blockIdx.x;
    int j = threadIdx.x;
    gs[j] = gbuf[i * NHID + j];
    __syncthreads();
    float acc = 0.f;
    #pragma unroll 8
    for (int k = 0; k < 128; k++)
        acc = fmaf(gs[k], w1[k * NHID + j], acc);
    o1[i * NHID + j] = acc + b1[j];
}

__global__ __launch_bounds__(128) void k_head2(const float* __restrict__ o1,
                                               const float* __restrict__ gamma,
                                               const float* __restrict__ beta,
                                               const float* __restrict__ w2,
                                               const float* __restrict__ b2,
                                               float* __restrict__ out){
    __shared__ float s_o1[128][129];
    __shared__ float sa[128], sb[128];
    int t = threadIdx.x;
    float s = 0.f, q = 0.f;
    for (int r = 0; r < 128; r++){
        float v = o1[r * NHID + t];
        s_o1[r][t] = v;
        s += v; q += v * v;
    }
    float mu = s * (1.f / 128.f);
    float rs = rsqrtf(q * (1.f / 128.f) - mu * mu + BN_EPS);
    float a = gamma[t] * rs;
    sa[t] = a;
    sb[t] = beta[t] - mu * a;
    __syncthreads();
    float a2 = 0.f;
    #pragma unroll 8
    for (int j = 0; j < 128; j++){
        float v = fmaf(s_o1[t][j], sa[j], sb[j]);
        a2 += fmaxf(v, 0.f) * w2[j];
    }
    out[t] = a2 + b2[0];
}

// ---------------- launch ----------------

extern "C" void kernel_launch(void* const* d_in, const int* in_sizes, int n_in,
                              void* d_out, int out_size, void* d_ws, size_t ws_size,
                              hipStream_t stream){
    const int*   x_idx    = (const int*)d_in[0];
    const int*   eidx     = (const int*)d_in[1];
    const int*   eattr    = (const int*)d_in[2];
    const int*   batch    = (const int*)d_in[3];
    const float* node_emb = (const float*)d_in[4];
    const float* edge_emb = (const float*)d_in[5];
    const float* conv_w1  = (const float*)d_in[6];
    const float* conv_w2  = (const float*)d_in[7];
    const float* bn_gamma = (const float*)d_in[8];
    const float* bn_beta  = (const float*)d_in[9];
    const float* out_w1   = (const float*)d_in[10];
    const float* out_b1   = (const float*)d_in[11];
    const float* out_bng  = (const float*)d_in[12];
    const float* out_bnb  = (const float*)d_in[13];
    const float* out_w2   = (const float*)d_in[14];
    const float* out_b2   = (const float*)d_in[15];
    float* out = (float*)d_out;

    char* base = (char*)d_ws;
    size_t off = 0;
    auto alloc = [&](size_t bytes) -> char* {
        char* r = base + off;
        off = (off + bytes + 255) & ~(size_t)255;
        return r;
    };
    float*          xbuf    = (float*)alloc((size_t)N_NODES * NHID * 4);   // 51.2 MB
    float*          h0buf   = (float*)alloc((size_t)N_NODES * NHID * 4);   // 51.2 MB
    unsigned short* xbf     = (unsigned short*)alloc((size_t)N_NODES * NHID * 2); // 25.6 MB
    int*            row_ptr = (int*)alloc((size_t)(N_NODES + 1) * 4);
    int*            cursor  = (int*)alloc((size_t)N_NODES * 4);
    int*            counts  = (int*)alloc((size_t)N_NODES * 4);
    int*            partial = (int*)alloc(512 * 4);
    int*            bcur    = (int*)alloc((size_t)FILL_NB * 4);
    unsigned*       pack    = (unsigned*)alloc((size_t)N_EDGES * 4);       // 6.4 MB
    uint2*          tmp     = (uint2*)alloc((size_t)N_EDGES * 8);          // 12.8 MB
    float*          combo   = (float*)alloc((size_t)2000 * NHID * 4);      // 1.0 MB
    unsigned short* wth     = (unsigned short*)alloc((size_t)8 * 16384 * 2); // 256 KB
    unsigned short* wtl     = (unsigned short*)alloc((size_t)8 * 16384 * 2); // 256 KB
    float*          stats   = (float*)alloc(NLAYER * 256 * 4);
    float*          gbuf    = (float*)alloc((size_t)N_GRAPHS * NHID * 4);
    float*          o1buf   = (float*)alloc((size_t)N_GRAPHS * NHID * 4);
    (void)ws_size; (void)in_sizes; (void)n_in; (void)out_size;

    hipMemsetAsync(counts, 0, (size_t)N_NODES * 4, stream);
    hipMemsetAsync(stats, 0, NLAYER * 256 * 4, stream);

    // CSR build (edges grouped by dst): hist -> scan -> two-phase bucketed fill
    k_hist<<<N_EDGES / 256, 256, 0, stream>>>(eidx + N_EDGES, counts);
    k_scan_partial<<<SCAN_NB, 256, 0, stream>>>(counts, partial);
    k_scan_top<<<1, 128, 0, stream>>>(partial, SCAN_NB, row_ptr);
    k_scan_final<<<SCAN_NB, 256, 0, stream>>>(counts, partial, row_ptr);
    hipMemcpyAsync(cursor, row_ptr, (size_t)N_NODES * 4, hipMemcpyDeviceToDevice, stream);
    k_binit<<<(FILL_NB + 255) / 256, 256, 0, stream>>>(row_ptr, bcur);
    k_fillA<<<(N_EDGES + FILL_CHUNK - 1) / FILL_CHUNK, 256, 0, stream>>>(
        eidx, eattr, x_idx, bcur, tmp);
    k_fillB<<<FILL_NB, 256, 0, stream>>>(tmp, row_ptr, cursor, pack);

    // per-call precomputes
    k_combo<<<(2000 * NHID) / 256, 256, 0, stream>>>(node_emb, edge_emb, combo);
    k_wsplit<<<131072 / 256, 256, 0, stream>>>(conv_w1, conv_w2, wth, wtl);
    k_initx<<<(N_NODES * 32) / 256, 256, 0, stream>>>(x_idx, node_emb, (float4*)xbuf);

    const int gemm_grid = (N_NODES + 127) / 128;     // 782
    for (int l = 0; l < NLAYER; l++){
        if (l == 0){
            k_agg0<<<(N_NODES * 64) / 256, 256, 0, stream>>>(
                xbuf, row_ptr, pack, combo, (float2*)h0buf);
        } else {
            k_agg<<<(N_NODES * 64) / 256, 256, 0, stream>>>(
                xbuf, (const ushort2*)xbf, row_ptr, pack,
                edge_emb + (size_t)l * 20 * NHID, (float2*)h0buf);
        }
        // t = relu(h0 @ w1)   (in place, split-bf16 MFMA)
        k_mfma<1, 0><<<gemm_grid, 256, 0, stream>>>(
            h0buf, wth + (size_t)l * 16384, wtl + (size_t)l * 16384, h0buf, nullptr);
        // h2 = t @ w2 (+ BN stats)   (in place)
        k_mfma<0, 1><<<gemm_grid, 256, 0, stream>>>(
            h0buf, wth + (size_t)(4 + l) * 16384, wtl + (size_t)(4 + l) * 16384,
            h0buf, stats + l * 256);
        k_norm<<<(N_NODES * 32) / 256, 256, 0, stream>>>(
            (const float4*)h0buf, (float4*)xbuf, (ushort4*)xbf, stats + l * 256,
            bn_gamma + l * NHID, bn_beta + l * NHID);
    }

    k_pool<<<N_GRAPHS, 256, 0, stream>>>(xbuf, batch, gbuf);
    k_head1<<<N_GRAPHS, 128, 0, stream>>>(gbuf, out_w1, out_b1, o1buf);
    k_head2<<<1, 128, 0, stream>>>(o1buf, out_bng, out_bnb, out_w2, out_b2, out);
}

// Round 12
// 1011.120 us; speedup vs baseline: 1.5153x; 1.0910x over previous
//
#include <hip/hip_runtime.h>

#define N_NODES 100000
#define N_EDGES 1600000
#define N_GRAPHS 128
#define NHID 128
#define NLAYER 4
#define BN_EPS 1e-5f

#define SCAN_ITEMS 1024
#define SCAN_NB ((N_NODES + SCAN_ITEMS - 1) / SCAN_ITEMS)   // 98

#define FILL_CHUNK 8192
#define FILL_NB ((N_NODES + 255) / 256)                      // 391 coarse buckets (256 nodes)

__device__ __forceinline__ float4 ld4(const float* p){ return *(const float4*)p; }
__device__ __forceinline__ void st4(float* p, float4 v){ *(float4*)p = v; }

typedef __attribute__((ext_vector_type(8))) short short8v;   // 8 bf16 = 4 VGPR
typedef __attribute__((ext_vector_type(4))) float f32x4;     // MFMA acc

// split fp32 -> bf16 hi (truncate) + bf16 lo (truncate of residual)
__device__ __forceinline__ void bsplit(float a, unsigned short& h, unsigned short& l){
    unsigned ab = __float_as_uint(a);
    h = (unsigned short)(ab >> 16);
    float hf = __uint_as_float((unsigned)h << 16);
    l = (unsigned short)(__float_as_uint(a - hf) >> 16);
}

// fp32 -> bf16 round-to-nearest-even
__device__ __forceinline__ unsigned short brne(float a){
    unsigned ab = __float_as_uint(a);
    return (unsigned short)((ab + 0x7FFFu + ((ab >> 16) & 1u)) >> 16);
}
__device__ __forceinline__ float b2f(unsigned short b){
    return __uint_as_float((unsigned)b << 16);
}

// ---------------- CSR build ----------------

__global__ void k_hist(const int* __restrict__ dst, int* __restrict__ counts){
    int e = blockIdx.x * 256 + threadIdx.x;
    if (e < N_EDGES) atomicAdd(&counts[dst[e]], 1);
}

__global__ void k_scan_partial(const int* __restrict__ counts, int* __restrict__ partial){
    __shared__ int s[256];
    int t = threadIdx.x;
    int base = blockIdx.x * SCAN_ITEMS + t * 4;
    int v = 0;
    #pragma unroll
    for (int k = 0; k < 4; k++) if (base + k < N_NODES) v += counts[base + k];
    s[t] = v;
    __syncthreads();
    for (int o = 128; o > 0; o >>= 1){
        if (t < o) s[t] += s[t + o];
        __syncthreads();
    }
    if (t == 0) partial[blockIdx.x] = s[0];
}

__global__ void k_scan_top(int* __restrict__ partial, int nb, int* __restrict__ row_ptr){
    __shared__ int s[128];
    int t = threadIdx.x;
    int v = (t < nb) ? partial[t] : 0;
    s[t] = v;
    __syncthreads();
    for (int d = 1; d < 128; d <<= 1){
        int add = (t >= d) ? s[t - d] : 0;
        __syncthreads();
        s[t] += add;
        __syncthreads();
    }
    if (t < nb) partial[t] = s[t] - v;           // exclusive
    if (t == 0) row_ptr[N_NODES] = N_EDGES;
}

__global__ void k_scan_final(const int* __restrict__ counts, const int* __restrict__ partial,
                             int* __restrict__ row_ptr){
    __shared__ int s[256];
    int t = threadIdx.x;
    int base = blockIdx.x * SCAN_ITEMS + t * 4;
    int v[4]; int tsum = 0;
    #pragma unroll
    for (int k = 0; k < 4; k++){ v[k] = (base + k < N_NODES) ? counts[base + k] : 0; tsum += v[k]; }
    s[t] = tsum;
    __syncthreads();
    for (int d = 1; d < 256; d <<= 1){
        int add = (t >= d) ? s[t - d] : 0;
        __syncthreads();
        s[t] += add;
        __syncthreads();
    }
    int off = partial[blockIdx.x] + s[t] - tsum;  // exclusive prefix for this thread
    #pragma unroll
    for (int k = 0; k < 4; k++){
        if (base + k < N_NODES) row_ptr[base + k] = off;
        off += v[k];
    }
}

// bucket cursors init from row_ptr at 256-node granularity
__global__ void k_binit(const int* __restrict__ row_ptr, int* __restrict__ bcur){
    int b = blockIdx.x * 256 + threadIdx.x;
    if (b < FILL_NB) bcur[b] = row_ptr[b * 256];
}

// pass A: LDS-binned coarse bucket sort -> tmp {packword, dst}, run-length XCD-local writes
__global__ __launch_bounds__(256) void k_fillA(const int* __restrict__ eidx,
                        const int* __restrict__ eattr, const int* __restrict__ x_idx,
                        int* __restrict__ bcur, uint2* __restrict__ tmp){
    __shared__ int cnt[FILL_NB];
    __shared__ int lstart[FILL_NB];
    __shared__ int lcur[FILL_NB];
    __shared__ int gbase[FILL_NB];
    __shared__ uint2 stage[FILL_CHUNK];              // 64 KB
    int t = threadIdx.x;
    int e0 = blockIdx.x * FILL_CHUNK;
    int n = min(FILL_CHUNK, N_EDGES - e0);
    for (int i = t; i < FILL_NB; i += 256) cnt[i] = 0;
    __syncthreads();
    for (int i = t; i < n; i += 256)
        atomicAdd(&cnt[(unsigned)eidx[N_EDGES + e0 + i] >> 8], 1);
    __syncthreads();
    if (t == 0){
        int run = 0;
        for (int b = 0; b < FILL_NB; b++){ lstart[b] = run; run += cnt[b]; }
    }
    __syncthreads();
    for (int i = t; i < FILL_NB; i += 256) lcur[i] = lstart[i];
    __syncthreads();
    for (int i = t; i < n; i += 256){
        int e = e0 + i;
        int d = eidx[N_EDGES + e];
        int s = eidx[e];
        int a = eattr[e];
        int xi = x_idx[s];
        unsigned w = (unsigned)s | ((unsigned)a << 17) | ((unsigned)xi << 22);
        int pos = atomicAdd(&lcur[d >> 8], 1);
        stage[pos] = make_uint2(w, (unsigned)d);
    }
    __syncthreads();
    for (int b = t; b < FILL_NB; b += 256)
        if (cnt[b] > 0) gbase[b] = atomicAdd(&bcur[b], cnt[b]);
    __syncthreads();
    for (int i = t; i < n; i += 256){
        uint2 v = stage[i];
        int b = (int)(v.y >> 8);
        tmp[gbase[b] + (i - lstart[b])] = v;
    }
}

// pass B: one block per coarse bucket; fine scatter within the bucket's own CSR window
__global__ __launch_bounds__(256) void k_fillB(const uint2* __restrict__ tmp,
                        const int* __restrict__ row_ptr,
                        int* __restrict__ cursor, unsigned* __restrict__ pack){
    int b = blockIdx.x;
    int start = row_ptr[b * 256];
    int end   = row_ptr[min((b + 1) * 256, N_NODES)];
    for (int p = start + (int)threadIdx.x; p < end; p += 256){
        uint2 v = tmp[p];
        int pos = atomicAdd(&cursor[v.y], 1);
        pack[pos] = v.x;
    }
}

// ---------------- layer-0 message memo table ----------------

__global__ void k_combo(const float* __restrict__ node_emb, const float* __restrict__ edge_emb0,
                        float* __restrict__ combo){
    int i = blockIdx.x * 256 + threadIdx.x;          // over 2000*128
    if (i >= 2000 * NHID) return;
    int row = i >> 7, c = i & 127;
    int ni = row / 20, a = row - ni * 20;
    combo[i] = fmaxf(node_emb[ni * NHID + c] + edge_emb0[a * NHID + c], 0.f);
}

// ---------------- W^T split tables: [which][layer][col][k] bf16 hi/lo ----------------

__global__ void k_wsplit(const float* __restrict__ w1, const float* __restrict__ w2,
                         unsigned short* __restrict__ wth, unsigned short* __restrict__ wtl){
    int i = blockIdx.x * 256 + threadIdx.x;          // 2*4*128*128 = 131072
    int which = i >> 16;
    int m = (i >> 14) & 3;
    int r = i & 16383;
    int k = r >> 7, c = r & 127;
    float v = (which ? w2 : w1)[m * 16384 + k * 128 + c];
    unsigned short h, l;
    bsplit(v, h, l);
    int o = ((which * 4 + m) * 128 + c) * 128 + k;   // transposed: [col][k]
    wth[o] = h; wtl[o] = l;
}

// ---------------- node embedding init ----------------

__global__ void k_initx(const int* __restrict__ x_idx, const float* __restrict__ node_emb,
                        float4* __restrict__ x4){
    int i = blockIdx.x * 256 + threadIdx.x;          // over N*32 float4s
    if (i >= N_NODES * 32) return;
    int n = i >> 5, c = i & 31;
    int id = x_idx[n];
    x4[i] = ((const float4*)node_emb)[id * 32 + c];
}

// ----- aggregation (layers 1-3): h0[n] = x[n] + sum relu(bf16(x[src]) + emb[attr]) -----

__global__ __launch_bounds__(256) void k_agg(const float* __restrict__ x,
                      const ushort2* __restrict__ xb,
                      const int* __restrict__ row_ptr,
                      const unsigned* __restrict__ pack, const float* __restrict__ emb_l,
                      float2* __restrict__ h0){
    int gid = blockIdx.x * 256 + threadIdx.x;
    int node = gid >> 6;
    int lane = threadIdx.x & 63;
    const float2* x2 = (const float2*)x;
    const float2* e2 = (const float2*)emb_l;
    float2 acc = x2[node * 64 + lane];
    int beg = row_ptr[node], end = row_ptr[node + 1];
    int i = beg;
    for (; i + 3 < end; i += 4){
        unsigned p0 = pack[i], p1 = pack[i+1], p2 = pack[i+2], p3 = pack[i+3];
        ushort2 g0 = xb[(p0 & 0x1FFFFu) * 64 + lane];
        ushort2 g1 = xb[(p1 & 0x1FFFFu) * 64 + lane];
        ushort2 g2 = xb[(p2 & 0x1FFFFu) * 64 + lane];
        ushort2 g3 = xb[(p3 & 0x1FFFFu) * 64 + lane];
        float2 b0 = e2[((p0 >> 17) & 31u) * 64 + lane];
        float2 b1 = e2[((p1 >> 17) & 31u) * 64 + lane];
        float2 b2 = e2[((p2 >> 17) & 31u) * 64 + lane];
        float2 b3 = e2[((p3 >> 17) & 31u) * 64 + lane];
        acc.x += (fmaxf(b2f(g0.x) + b0.x, 0.f) + fmaxf(b2f(g1.x) + b1.x, 0.f))
               + (fmaxf(b2f(g2.x) + b2.x, 0.f) + fmaxf(b2f(g3.x) + b3.x, 0.f));
        acc.y += (fmaxf(b2f(g0.y) + b0.y, 0.f) + fmaxf(b2f(g1.y) + b1.y, 0.f))
               + (fmaxf(b2f(g2.y) + b2.y, 0.f) + fmaxf(b2f(g3.y) + b3.y, 0.f));
    }
    for (; i < end; i++){
        unsigned p = pack[i];
        ushort2 g = xb[(p & 0x1FFFFu) * 64 + lane];
        float2 ev = e2[((p >> 17) & 31u) * 64 + lane];
        acc.x += fmaxf(b2f(g.x) + ev.x, 0.f);
        acc.y += fmaxf(b2f(g.y) + ev.y, 0.f);
    }
    h0[node * 64 + lane] = acc;
}

// ---------------- aggregation (layer 0): memo table ----------------

__global__ __launch_bounds__(256) void k_agg0(const float* __restrict__ x,
                      const int* __restrict__ row_ptr,
                      const unsigned* __restrict__ pack,
                      const float* __restrict__ combo,
                      float2* __restrict__ h0){
    int gid = blockIdx.x * 256 + threadIdx.x;
    int node = gid >> 6;
    int lane = threadIdx.x & 63;
    const float2* x2 = (const float2*)x;
    const float2* c2 = (const float2*)combo;
    float2 acc = x2[node * 64 + lane];
    int beg = row_ptr[node], end = row_ptr[node + 1];
    int i = beg;
    for (; i + 3 < end; i += 4){
        unsigned p0 = pack[i], p1 = pack[i+1], p2 = pack[i+2], p3 = pack[i+3];
        int ci0 = (int)((p0 >> 22) & 127u) * 20 + (int)((p0 >> 17) & 31u);
        int ci1 = (int)((p1 >> 22) & 127u) * 20 + (int)((p1 >> 17) & 31u);
        int ci2 = (int)((p2 >> 22) & 127u) * 20 + (int)((p2 >> 17) & 31u);
        int ci3 = (int)((p3 >> 22) & 127u) * 20 + (int)((p3 >> 17) & 31u);
        float2 m0 = c2[ci0 * 64 + lane];
        float2 m1 = c2[ci1 * 64 + lane];
        float2 m2 = c2[ci2 * 64 + lane];
        float2 m3 = c2[ci3 * 64 + lane];
        acc.x += (m0.x + m1.x) + (m2.x + m3.x);
        acc.y += (m0.y + m1.y) + (m2.y + m3.y);
    }
    for (; i < end; i++){
        unsigned p = pack[i];
        int ci = (int)((p >> 22) & 127u) * 20 + (int)((p >> 17) & 31u);
        float2 m = c2[ci * 64 + lane];
        acc.x += m.x;
        acc.y += m.y;
    }
    h0[node * 64 + lane] = acc;
}

// ---- split-bf16 MFMA GEMM: C(128x128) = A(128x128) @ W, via Ah@Wh + Ah@Wl + Al@Wh ----

template<int RELU_OUT, int DO_STATS>
__global__ __launch_bounds__(256) void k_mfma(const float* __restrict__ A,
                                              const unsigned short* __restrict__ Wth,
                                              const unsigned short* __restrict__ Wtl,
                                              float* __restrict__ out,
                                              float* __restrict__ stats_l){
    __shared__ unsigned short Ah[128][40], Al[128][40];   // 80 B pitch: 2-way banks only
    __shared__ unsigned short Bh[128][40], Bl[128][40];   // W^T chunk [col][k]
    const int tid = threadIdx.x;
    const int w = tid >> 6;          // wave 0..3 -> rows [w*32, w*32+32)
    const int l = tid & 63;
    const int lr = l & 15;           // fragment row/col index
    const int lk = l >> 4;           // k-group
    const int row0 = blockIdx.x * 128;

    f32x4 acc[2][8];
    #pragma unroll
    for (int m = 0; m < 2; m++)
        #pragma unroll
        for (int n = 0; n < 8; n++) acc[m][n] = (f32x4)(0.f);

    for (int kc = 0; kc < 4; kc++){
        __syncthreads();
        // stage A chunk: 128 rows x 32 k fp32 -> bf16 hi/lo
        #pragma unroll
        for (int q = 0; q < 4; q++){
            int f = tid + 256 * q;                 // 1024 float4s
            int r = f >> 3, kq = f & 7;
            int gr = row0 + r;
            float4 v = make_float4(0.f, 0.f, 0.f, 0.f);
            if (gr < N_NODES) v = ld4(A + (size_t)gr * NHID + kc * 32 + kq * 4);
            unsigned short h0,l0,h1,l1,h2,l2,h3,l3;
            bsplit(v.x, h0, l0); bsplit(v.y, h1, l1);
            bsplit(v.z, h2, l2); bsplit(v.w, h3, l3);
            *(ushort4*)&Ah[r][kq * 4] = make_ushort4(h0, h1, h2, h3);
            *(ushort4*)&Al[r][kq * 4] = make_ushort4(l0, l1, l2, l3);
        }
        // stage W^T chunk: 128 cols x 32 k bf16 hi/lo (already transposed in global)
        #pragma unroll
        for (int q = 0; q < 2; q++){
            int f = tid + 256 * q;                 // 512 16B loads
            int c = f >> 2, kq = f & 3;
            size_t gi = (size_t)c * 128 + kc * 32 + kq * 8;
            *(uint4*)&Bh[c][kq * 8] = *(const uint4*)(Wth + gi);
            *(uint4*)&Bl[c][kq * 8] = *(const uint4*)(Wtl + gi);
        }
        __syncthreads();
        // fragments: A row = w*32 + m*16 + lr, k = lk*8..+8 (contiguous)
        short8v pah[2], pal[2];
        #pragma unroll
        for (int m = 0; m < 2; m++){
            pah[m] = *(const short8v*)&Ah[w * 32 + m * 16 + lr][lk * 8];
            pal[m] = *(const short8v*)&Al[w * 32 + m * 16 + lr][lk * 8];
        }
        #pragma unroll
        for (int n = 0; n < 8; n++){
            short8v pbh = *(const short8v*)&Bh[n * 16 + lr][lk * 8];
            short8v pbl = *(const short8v*)&Bl[n * 16 + lr][lk * 8];
            #pragma unroll
            for (int m = 0; m < 2; m++){
                acc[m][n] = __builtin_amdgcn_mfma_f32_16x16x32_bf16(pal[m], pbh, acc[m][n], 0, 0, 0);
                acc[m][n] = __builtin_amdgcn_mfma_f32_16x16x32_bf16(pah[m], pbl, acc[m][n], 0, 0, 0);
                acc[m][n] = __builtin_amdgcn_mfma_f32_16x16x32_bf16(pah[m], pbh, acc[m][n], 0, 0, 0);
            }
        }
    }

    if (RELU_OUT){
        #pragma unroll
        for (int m = 0; m < 2; m++)
            #pragma unroll
            for (int n = 0; n < 8; n++)
                #pragma unroll
                for (int j = 0; j < 4; j++) acc[m][n][j] = fmaxf(acc[m][n][j], 0.f);
    }
    // store: C row = row0 + w*32 + m*16 + lk*4 + j, col = n*16 + lr
    #pragma unroll
    for (int m = 0; m < 2; m++)
        #pragma unroll
        for (int j = 0; j < 4; j++){
            int gr = row0 + w * 32 + m * 16 + lk * 4 + j;
            if (gr < N_NODES){
                #pragma unroll
                for (int n = 0; n < 8; n++)
                    out[(size_t)gr * NHID + n * 16 + lr] = acc[m][n][j];
            }
        }

    if (DO_STATS){
        __syncthreads();                       // all LDS frag reads complete
        float* red  = (float*)&Ah[0][0];       // [16][128] col sums
        float* red2 = (float*)&Bh[0][0];       // [16][128] col sumsq
        #pragma unroll
        for (int n = 0; n < 8; n++){
            float s = 0.f, q = 0.f;
            #pragma unroll
            for (int m = 0; m < 2; m++)
                #pragma unroll
                for (int j = 0; j < 4; j++){ float v = acc[m][n][j]; s += v; q += v * v; }
            red [(w * 4 + lk) * 128 + n * 16 + lr] = s;
            red2[(w * 4 + lk) * 128 + n * 16 + lr] = q;
        }
        __syncthreads();
        if (tid < 128){
            float s = 0.f, q = 0.f;
            #pragma unroll
            for (int r2 = 0; r2 < 16; r2++){
                s += red[r2 * 128 + tid];
                q += red2[r2 * 128 + tid];
            }
            atomicAdd(&stats_l[tid], s);
            atomicAdd(&stats_l[128 + tid], q);
        }
    }
}

// -------- normalize + relu + residual; also emit bf16 shadow copy of x for gathers --------

__global__ void k_norm(const float4* __restrict__ h2, float4* __restrict__ x,
                       ushort4* __restrict__ xb,
                       const float* __restrict__ stats_l,
                       const float* __restrict__ gamma, const float* __restrict__ beta){
    int i = blockIdx.x * 256 + threadIdx.x;
    if (i >= N_NODES * 32) return;
    int g = (i & 31);
    float4 sv = ((const float4*)stats_l)[g];
    float4 qv = ((const float4*)(stats_l + 128))[g];
    float4 gm = ((const float4*)gamma)[g];
    float4 bt = ((const float4*)beta)[g];
    float4 ca, cb;
    {
        float mu, var;
        mu = sv.x * (1.f / N_NODES); var = qv.x * (1.f / N_NODES) - mu * mu;
        ca.x = gm.x * rsqrtf(var + BN_EPS); cb.x = bt.x - mu * ca.x;
        mu = sv.y * (1.f / N_NODES); var = qv.y * (1.f / N_NODES) - mu * mu;
        ca.y = gm.y * rsqrtf(var + BN_EPS); cb.y = bt.y - mu * ca.y;
        mu = sv.z * (1.f / N_NODES); var = qv.z * (1.f / N_NODES) - mu * mu;
        ca.z = gm.z * rsqrtf(var + BN_EPS); cb.z = bt.z - mu * ca.z;
        mu = sv.w * (1.f / N_NODES); var = qv.w * (1.f / N_NODES) - mu * mu;
        ca.w = gm.w * rsqrtf(var + BN_EPS); cb.w = bt.w - mu * ca.w;
    }
    float4 h = h2[i];
    float4 xv = x[i];
    float4 r;
    r.x = fmaxf(fmaf(h.x, ca.x, cb.x), 0.f) + xv.x;
    r.y = fmaxf(fmaf(h.y, ca.y, cb.y), 0.f) + xv.y;
    r.z = fmaxf(fmaf(h.z, ca.z, cb.z), 0.f) + xv.z;
    r.w = fmaxf(fmaf(h.w, ca.w, cb.w), 0.f) + xv.w;
    x[i] = r;
    xb[i] = make_ushort4(brne(r.x), brne(r.y), brne(r.z), brne(r.w));
}

// -------- pooling: chunked over nodes (batch sorted), per-run register accumulation --------

__global__ __launch_bounds__(256) void k_pool(const float* __restrict__ x,
                       const int* __restrict__ batch, float* __restrict__ gbuf){
    int c = threadIdx.x & 127;
    int half = threadIdx.x >> 7;
    int n0 = blockIdx.x * 128;
    int nend = min(n0 + 128, N_NODES);
    float acc = 0.f;
    int gcur = -1;
    for (int n = n0 + half; n < nend; n += 2){
        int g = batch[n];
        if (g != gcur){
            if (gcur >= 0) atomicAdd(&gbuf[gcur * NHID + c], acc);
            acc = 0.f; gcur = g;
        }
        acc += x[(size_t)n * NHID + c];
    }
    if (gcur >= 0) atomicAdd(&gbuf[gcur * NHID + c], acc);
}

// ---------------- output head ----------------

__global__ __launch_bounds__(128) void k_head1(const float* __restrict__ gbuf,
                                               const float* __restrict__ w1,
                                               const float* __restrict__ b1,
                                               float* __restrict__ o1){
    __shared__ float gs[128];
    int i = blockIdx.x;
    int j = threadIdx.x;
    gs[j] = gbuf[i * NHID + j];
    __syncthreads();
    float acc = 0.f;
    #pragma unroll 8
    for (int k = 0; k < 128; k++)
        acc = fmaf(gs[k], w1[k * NHID + j], acc);
    o1[i * NHID + j] = acc + b1[j];
}

__global__ __launch_bounds__(128) void k_head2(const float* __restrict__ o1,
                                               const float* __restrict__ gamma,
                                               const float* __restrict__ beta,
                                               const float* __restrict__ w2,
                                               const float* __restrict__ b2,
                                               float* __restrict__ out){
    __shared__ float s_o1[128][129];
    __shared__ float sa[128], sb[128];
    int t = threadIdx.x;
    float s = 0.f, q = 0.f;
    for (int r = 0; r < 128; r++){
        float v = o1[r * NHID + t];
        s_o1[r][t] = v;
        s += v; q += v * v;
    }
    float mu = s * (1.f / 128.f);
    float rs = rsqrtf(q * (1.f / 128.f) - mu * mu + BN_EPS);
    float a = gamma[t] * rs;
    sa[t] = a;
    sb[t] = beta[t] - mu * a;
    __syncthreads();
    float a2 = 0.f;
    #pragma unroll 8
    for (int j = 0; j < 128; j++){
        float v = fmaf(s_o1[t][j], sa[j], sb[j]);
        a2 += fmaxf(v, 0.f) * w2[j];
    }
    out[t] = a2 + b2[0];
}

// ---------------- launch ----------------

extern "C" void kernel_launch(void* const* d_in, const int* in_sizes, int n_in,
                              void* d_out, int out_size, void* d_ws, size_t ws_size,
                              hipStream_t stream){
    const int*   x_idx    = (const int*)d_in[0];
    const int*   eidx     = (const int*)d_in[1];
    const int*   eattr    = (const int*)d_in[2];
    const int*   batch    = (const int*)d_in[3];
    const float* node_emb = (const float*)d_in[4];
    const float* edge_emb = (const float*)d_in[5];
    const float* conv_w1  = (const float*)d_in[6];
    const float* conv_w2  = (const float*)d_in[7];
    const float* bn_gamma = (const float*)d_in[8];
    const float* bn_beta  = (const float*)d_in[9];
    const float* out_w1   = (const float*)d_in[10];
    const float* out_b1   = (const float*)d_in[11];
    const float* out_bng  = (const float*)d_in[12];
    const float* out_bnb  = (const float*)d_in[13];
    const float* out_w2   = (const float*)d_in[14];
    const float* out_b2   = (const float*)d_in[15];
    float* out = (float*)d_out;

    char* base = (char*)d_ws;
    size_t off = 0;
    auto alloc = [&](size_t bytes) -> char* {
        char* r = base + off;
        off = (off + bytes + 255) & ~(size_t)255;
        return r;
    };
    float*          xbuf    = (float*)alloc((size_t)N_NODES * NHID * 4);   // 51.2 MB
    float*          h0buf   = (float*)alloc((size_t)N_NODES * NHID * 4);   // 51.2 MB
    unsigned short* xbf     = (unsigned short*)alloc((size_t)N_NODES * NHID * 2); // 25.6 MB
    int*            row_ptr = (int*)alloc((size_t)(N_NODES + 1) * 4);
    int*            cursor  = (int*)alloc((size_t)N_NODES * 4);
    int*            counts  = (int*)alloc((size_t)N_NODES * 4);
    int*            partial = (int*)alloc(512 * 4);
    int*            bcur    = (int*)alloc((size_t)FILL_NB * 4);
    unsigned*       pack    = (unsigned*)alloc((size_t)N_EDGES * 4);       // 6.4 MB
    uint2*          tmp     = (uint2*)alloc((size_t)N_EDGES * 8);          // 12.8 MB
    float*          combo   = (float*)alloc((size_t)2000 * NHID * 4);      // 1.0 MB
    unsigned short* wth     = (unsigned short*)alloc((size_t)8 * 16384 * 2); // 256 KB
    unsigned short* wtl     = (unsigned short*)alloc((size_t)8 * 16384 * 2); // 256 KB
    float*          stats   = (float*)alloc(NLAYER * 256 * 4);
    float*          gbuf    = (float*)alloc((size_t)N_GRAPHS * NHID * 4);
    float*          o1buf   = (float*)alloc((size_t)N_GRAPHS * NHID * 4);
    (void)ws_size; (void)in_sizes; (void)n_in; (void)out_size;

    hipMemsetAsync(counts, 0, (size_t)N_NODES * 4, stream);
    hipMemsetAsync(stats, 0, NLAYER * 256 * 4, stream);
    hipMemsetAsync(gbuf, 0, (size_t)N_GRAPHS * NHID * 4, stream);

    // CSR build (edges grouped by dst): hist -> scan -> two-phase bucketed fill
    k_hist<<<N_EDGES / 256, 256, 0, stream>>>(eidx + N_EDGES, counts);
    k_scan_partial<<<SCAN_NB, 256, 0, stream>>>(counts, partial);
    k_scan_top<<<1, 128, 0, stream>>>(partial, SCAN_NB, row_ptr);
    k_scan_final<<<SCAN_NB, 256, 0, stream>>>(counts, partial, row_ptr);
    hipMemcpyAsync(cursor, row_ptr, (size_t)N_NODES * 4, hipMemcpyDeviceToDevice, stream);
    k_binit<<<(FILL_NB + 255) / 256, 256, 0, stream>>>(row_ptr, bcur);
    k_fillA<<<(N_EDGES + FILL_CHUNK - 1) / FILL_CHUNK, 256, 0, stream>>>(
        eidx, eattr, x_idx, bcur, tmp);
    k_fillB<<<FILL_NB, 256, 0, stream>>>(tmp, row_ptr, cursor, pack);

    // per-call precomputes
    k_combo<<<(2000 * NHID) / 256, 256, 0, stream>>>(node_emb, edge_emb, combo);
    k_wsplit<<<131072 / 256, 256, 0, stream>>>(conv_w1, conv_w2, wth, wtl);
    k_initx<<<(N_NODES * 32) / 256, 256, 0, stream>>>(x_idx, node_emb, (float4*)xbuf);

    const int gemm_grid = (N_NODES + 127) / 128;     // 782
    for (int l = 0; l < NLAYER; l++){
        if (l == 0){
            k_agg0<<<(N_NODES * 64) / 256, 256, 0, stream>>>(
                xbuf, row_ptr, pack, combo, (float2*)h0buf);
        } else {
            k_agg<<<(N_NODES * 64) / 256, 256, 0, stream>>>(
                xbuf, (const ushort2*)xbf, row_ptr, pack,
                edge_emb + (size_t)l * 20 * NHID, (float2*)h0buf);
        }
        // t = relu(h0 @ w1)   (in place, split-bf16 MFMA)
        k_mfma<1, 0><<<gemm_grid, 256, 0, stream>>>(
            h0buf, wth + (size_t)l * 16384, wtl + (size_t)l * 16384, h0buf, nullptr);
        // h2 = t @ w2 (+ BN stats)   (in place)
        k_mfma<0, 1><<<gemm_grid, 256, 0, stream>>>(
            h0buf, wth + (size_t)(4 + l) * 16384, wtl + (size_t)(4 + l) * 16384,
            h0buf, stats + l * 256);
        k_norm<<<(N_NODES * 32) / 256, 256, 0, stream>>>(
            (const float4*)h0buf, (float4*)xbuf, (ushort4*)xbf, stats + l * 256,
            bn_gamma + l * NHID, bn_beta + l * NHID);
    }

    k_pool<<<(N_NODES + 127) / 128, 256, 0, stream>>>(xbuf, batch, gbuf);
    k_head1<<<N_GRAPHS, 128, 0, stream>>>(gbuf, out_w1, out_b1, o1buf);
    k_head2<<<1, 128, 0, stream>>>(o1buf, out_bng, out_bnb, out_w2, out_b2, out);
}

// Round 13
// 958.099 us; speedup vs baseline: 1.5992x; 1.0553x over previous
//
#include <hip/hip_runtime.h>

#define N_NODES 100000
#define N_EDGES 1600000
#define N_GRAPHS 128
#define NHID 128
#define NLAYER 4
#define BN_EPS 1e-5f

#define SCAN_ITEMS 1024
#define SCAN_NB ((N_NODES + SCAN_ITEMS - 1) / SCAN_ITEMS)   // 98

#define FILL_CHUNK 8192
#define FILL_NB ((N_NODES + 255) / 256)                      // 391 coarse buckets (256 nodes)

__device__ __forceinline__ float4 ld4(const float* p){ return *(const float4*)p; }
__device__ __forceinline__ void st4(float* p, float4 v){ *(float4*)p = v; }

typedef __attribute__((ext_vector_type(8))) short short8v;   // 8 bf16 = 4 VGPR
typedef __attribute__((ext_vector_type(4))) float f32x4;     // MFMA acc

// split fp32 -> bf16 hi (truncate) + bf16 lo (truncate of residual)
__device__ __forceinline__ void bsplit(float a, unsigned short& h, unsigned short& l){
    unsigned ab = __float_as_uint(a);
    h = (unsigned short)(ab >> 16);
    float hf = __uint_as_float((unsigned)h << 16);
    l = (unsigned short)(__float_as_uint(a - hf) >> 16);
}

// fp32 -> bf16 round-to-nearest-even
__device__ __forceinline__ unsigned short brne(float a){
    unsigned ab = __float_as_uint(a);
    return (unsigned short)((ab + 0x7FFFu + ((ab >> 16) & 1u)) >> 16);
}
__device__ __forceinline__ float b2f(unsigned short b){
    return __uint_as_float((unsigned)b << 16);
}

// ---------------- CSR build ----------------

__global__ void k_hist(const int* __restrict__ dst, int* __restrict__ counts){
    int e = blockIdx.x * 256 + threadIdx.x;
    if (e < N_EDGES) atomicAdd(&counts[dst[e]], 1);
}

__global__ void k_scan_partial(const int* __restrict__ counts, int* __restrict__ partial){
    __shared__ int s[256];
    int t = threadIdx.x;
    int base = blockIdx.x * SCAN_ITEMS + t * 4;
    int v = 0;
    #pragma unroll
    for (int k = 0; k < 4; k++) if (base + k < N_NODES) v += counts[base + k];
    s[t] = v;
    __syncthreads();
    for (int o = 128; o > 0; o >>= 1){
        if (t < o) s[t] += s[t + o];
        __syncthreads();
    }
    if (t == 0) partial[blockIdx.x] = s[0];
}

__global__ void k_scan_top(int* __restrict__ partial, int nb, int* __restrict__ row_ptr){
    __shared__ int s[128];
    int t = threadIdx.x;
    int v = (t < nb) ? partial[t] : 0;
    s[t] = v;
    __syncthreads();
    for (int d = 1; d < 128; d <<= 1){
        int add = (t >= d) ? s[t - d] : 0;
        __syncthreads();
        s[t] += add;
        __syncthreads();
    }
    if (t < nb) partial[t] = s[t] - v;           // exclusive
    if (t == 0) row_ptr[N_NODES] = N_EDGES;
}

__global__ void k_scan_final(const int* __restrict__ counts, const int* __restrict__ partial,
                             int* __restrict__ row_ptr){
    __shared__ int s[256];
    int t = threadIdx.x;
    int base = blockIdx.x * SCAN_ITEMS + t * 4;
    int v[4]; int tsum = 0;
    #pragma unroll
    for (int k = 0; k < 4; k++){ v[k] = (base + k < N_NODES) ? counts[base + k] : 0; tsum += v[k]; }
    s[t] = tsum;
    __syncthreads();
    for (int d = 1; d < 256; d <<= 1){
        int add = (t >= d) ? s[t - d] : 0;
        __syncthreads();
        s[t] += add;
        __syncthreads();
    }
    int off = partial[blockIdx.x] + s[t] - tsum;  // exclusive prefix for this thread
    #pragma unroll
    for (int k = 0; k < 4; k++){
        if (base + k < N_NODES) row_ptr[base + k] = off;
        off += v[k];
    }
}

// bucket cursors init from row_ptr at 256-node granularity
__global__ void k_binit(const int* __restrict__ row_ptr, int* __restrict__ bcur){
    int b = blockIdx.x * 256 + threadIdx.x;
    if (b < FILL_NB) bcur[b] = row_ptr[b * 256];
}

// pass A: LDS-binned coarse bucket sort -> tmp {packword, dst}, run-length XCD-local writes
__global__ __launch_bounds__(256) void k_fillA(const int* __restrict__ eidx,
                        const int* __restrict__ eattr, const int* __restrict__ x_idx,
                        int* __restrict__ bcur, uint2* __restrict__ tmp){
    __shared__ int cnt[FILL_NB];
    __shared__ int lstart[FILL_NB];
    __shared__ int lcur[FILL_NB];
    __shared__ int gbase[FILL_NB];
    __shared__ uint2 stage[FILL_CHUNK];              // 64 KB
    int t = threadIdx.x;
    int e0 = blockIdx.x * FILL_CHUNK;
    int n = min(FILL_CHUNK, N_EDGES - e0);
    for (int i = t; i < FILL_NB; i += 256) cnt[i] = 0;
    __syncthreads();
    for (int i = t; i < n; i += 256)
        atomicAdd(&cnt[(unsigned)eidx[N_EDGES + e0 + i] >> 8], 1);
    __syncthreads();
    if (t == 0){
        int run = 0;
        for (int b = 0; b < FILL_NB; b++){ lstart[b] = run; run += cnt[b]; }
    }
    __syncthreads();
    for (int i = t; i < FILL_NB; i += 256) lcur[i] = lstart[i];
    __syncthreads();
    for (int i = t; i < n; i += 256){
        int e = e0 + i;
        int d = eidx[N_EDGES + e];
        int s = eidx[e];
        int a = eattr[e];
        int xi = x_idx[s];
        unsigned w = (unsigned)s | ((unsigned)a << 17) | ((unsigned)xi << 22);
        int pos = atomicAdd(&lcur[d >> 8], 1);
        stage[pos] = make_uint2(w, (unsigned)d);
    }
    __syncthreads();
    for (int b = t; b < FILL_NB; b += 256)
        if (cnt[b] > 0) gbase[b] = atomicAdd(&bcur[b], cnt[b]);
    __syncthreads();
    for (int i = t; i < n; i += 256){
        uint2 v = stage[i];
        int b = (int)(v.y >> 8);
        tmp[gbase[b] + (i - lstart[b])] = v;
    }
}

// pass B: one block per coarse bucket; fine scatter within the bucket's own CSR window
__global__ __launch_bounds__(256) void k_fillB(const uint2* __restrict__ tmp,
                        const int* __restrict__ row_ptr,
                        int* __restrict__ cursor, unsigned* __restrict__ pack){
    int b = blockIdx.x;
    int start = row_ptr[b * 256];
    int end   = row_ptr[min((b + 1) * 256, N_NODES)];
    for (int p = start + (int)threadIdx.x; p < end; p += 256){
        uint2 v = tmp[p];
        int pos = atomicAdd(&cursor[v.y], 1);
        pack[pos] = v.x;
    }
}

// ---------------- layer-0 message memo table ----------------

__global__ void k_combo(const float* __restrict__ node_emb, const float* __restrict__ edge_emb0,
                        float* __restrict__ combo){
    int i = blockIdx.x * 256 + threadIdx.x;          // over 2000*128
    if (i >= 2000 * NHID) return;
    int row = i >> 7, c = i & 127;
    int ni = row / 20, a = row - ni * 20;
    combo[i] = fmaxf(node_emb[ni * NHID + c] + edge_emb0[a * NHID + c], 0.f);
}

// ---------------- W^T split tables: [which][layer][col][k] bf16 hi/lo ----------------

__global__ void k_wsplit(const float* __restrict__ w1, const float* __restrict__ w2,
                         unsigned short* __restrict__ wth, unsigned short* __restrict__ wtl){
    int i = blockIdx.x * 256 + threadIdx.x;          // 2*4*128*128 = 131072
    int which = i >> 16;
    int m = (i >> 14) & 3;
    int r = i & 16383;
    int k = r >> 7, c = r & 127;
    float v = (which ? w2 : w1)[m * 16384 + k * 128 + c];
    unsigned short h, l;
    bsplit(v, h, l);
    int o = ((which * 4 + m) * 128 + c) * 128 + k;   // transposed: [col][k]
    wth[o] = h; wtl[o] = l;
}

// ---------------- node embedding init ----------------

__global__ void k_initx(const int* __restrict__ x_idx, const float* __restrict__ node_emb,
                        float4* __restrict__ x4){
    int i = blockIdx.x * 256 + threadIdx.x;          // over N*32 float4s
    if (i >= N_NODES * 32) return;
    int n = i >> 5, c = i & 31;
    int id = x_idx[n];
    x4[i] = ((const float4*)node_emb)[id * 32 + c];
}

// ----- aggregation (layers 1-3): h0[n] = x[n] + sum relu(bf16(x[src]) + emb[attr]) -----

__global__ __launch_bounds__(256) void k_agg(const float* __restrict__ x,
                      const ushort2* __restrict__ xb,
                      const int* __restrict__ row_ptr,
                      const unsigned* __restrict__ pack, const float* __restrict__ emb_l,
                      float2* __restrict__ h0){
    int gid = blockIdx.x * 256 + threadIdx.x;
    int node = gid >> 6;
    int lane = threadIdx.x & 63;
    const float2* x2 = (const float2*)x;
    const float2* e2 = (const float2*)emb_l;
    float2 acc = x2[node * 64 + lane];
    int beg = row_ptr[node], end = row_ptr[node + 1];
    int i = beg;
    for (; i + 3 < end; i += 4){
        unsigned p0 = pack[i], p1 = pack[i+1], p2 = pack[i+2], p3 = pack[i+3];
        ushort2 g0 = xb[(p0 & 0x1FFFFu) * 64 + lane];
        ushort2 g1 = xb[(p1 & 0x1FFFFu) * 64 + lane];
        ushort2 g2 = xb[(p2 & 0x1FFFFu) * 64 + lane];
        ushort2 g3 = xb[(p3 & 0x1FFFFu) * 64 + lane];
        float2 b0 = e2[((p0 >> 17) & 31u) * 64 + lane];
        float2 b1 = e2[((p1 >> 17) & 31u) * 64 + lane];
        float2 b2 = e2[((p2 >> 17) & 31u) * 64 + lane];
        float2 b3 = e2[((p3 >> 17) & 31u) * 64 + lane];
        acc.x += (fmaxf(b2f(g0.x) + b0.x, 0.f) + fmaxf(b2f(g1.x) + b1.x, 0.f))
               + (fmaxf(b2f(g2.x) + b2.x, 0.f) + fmaxf(b2f(g3.x) + b3.x, 0.f));
        acc.y += (fmaxf(b2f(g0.y) + b0.y, 0.f) + fmaxf(b2f(g1.y) + b1.y, 0.f))
               + (fmaxf(b2f(g2.y) + b2.y, 0.f) + fmaxf(b2f(g3.y) + b3.y, 0.f));
    }
    for (; i < end; i++){
        unsigned p = pack[i];
        ushort2 g = xb[(p & 0x1FFFFu) * 64 + lane];
        float2 ev = e2[((p >> 17) & 31u) * 64 + lane];
        acc.x += fmaxf(b2f(g.x) + ev.x, 0.f);
        acc.y += fmaxf(b2f(g.y) + ev.y, 0.f);
    }
    h0[node * 64 + lane] = acc;
}

// ---------------- aggregation (layer 0): memo table ----------------

__global__ __launch_bounds__(256) void k_agg0(const float* __restrict__ x,
                      const int* __restrict__ row_ptr,
                      const unsigned* __restrict__ pack,
                      const float* __restrict__ combo,
                      float2* __restrict__ h0){
    int gid = blockIdx.x * 256 + threadIdx.x;
    int node = gid >> 6;
    int lane = threadIdx.x & 63;
    const float2* x2 = (const float2*)x;
    const float2* c2 = (const float2*)combo;
    float2 acc = x2[node * 64 + lane];
    int beg = row_ptr[node], end = row_ptr[node + 1];
    int i = beg;
    for (; i + 3 < end; i += 4){
        unsigned p0 = pack[i], p1 = pack[i+1], p2 = pack[i+2], p3 = pack[i+3];
        int ci0 = (int)((p0 >> 22) & 127u) * 20 + (int)((p0 >> 17) & 31u);
        int ci1 = (int)((p1 >> 22) & 127u) * 20 + (int)((p1 >> 17) & 31u);
        int ci2 = (int)((p2 >> 22) & 127u) * 20 + (int)((p2 >> 17) & 31u);
        int ci3 = (int)((p3 >> 22) & 127u) * 20 + (int)((p3 >> 17) & 31u);
        float2 m0 = c2[ci0 * 64 + lane];
        float2 m1 = c2[ci1 * 64 + lane];
        float2 m2 = c2[ci2 * 64 + lane];
        float2 m3 = c2[ci3 * 64 + lane];
        acc.x += (m0.x + m1.x) + (m2.x + m3.x);
        acc.y += (m0.y + m1.y) + (m2.y + m3.y);
    }
    for (; i < end; i++){
        unsigned p = pack[i];
        int ci = (int)((p >> 22) & 127u) * 20 + (int)((p >> 17) & 31u);
        float2 m = c2[ci * 64 + lane];
        acc.x += m.x;
        acc.y += m.y;
    }
    h0[node * 64 + lane] = acc;
}

// ---- fused MLP: h2 = (relu(h0@W1))@W2 + BN stats, split-bf16 MFMA, t streamed via LDS ----
// Phase 1: acc1 = h0@W1 (A staged hi/lo from global). relu.
// Phase 2: per 32-col chunk, threads write their acc1 fragment (bsplit) into Ah/Al,
//          stage W2^T chunk into Bh/Bl, MFMA into acc2. Bit-identical to the former
//          two-kernel path (same hi/lo split of relu(t), same dropped Al@Wl term).
// In-place over A safe: block reads only its own 128-row panel.

__global__ __launch_bounds__(256) void k_mlp(const float* __restrict__ A,
                                             const unsigned short* __restrict__ W1th,
                                             const unsigned short* __restrict__ W1tl,
                                             const unsigned short* __restrict__ W2th,
                                             const unsigned short* __restrict__ W2tl,
                                             float* __restrict__ out,
                                             float* __restrict__ stats_l){
    __shared__ unsigned short Ah[128][40], Al[128][40];   // A chunk, then t chunk
    __shared__ unsigned short Bh[128][40], Bl[128][40];   // W^T chunk [col][k]
    const int tid = threadIdx.x;
    const int w = tid >> 6;
    const int l = tid & 63;
    const int lr = l & 15;
    const int lk = l >> 4;
    const int row0 = blockIdx.x * 128;

    f32x4 acc1[2][8], acc2[2][8];
    #pragma unroll
    for (int m = 0; m < 2; m++)
        #pragma unroll
        for (int n = 0; n < 8; n++){ acc1[m][n] = (f32x4)(0.f); acc2[m][n] = (f32x4)(0.f); }

    // ---- phase 1: acc1 = h0 @ W1 ----
    for (int kc = 0; kc < 4; kc++){
        __syncthreads();
        #pragma unroll
        for (int q = 0; q < 4; q++){
            int f = tid + 256 * q;
            int r = f >> 3, kq = f & 7;
            int gr = row0 + r;
            float4 v = make_float4(0.f, 0.f, 0.f, 0.f);
            if (gr < N_NODES) v = ld4(A + (size_t)gr * NHID + kc * 32 + kq * 4);
            unsigned short h0,l0,h1,l1,h2,l2,h3,l3;
            bsplit(v.x, h0, l0); bsplit(v.y, h1, l1);
            bsplit(v.z, h2, l2); bsplit(v.w, h3, l3);
            *(ushort4*)&Ah[r][kq * 4] = make_ushort4(h0, h1, h2, h3);
            *(ushort4*)&Al[r][kq * 4] = make_ushort4(l0, l1, l2, l3);
        }
        #pragma unroll
        for (int q = 0; q < 2; q++){
            int f = tid + 256 * q;
            int c = f >> 2, kq = f & 3;
            size_t gi = (size_t)c * 128 + kc * 32 + kq * 8;
            *(uint4*)&Bh[c][kq * 8] = *(const uint4*)(W1th + gi);
            *(uint4*)&Bl[c][kq * 8] = *(const uint4*)(W1tl + gi);
        }
        __syncthreads();
        short8v pah[2], pal[2];
        #pragma unroll
        for (int m = 0; m < 2; m++){
            pah[m] = *(const short8v*)&Ah[w * 32 + m * 16 + lr][lk * 8];
            pal[m] = *(const short8v*)&Al[w * 32 + m * 16 + lr][lk * 8];
        }
        #pragma unroll
        for (int n = 0; n < 8; n++){
            short8v pbh = *(const short8v*)&Bh[n * 16 + lr][lk * 8];
            short8v pbl = *(const short8v*)&Bl[n * 16 + lr][lk * 8];
            #pragma unroll
            for (int m = 0; m < 2; m++){
                acc1[m][n] = __builtin_amdgcn_mfma_f32_16x16x32_bf16(pal[m], pbh, acc1[m][n], 0, 0, 0);
                acc1[m][n] = __builtin_amdgcn_mfma_f32_16x16x32_bf16(pah[m], pbl, acc1[m][n], 0, 0, 0);
                acc1[m][n] = __builtin_amdgcn_mfma_f32_16x16x32_bf16(pah[m], pbh, acc1[m][n], 0, 0, 0);
            }
        }
    }

    // relu(t)
    #pragma unroll
    for (int m = 0; m < 2; m++)
        #pragma unroll
        for (int n = 0; n < 8; n++)
            #pragma unroll
            for (int j = 0; j < 4; j++) acc1[m][n][j] = fmaxf(acc1[m][n][j], 0.f);

    // ---- phase 2: acc2 = t @ W2, t chunk streamed through Ah/Al ----
    for (int kc = 0; kc < 4; kc++){
        __syncthreads();                               // prior LDS reads complete
        // write t cols [kc*32, kc*32+32): fragment (row, col) -> Ah/Al[row][col - kc*32]
        #pragma unroll
        for (int m = 0; m < 2; m++)
            #pragma unroll
            for (int j = 0; j < 4; j++){
                int trow = w * 32 + m * 16 + lk * 4 + j;
                #pragma unroll
                for (int nn = 0; nn < 2; nn++){
                    float v = acc1[m][kc * 2 + nn][j];
                    unsigned short h, lo;
                    bsplit(v, h, lo);
                    int tcol = nn * 16 + lr;
                    Ah[trow][tcol] = h;
                    Al[trow][tcol] = lo;
                }
            }
        #pragma unroll
        for (int q = 0; q < 2; q++){
            int f = tid + 256 * q;
            int c = f >> 2, kq = f & 3;
            size_t gi = (size_t)c * 128 + kc * 32 + kq * 8;
            *(uint4*)&Bh[c][kq * 8] = *(const uint4*)(W2th + gi);
            *(uint4*)&Bl[c][kq * 8] = *(const uint4*)(W2tl + gi);
        }
        __syncthreads();
        short8v pah[2], pal[2];
        #pragma unroll
        for (int m = 0; m < 2; m++){
            pah[m] = *(const short8v*)&Ah[w * 32 + m * 16 + lr][lk * 8];
            pal[m] = *(const short8v*)&Al[w * 32 + m * 16 + lr][lk * 8];
        }
        #pragma unroll
        for (int n = 0; n < 8; n++){
            short8v pbh = *(const short8v*)&Bh[n * 16 + lr][lk * 8];
            short8v pbl = *(const short8v*)&Bl[n * 16 + lr][lk * 8];
            #pragma unroll
            for (int m = 0; m < 2; m++){
                acc2[m][n] = __builtin_amdgcn_mfma_f32_16x16x32_bf16(pal[m], pbh, acc2[m][n], 0, 0, 0);
                acc2[m][n] = __builtin_amdgcn_mfma_f32_16x16x32_bf16(pah[m], pbl, acc2[m][n], 0, 0, 0);
                acc2[m][n] = __builtin_amdgcn_mfma_f32_16x16x32_bf16(pah[m], pbh, acc2[m][n], 0, 0, 0);
            }
        }
    }

    // store h2
    #pragma unroll
    for (int m = 0; m < 2; m++)
        #pragma unroll
        for (int j = 0; j < 4; j++){
            int gr = row0 + w * 32 + m * 16 + lk * 4 + j;
            if (gr < N_NODES){
                #pragma unroll
                for (int n = 0; n < 8; n++)
                    out[(size_t)gr * NHID + n * 16 + lr] = acc2[m][n][j];
            }
        }

    // BN stats (padded rows contribute exactly 0)
    __syncthreads();
    float* red  = (float*)&Ah[0][0];
    float* red2 = (float*)&Bh[0][0];
    #pragma unroll
    for (int n = 0; n < 8; n++){
        float s = 0.f, q = 0.f;
        #pragma unroll
        for (int m = 0; m < 2; m++)
            #pragma unroll
            for (int j = 0; j < 4; j++){ float v = acc2[m][n][j]; s += v; q += v * v; }
        red [(w * 4 + lk) * 128 + n * 16 + lr] = s;
        red2[(w * 4 + lk) * 128 + n * 16 + lr] = q;
    }
    __syncthreads();
    if (tid < 128){
        float s = 0.f, q = 0.f;
        #pragma unroll
        for (int r2 = 0; r2 < 16; r2++){
            s += red[r2 * 128 + tid];
            q += red2[r2 * 128 + tid];
        }
        atomicAdd(&stats_l[tid], s);
        atomicAdd(&stats_l[128 + tid], q);
    }
}

// -------- normalize + relu + residual; also emit bf16 shadow copy of x for gathers --------

__global__ void k_norm(const float4* __restrict__ h2, float4* __restrict__ x,
                       ushort4* __restrict__ xb,
                       const float* __restrict__ stats_l,
                       const float* __restrict__ gamma, const float* __restrict__ beta){
    int i = blockIdx.x * 256 + threadIdx.x;
    if (i >= N_NODES * 32) return;
    int g = (i & 31);
    float4 sv = ((const float4*)stats_l)[g];
    float4 qv = ((const float4*)(stats_l + 128))[g];
    float4 gm = ((const float4*)gamma)[g];
    float4 bt = ((const float4*)beta)[g];
    float4 ca, cb;
    {
        float mu, var;
        mu = sv.x * (1.f / N_NODES); var = qv.x * (1.f / N_NODES) - mu * mu;
        ca.x = gm.x * rsqrtf(var + BN_EPS); cb.x = bt.x - mu * ca.x;
        mu = sv.y * (1.f / N_NODES); var = qv.y * (1.f / N_NODES) - mu * mu;
        ca.y = gm.y * rsqrtf(var + BN_EPS); cb.y = bt.y - mu * ca.y;
        mu = sv.z * (1.f / N_NODES); var = qv.z * (1.f / N_NODES) - mu * mu;
        ca.z = gm.z * rsqrtf(var + BN_EPS); cb.z = bt.z - mu * ca.z;
        mu = sv.w * (1.f / N_NODES); var = qv.w * (1.f / N_NODES) - mu * mu;
        ca.w = gm.w * rsqrtf(var + BN_EPS); cb.w = bt.w - mu * ca.w;
    }
    float4 h = h2[i];
    float4 xv = x[i];
    float4 r;
    r.x = fmaxf(fmaf(h.x, ca.x, cb.x), 0.f) + xv.x;
    r.y = fmaxf(fmaf(h.y, ca.y, cb.y), 0.f) + xv.y;
    r.z = fmaxf(fmaf(h.z, ca.z, cb.z), 0.f) + xv.z;
    r.w = fmaxf(fmaf(h.w, ca.w, cb.w), 0.f) + xv.w;
    x[i] = r;
    xb[i] = make_ushort4(brne(r.x), brne(r.y), brne(r.z), brne(r.w));
}

// -------- pooling: chunked over nodes (batch sorted), per-run register accumulation --------

__global__ __launch_bounds__(256) void k_pool(const float* __restrict__ x,
                       const int* __restrict__ batch, float* __restrict__ gbuf){
    int c = threadIdx.x & 127;
    int half = threadIdx.x >> 7;
    int n0 = blockIdx.x * 128;
    int nend = min(n0 + 128, N_NODES);
    float acc = 0.f;
    int gcur = -1;
    for (int n = n0 + half; n < nend; n += 2){
        int g = batch[n];
        if (g != gcur){
            if (gcur >= 0) atomicAdd(&gbuf[gcur * NHID + c], acc);
            acc = 0.f; gcur = g;
        }
        acc += x[(size_t)n * NHID + c];
    }
    if (gcur >= 0) atomicAdd(&gbuf[gcur * NHID + c], acc);
}

// ---------------- output head ----------------

__global__ __launch_bounds__(128) void k_head1(const float* __restrict__ gbuf,
                                               const float* __restrict__ w1,
                                               const float* __restrict__ b1,
                                               float* __restrict__ o1){
    __shared__ float gs[128];
    int i = blockIdx.x;
    int j = threadIdx.x;
    gs[j] = gbuf[i * NHID + j];
    __syncthreads();
    float acc = 0.f;
    #pragma unroll 8
    for (int k = 0; k < 128; k++)
        acc = fmaf(gs[k], w1[k * NHID + j], acc);
    o1[i * NHID + j] = acc + b1[j];
}

__global__ __launch_bounds__(128) void k_head2(const float* __restrict__ o1,
                                               const float* __restrict__ gamma,
                                               const float* __restrict__ beta,
                                               const float* __restrict__ w2,
                                               const float* __restrict__ b2,
                                               float* __restrict__ out){
    __shared__ float s_o1[128][129];
    __shared__ float sa[128], sb[128];
    int t = threadIdx.x;
    float s = 0.f, q = 0.f;
    for (int r = 0; r < 128; r++){
        float v = o1[r * NHID + t];
        s_o1[r][t] = v;
        s += v; q += v * v;
    }
    float mu = s * (1.f / 128.f);
    float rs = rsqrtf(q * (1.f / 128.f) - mu * mu + BN_EPS);
    float a = gamma[t] * rs;
    sa[t] = a;
    sb[t] = beta[t] - mu * a;
    __syncthreads();
    float a2 = 0.f;
    #pragma unroll 8
    for (int j = 0; j < 128; j++){
        float v = fmaf(s_o1[t][j], sa[j], sb[j]);
        a2 += fmaxf(v, 0.f) * w2[j];
    }
    out[t] = a2 + b2[0];
}

// ---------------- launch ----------------

extern "C" void kernel_launch(void* const* d_in, const int* in_sizes, int n_in,
                              void* d_out, int out_size, void* d_ws, size_t ws_size,
                              hipStream_t stream){
    const int*   x_idx    = (const int*)d_in[0];
    const int*   eidx     = (const int*)d_in[1];
    const int*   eattr    = (const int*)d_in[2];
    const int*   batch    = (const int*)d_in[3];
    const float* node_emb = (const float*)d_in[4];
    const float* edge_emb = (const float*)d_in[5];
    const float* conv_w1  = (const float*)d_in[6];
    const float* conv_w2  = (const float*)d_in[7];
    const float* bn_gamma = (const float*)d_in[8];
    const float* bn_beta  = (const float*)d_in[9];
    const float* out_w1   = (const float*)d_in[10];
    const float* out_b1   = (const float*)d_in[11];
    const float* out_bng  = (const float*)d_in[12];
    const float* out_bnb  = (const float*)d_in[13];
    const float* out_w2   = (const float*)d_in[14];
    const float* out_b2   = (const float*)d_in[15];
    float* out = (float*)d_out;

    char* base = (char*)d_ws;
    size_t off = 0;
    auto alloc = [&](size_t bytes) -> char* {
        char* r = base + off;
        off = (off + bytes + 255) & ~(size_t)255;
        return r;
    };
    float*          xbuf    = (float*)alloc((size_t)N_NODES * NHID * 4);   // 51.2 MB
    float*          h0buf   = (float*)alloc((size_t)N_NODES * NHID * 4);   // 51.2 MB
    unsigned short* xbf     = (unsigned short*)alloc((size_t)N_NODES * NHID * 2); // 25.6 MB
    int*            row_ptr = (int*)alloc((size_t)(N_NODES + 1) * 4);
    int*            cursor  = (int*)alloc((size_t)N_NODES * 4);
    int*            counts  = (int*)alloc((size_t)N_NODES * 4);
    int*            partial = (int*)alloc(512 * 4);
    int*            bcur    = (int*)alloc((size_t)FILL_NB * 4);
    unsigned*       pack    = (unsigned*)alloc((size_t)N_EDGES * 4);       // 6.4 MB
    uint2*          tmp     = (uint2*)alloc((size_t)N_EDGES * 8);          // 12.8 MB
    float*          combo   = (float*)alloc((size_t)2000 * NHID * 4);      // 1.0 MB
    unsigned short* wth     = (unsigned short*)alloc((size_t)8 * 16384 * 2); // 256 KB
    unsigned short* wtl     = (unsigned short*)alloc((size_t)8 * 16384 * 2); // 256 KB
    float*          stats   = (float*)alloc(NLAYER * 256 * 4);
    float*          gbuf    = (float*)alloc((size_t)N_GRAPHS * NHID * 4);
    float*          o1buf   = (float*)alloc((size_t)N_GRAPHS * NHID * 4);
    (void)ws_size; (void)in_sizes; (void)n_in; (void)out_size;

    hipMemsetAsync(counts, 0, (size_t)N_NODES * 4, stream);
    hipMemsetAsync(stats, 0, NLAYER * 256 * 4, stream);
    hipMemsetAsync(gbuf, 0, (size_t)N_GRAPHS * NHID * 4, stream);

    // CSR build (edges grouped by dst): hist -> scan -> two-phase bucketed fill
    k_hist<<<N_EDGES / 256, 256, 0, stream>>>(eidx + N_EDGES, counts);
    k_scan_partial<<<SCAN_NB, 256, 0, stream>>>(counts, partial);
    k_scan_top<<<1, 128, 0, stream>>>(partial, SCAN_NB, row_ptr);
    k_scan_final<<<SCAN_NB, 256, 0, stream>>>(counts, partial, row_ptr);
    hipMemcpyAsync(cursor, row_ptr, (size_t)N_NODES * 4, hipMemcpyDeviceToDevice, stream);
    k_binit<<<(FILL_NB + 255) / 256, 256, 0, stream>>>(row_ptr, bcur);
    k_fillA<<<(N_EDGES + FILL_CHUNK - 1) / FILL_CHUNK, 256, 0, stream>>>(
        eidx, eattr, x_idx, bcur, tmp);
    k_fillB<<<FILL_NB, 256, 0, stream>>>(tmp, row_ptr, cursor, pack);

    // per-call precomputes
    k_combo<<<(2000 * NHID) / 256, 256, 0, stream>>>(node_emb, edge_emb, combo);
    k_wsplit<<<131072 / 256, 256, 0, stream>>>(conv_w1, conv_w2, wth, wtl);
    k_initx<<<(N_NODES * 32) / 256, 256, 0, stream>>>(x_idx, node_emb, (float4*)xbuf);

    const int gemm_grid = (N_NODES + 127) / 128;     // 782
    for (int l = 0; l < NLAYER; l++){
        if (l == 0){
            k_agg0<<<(N_NODES * 64) / 256, 256, 0, stream>>>(
                xbuf, row_ptr, pack, combo, (float2*)h0buf);
        } else {
            k_agg<<<(N_NODES * 64) / 256, 256, 0, stream>>>(
                xbuf, (const ushort2*)xbf, row_ptr, pack,
                edge_emb + (size_t)l * 20 * NHID, (float2*)h0buf);
        }
        // h2 = relu(h0@W1)@W2 fused (in place) + BN stats
        k_mlp<<<gemm_grid, 256, 0, stream>>>(
            h0buf,
            wth + (size_t)l * 16384, wtl + (size_t)l * 16384,
            wth + (size_t)(4 + l) * 16384, wtl + (size_t)(4 + l) * 16384,
            h0buf, stats + l * 256);
        k_norm<<<(N_NODES * 32) / 256, 256, 0, stream>>>(
            (const float4*)h0buf, (float4*)xbuf, (ushort4*)xbf, stats + l * 256,
            bn_gamma + l * NHID, bn_beta + l * NHID);
    }

    k_pool<<<(N_NODES + 127) / 128, 256, 0, stream>>>(xbuf, batch, gbuf);
    k_head1<<<N_GRAPHS, 128, 0, stream>>>(gbuf, out_w1, out_b1, o1buf);
    k_head2<<<1, 128, 0, stream>>>(o1buf, out_bng, out_bnb, out_w2, out_b2, out);
}

// Round 14
// 947.201 us; speedup vs baseline: 1.6176x; 1.0115x over previous
//
#include <hip/hip_runtime.h>

#define N_NODES 100000
#define N_EDGES 1600000
#define N_GRAPHS 128
#define NHID 128
#define NLAYER 4
#define BN_EPS 1e-5f

#define SCAN_ITEMS 1024
#define SCAN_NB ((N_NODES + SCAN_ITEMS - 1) / SCAN_ITEMS)   // 98

#define FILL_CHUNK 8192
#define FILL_NB ((N_NODES + 255) / 256)                      // 391 coarse buckets (256 nodes)

__device__ __forceinline__ float4 ld4(const float* p){ return *(const float4*)p; }
__device__ __forceinline__ void st4(float* p, float4 v){ *(float4*)p = v; }

typedef __attribute__((ext_vector_type(8))) short short8v;   // 8 bf16 = 4 VGPR
typedef __attribute__((ext_vector_type(4))) float f32x4;     // MFMA acc

// split fp32 -> bf16 hi (truncate) + bf16 lo (truncate of residual)
__device__ __forceinline__ void bsplit(float a, unsigned short& h, unsigned short& l){
    unsigned ab = __float_as_uint(a);
    h = (unsigned short)(ab >> 16);
    float hf = __uint_as_float((unsigned)h << 16);
    l = (unsigned short)(__float_as_uint(a - hf) >> 16);
}

// fp32 -> bf16 round-to-nearest-even
__device__ __forceinline__ unsigned short brne(float a){
    unsigned ab = __float_as_uint(a);
    return (unsigned short)((ab + 0x7FFFu + ((ab >> 16) & 1u)) >> 16);
}
__device__ __forceinline__ float b2f(unsigned short b){
    return __uint_as_float((unsigned)b << 16);
}

// ---------------- CSR build ----------------

__global__ void k_hist(const int* __restrict__ dst, int* __restrict__ counts){
    int e = blockIdx.x * 256 + threadIdx.x;
    if (e < N_EDGES) atomicAdd(&counts[dst[e]], 1);
}

__global__ void k_scan_partial(const int* __restrict__ counts, int* __restrict__ partial){
    __shared__ int s[256];
    int t = threadIdx.x;
    int base = blockIdx.x * SCAN_ITEMS + t * 4;
    int v = 0;
    #pragma unroll
    for (int k = 0; k < 4; k++) if (base + k < N_NODES) v += counts[base + k];
    s[t] = v;
    __syncthreads();
    for (int o = 128; o > 0; o >>= 1){
        if (t < o) s[t] += s[t + o];
        __syncthreads();
    }
    if (t == 0) partial[blockIdx.x] = s[0];
}

__global__ void k_scan_top(int* __restrict__ partial, int nb, int* __restrict__ row_ptr){
    __shared__ int s[128];
    int t = threadIdx.x;
    int v = (t < nb) ? partial[t] : 0;
    s[t] = v;
    __syncthreads();
    for (int d = 1; d < 128; d <<= 1){
        int add = (t >= d) ? s[t - d] : 0;
        __syncthreads();
        s[t] += add;
        __syncthreads();
    }
    if (t < nb) partial[t] = s[t] - v;           // exclusive
    if (t == 0) row_ptr[N_NODES] = N_EDGES;
}

__global__ void k_scan_final(const int* __restrict__ counts, const int* __restrict__ partial,
                             int* __restrict__ row_ptr){
    __shared__ int s[256];
    int t = threadIdx.x;
    int base = blockIdx.x * SCAN_ITEMS + t * 4;
    int v[4]; int tsum = 0;
    #pragma unroll
    for (int k = 0; k < 4; k++){ v[k] = (base + k < N_NODES) ? counts[base + k] : 0; tsum += v[k]; }
    s[t] = tsum;
    __syncthreads();
    for (int d = 1; d < 256; d <<= 1){
        int add = (t >= d) ? s[t - d] : 0;
        __syncthreads();
        s[t] += add;
        __syncthreads();
    }
    int off = partial[blockIdx.x] + s[t] - tsum;  // exclusive prefix for this thread
    #pragma unroll
    for (int k = 0; k < 4; k++){
        if (base + k < N_NODES) row_ptr[base + k] = off;
        off += v[k];
    }
}

// bucket cursors init from row_ptr at 256-node granularity
__global__ void k_binit(const int* __restrict__ row_ptr, int* __restrict__ bcur){
    int b = blockIdx.x * 256 + threadIdx.x;
    if (b < FILL_NB) bcur[b] = row_ptr[b * 256];
}

// pass A: LDS-binned coarse bucket sort -> tmp {packword, dst}, run-length XCD-local writes
__global__ __launch_bounds__(256) void k_fillA(const int* __restrict__ eidx,
                        const int* __restrict__ eattr, const int* __restrict__ x_idx,
                        int* __restrict__ bcur, uint2* __restrict__ tmp){
    __shared__ int cnt[FILL_NB];
    __shared__ int lstart[FILL_NB];
    __shared__ int lcur[FILL_NB];
    __shared__ int gbase[FILL_NB];
    __shared__ uint2 stage[FILL_CHUNK];              // 64 KB
    int t = threadIdx.x;
    int e0 = blockIdx.x * FILL_CHUNK;
    int n = min(FILL_CHUNK, N_EDGES - e0);
    for (int i = t; i < FILL_NB; i += 256) cnt[i] = 0;
    __syncthreads();
    for (int i = t; i < n; i += 256)
        atomicAdd(&cnt[(unsigned)eidx[N_EDGES + e0 + i] >> 8], 1);
    __syncthreads();
    if (t == 0){
        int run = 0;
        for (int b = 0; b < FILL_NB; b++){ lstart[b] = run; run += cnt[b]; }
    }
    __syncthreads();
    for (int i = t; i < FILL_NB; i += 256) lcur[i] = lstart[i];
    __syncthreads();
    for (int i = t; i < n; i += 256){
        int e = e0 + i;
        int d = eidx[N_EDGES + e];
        int s = eidx[e];
        int a = eattr[e];
        int xi = x_idx[s];
        unsigned w = (unsigned)s | ((unsigned)a << 17) | ((unsigned)xi << 22);
        int pos = atomicAdd(&lcur[d >> 8], 1);
        stage[pos] = make_uint2(w, (unsigned)d);
    }
    __syncthreads();
    for (int b = t; b < FILL_NB; b += 256)
        if (cnt[b] > 0) gbase[b] = atomicAdd(&bcur[b], cnt[b]);
    __syncthreads();
    for (int i = t; i < n; i += 256){
        uint2 v = stage[i];
        int b = (int)(v.y >> 8);
        tmp[gbase[b] + (i - lstart[b])] = v;
    }
}

// pass B: one block per coarse bucket; fine scatter within the bucket's own CSR window
__global__ __launch_bounds__(256) void k_fillB(const uint2* __restrict__ tmp,
                        const int* __restrict__ row_ptr,
                        int* __restrict__ cursor, unsigned* __restrict__ pack){
    int b = blockIdx.x;
    int start = row_ptr[b * 256];
    int end   = row_ptr[min((b + 1) * 256, N_NODES)];
    for (int p = start + (int)threadIdx.x; p < end; p += 256){
        uint2 v = tmp[p];
        int pos = atomicAdd(&cursor[v.y], 1);
        pack[pos] = v.x;
    }
}

// ---------------- layer-0 message memo table ----------------

__global__ void k_combo(const float* __restrict__ node_emb, const float* __restrict__ edge_emb0,
                        float* __restrict__ combo){
    int i = blockIdx.x * 256 + threadIdx.x;          // over 2000*128
    if (i >= 2000 * NHID) return;
    int row = i >> 7, c = i & 127;
    int ni = row / 20, a = row - ni * 20;
    combo[i] = fmaxf(node_emb[ni * NHID + c] + edge_emb0[a * NHID + c], 0.f);
}

// ---------------- W^T split tables: [which][layer][col][k] bf16 hi/lo ----------------

__global__ void k_wsplit(const float* __restrict__ w1, const float* __restrict__ w2,
                         unsigned short* __restrict__ wth, unsigned short* __restrict__ wtl){
    int i = blockIdx.x * 256 + threadIdx.x;          // 2*4*128*128 = 131072
    int which = i >> 16;
    int m = (i >> 14) & 3;
    int r = i & 16383;
    int k = r >> 7, c = r & 127;
    float v = (which ? w2 : w1)[m * 16384 + k * 128 + c];
    unsigned short h, l;
    bsplit(v, h, l);
    int o = ((which * 4 + m) * 128 + c) * 128 + k;   // transposed: [col][k]
    wth[o] = h; wtl[o] = l;
}

// ---------------- node embedding init ----------------

__global__ void k_initx(const int* __restrict__ x_idx, const float* __restrict__ node_emb,
                        float4* __restrict__ x4){
    int i = blockIdx.x * 256 + threadIdx.x;          // over N*32 float4s
    if (i >= N_NODES * 32) return;
    int n = i >> 5, c = i & 31;
    int id = x_idx[n];
    x4[i] = ((const float4*)node_emb)[id * 32 + c];
}

// ----- aggregation (layers 1-3): h0 = x + sum relu(bf16(x[src]) + emb[attr]) -----
// emits h0 directly in split hi/lo bf16 form (exactly bsplit of the fp32 value)

__global__ __launch_bounds__(256) void k_agg(const float* __restrict__ x,
                      const ushort2* __restrict__ xb,
                      const int* __restrict__ row_ptr,
                      const unsigned* __restrict__ pack, const float* __restrict__ emb_l,
                      unsigned short* __restrict__ h0h, unsigned short* __restrict__ h0l){
    int gid = blockIdx.x * 256 + threadIdx.x;
    int node = gid >> 6;
    int lane = threadIdx.x & 63;
    const float2* x2 = (const float2*)x;
    const float2* e2 = (const float2*)emb_l;
    float2 acc = x2[node * 64 + lane];
    int beg = row_ptr[node], end = row_ptr[node + 1];
    int i = beg;
    for (; i + 3 < end; i += 4){
        unsigned p0 = pack[i], p1 = pack[i+1], p2 = pack[i+2], p3 = pack[i+3];
        ushort2 g0 = xb[(p0 & 0x1FFFFu) * 64 + lane];
        ushort2 g1 = xb[(p1 & 0x1FFFFu) * 64 + lane];
        ushort2 g2 = xb[(p2 & 0x1FFFFu) * 64 + lane];
        ushort2 g3 = xb[(p3 & 0x1FFFFu) * 64 + lane];
        float2 b0 = e2[((p0 >> 17) & 31u) * 64 + lane];
        float2 b1 = e2[((p1 >> 17) & 31u) * 64 + lane];
        float2 b2 = e2[((p2 >> 17) & 31u) * 64 + lane];
        float2 b3 = e2[((p3 >> 17) & 31u) * 64 + lane];
        acc.x += (fmaxf(b2f(g0.x) + b0.x, 0.f) + fmaxf(b2f(g1.x) + b1.x, 0.f))
               + (fmaxf(b2f(g2.x) + b2.x, 0.f) + fmaxf(b2f(g3.x) + b3.x, 0.f));
        acc.y += (fmaxf(b2f(g0.y) + b0.y, 0.f) + fmaxf(b2f(g1.y) + b1.y, 0.f))
               + (fmaxf(b2f(g2.y) + b2.y, 0.f) + fmaxf(b2f(g3.y) + b3.y, 0.f));
    }
    for (; i < end; i++){
        unsigned p = pack[i];
        ushort2 g = xb[(p & 0x1FFFFu) * 64 + lane];
        float2 ev = e2[((p >> 17) & 31u) * 64 + lane];
        acc.x += fmaxf(b2f(g.x) + ev.x, 0.f);
        acc.y += fmaxf(b2f(g.y) + ev.y, 0.f);
    }
    unsigned short hx, lx, hy, ly;
    bsplit(acc.x, hx, lx); bsplit(acc.y, hy, ly);
    *(ushort2*)(h0h + (size_t)node * NHID + lane * 2) = make_ushort2(hx, hy);
    *(ushort2*)(h0l + (size_t)node * NHID + lane * 2) = make_ushort2(lx, ly);
}

// ---------------- aggregation (layer 0): memo table, same split-form output ----------------

__global__ __launch_bounds__(256) void k_agg0(const float* __restrict__ x,
                      const int* __restrict__ row_ptr,
                      const unsigned* __restrict__ pack,
                      const float* __restrict__ combo,
                      unsigned short* __restrict__ h0h, unsigned short* __restrict__ h0l){
    int gid = blockIdx.x * 256 + threadIdx.x;
    int node = gid >> 6;
    int lane = threadIdx.x & 63;
    const float2* x2 = (const float2*)x;
    const float2* c2 = (const float2*)combo;
    float2 acc = x2[node * 64 + lane];
    int beg = row_ptr[node], end = row_ptr[node + 1];
    int i = beg;
    for (; i + 3 < end; i += 4){
        unsigned p0 = pack[i], p1 = pack[i+1], p2 = pack[i+2], p3 = pack[i+3];
        int ci0 = (int)((p0 >> 22) & 127u) * 20 + (int)((p0 >> 17) & 31u);
        int ci1 = (int)((p1 >> 22) & 127u) * 20 + (int)((p1 >> 17) & 31u);
        int ci2 = (int)((p2 >> 22) & 127u) * 20 + (int)((p2 >> 17) & 31u);
        int ci3 = (int)((p3 >> 22) & 127u) * 20 + (int)((p3 >> 17) & 31u);
        float2 m0 = c2[ci0 * 64 + lane];
        float2 m1 = c2[ci1 * 64 + lane];
        float2 m2 = c2[ci2 * 64 + lane];
        float2 m3 = c2[ci3 * 64 + lane];
        acc.x += (m0.x + m1.x) + (m2.x + m3.x);
        acc.y += (m0.y + m1.y) + (m2.y + m3.y);
    }
    for (; i < end; i++){
        unsigned p = pack[i];
        int ci = (int)((p >> 22) & 127u) * 20 + (int)((p >> 17) & 31u);
        float2 m = c2[ci * 64 + lane];
        acc.x += m.x;
        acc.y += m.y;
    }
    unsigned short hx, lx, hy, ly;
    bsplit(acc.x, hx, lx); bsplit(acc.y, hy, ly);
    *(ushort2*)(h0h + (size_t)node * NHID + lane * 2) = make_ushort2(hx, hy);
    *(ushort2*)(h0l + (size_t)node * NHID + lane * 2) = make_ushort2(lx, ly);
}

// ---- fused MLP: h2 = (relu(h0@W1))@W2 + BN stats; h0 arrives pre-split hi/lo ----
// Phase-1 staging is now pure 16B copies (no bsplit). Values bit-identical to before.

__global__ __launch_bounds__(256) void k_mlp(const unsigned short* __restrict__ h0h,
                                             const unsigned short* __restrict__ h0l,
                                             const unsigned short* __restrict__ W1th,
                                             const unsigned short* __restrict__ W1tl,
                                             const unsigned short* __restrict__ W2th,
                                             const unsigned short* __restrict__ W2tl,
                                             float* __restrict__ out,
                                             float* __restrict__ stats_l){
    __shared__ unsigned short Ah[128][40], Al[128][40];   // A chunk, then t chunk
    __shared__ unsigned short Bh[128][40], Bl[128][40];   // W^T chunk [col][k]
    const int tid = threadIdx.x;
    const int w = tid >> 6;
    const int l = tid & 63;
    const int lr = l & 15;
    const int lk = l >> 4;
    const int row0 = blockIdx.x * 128;

    f32x4 acc1[2][8], acc2[2][8];
    #pragma unroll
    for (int m = 0; m < 2; m++)
        #pragma unroll
        for (int n = 0; n < 8; n++){ acc1[m][n] = (f32x4)(0.f); acc2[m][n] = (f32x4)(0.f); }

    // ---- phase 1: acc1 = h0 @ W1 (staging = direct hi/lo copies) ----
    for (int kc = 0; kc < 4; kc++){
        __syncthreads();
        #pragma unroll
        for (int q = 0; q < 2; q++){
            int f = tid + 256 * q;                  // 0..511
            int r = f >> 2, kq = f & 3;
            int gr = row0 + r;
            uint4 vh = make_uint4(0u, 0u, 0u, 0u), vl = make_uint4(0u, 0u, 0u, 0u);
            if (gr < N_NODES){
                size_t gi = (size_t)gr * NHID + kc * 32 + kq * 8;
                vh = *(const uint4*)(h0h + gi);
                vl = *(const uint4*)(h0l + gi);
            }
            *(uint4*)&Ah[r][kq * 8] = vh;
            *(uint4*)&Al[r][kq * 8] = vl;
        }
        #pragma unroll
        for (int q = 0; q < 2; q++){
            int f = tid + 256 * q;
            int c = f >> 2, kq = f & 3;
            size_t gi = (size_t)c * 128 + kc * 32 + kq * 8;
            *(uint4*)&Bh[c][kq * 8] = *(const uint4*)(W1th + gi);
            *(uint4*)&Bl[c][kq * 8] = *(const uint4*)(W1tl + gi);
        }
        __syncthreads();
        short8v pah[2], pal[2];
        #pragma unroll
        for (int m = 0; m < 2; m++){
            pah[m] = *(const short8v*)&Ah[w * 32 + m * 16 + lr][lk * 8];
            pal[m] = *(const short8v*)&Al[w * 32 + m * 16 + lr][lk * 8];
        }
        #pragma unroll
        for (int n = 0; n < 8; n++){
            short8v pbh = *(const short8v*)&Bh[n * 16 + lr][lk * 8];
            short8v pbl = *(const short8v*)&Bl[n * 16 + lr][lk * 8];
            #pragma unroll
            for (int m = 0; m < 2; m++){
                acc1[m][n] = __builtin_amdgcn_mfma_f32_16x16x32_bf16(pal[m], pbh, acc1[m][n], 0, 0, 0);
                acc1[m][n] = __builtin_amdgcn_mfma_f32_16x16x32_bf16(pah[m], pbl, acc1[m][n], 0, 0, 0);
                acc1[m][n] = __builtin_amdgcn_mfma_f32_16x16x32_bf16(pah[m], pbh, acc1[m][n], 0, 0, 0);
            }
        }
    }

    // relu(t)
    #pragma unroll
    for (int m = 0; m < 2; m++)
        #pragma unroll
        for (int n = 0; n < 8; n++)
            #pragma unroll
            for (int j = 0; j < 4; j++) acc1[m][n][j] = fmaxf(acc1[m][n][j], 0.f);

    // ---- phase 2: acc2 = t @ W2, t chunk streamed through Ah/Al ----
    for (int kc = 0; kc < 4; kc++){
        __syncthreads();                               // prior LDS reads complete
        #pragma unroll
        for (int m = 0; m < 2; m++)
            #pragma unroll
            for (int j = 0; j < 4; j++){
                int trow = w * 32 + m * 16 + lk * 4 + j;
                #pragma unroll
                for (int nn = 0; nn < 2; nn++){
                    float v = acc1[m][kc * 2 + nn][j];
                    unsigned short h, lo;
                    bsplit(v, h, lo);
                    int tcol = nn * 16 + lr;
                    Ah[trow][tcol] = h;
                    Al[trow][tcol] = lo;
                }
            }
        #pragma unroll
        for (int q = 0; q < 2; q++){
            int f = tid + 256 * q;
            int c = f >> 2, kq = f & 3;
            size_t gi = (size_t)c * 128 + kc * 32 + kq * 8;
            *(uint4*)&Bh[c][kq * 8] = *(const uint4*)(W2th + gi);
            *(uint4*)&Bl[c][kq * 8] = *(const uint4*)(W2tl + gi);
        }
        __syncthreads();
        short8v pah[2], pal[2];
        #pragma unroll
        for (int m = 0; m < 2; m++){
            pah[m] = *(const short8v*)&Ah[w * 32 + m * 16 + lr][lk * 8];
            pal[m] = *(const short8v*)&Al[w * 32 + m * 16 + lr][lk * 8];
        }
        #pragma unroll
        for (int n = 0; n < 8; n++){
            short8v pbh = *(const short8v*)&Bh[n * 16 + lr][lk * 8];
            short8v pbl = *(const short8v*)&Bl[n * 16 + lr][lk * 8];
            #pragma unroll
            for (int m = 0; m < 2; m++){
                acc2[m][n] = __builtin_amdgcn_mfma_f32_16x16x32_bf16(pal[m], pbh, acc2[m][n], 0, 0, 0);
                acc2[m][n] = __builtin_amdgcn_mfma_f32_16x16x32_bf16(pah[m], pbl, acc2[m][n], 0, 0, 0);
                acc2[m][n] = __builtin_amdgcn_mfma_f32_16x16x32_bf16(pah[m], pbh, acc2[m][n], 0, 0, 0);
            }
        }
    }

    // store h2
    #pragma unroll
    for (int m = 0; m < 2; m++)
        #pragma unroll
        for (int j = 0; j < 4; j++){
            int gr = row0 + w * 32 + m * 16 + lk * 4 + j;
            if (gr < N_NODES){
                #pragma unroll
                for (int n = 0; n < 8; n++)
                    out[(size_t)gr * NHID + n * 16 + lr] = acc2[m][n][j];
            }
        }

    // BN stats (padded rows contribute exactly 0)
    __syncthreads();
    float* red  = (float*)&Ah[0][0];
    float* red2 = (float*)&Bh[0][0];
    #pragma unroll
    for (int n = 0; n < 8; n++){
        float s = 0.f, q = 0.f;
        #pragma unroll
        for (int m = 0; m < 2; m++)
            #pragma unroll
            for (int j = 0; j < 4; j++){ float v = acc2[m][n][j]; s += v; q += v * v; }
        red [(w * 4 + lk) * 128 + n * 16 + lr] = s;
        red2[(w * 4 + lk) * 128 + n * 16 + lr] = q;
    }
    __syncthreads();
    if (tid < 128){
        float s = 0.f, q = 0.f;
        #pragma unroll
        for (int r2 = 0; r2 < 16; r2++){
            s += red[r2 * 128 + tid];
            q += red2[r2 * 128 + tid];
        }
        atomicAdd(&stats_l[tid], s);
        atomicAdd(&stats_l[128 + tid], q);
    }
}

// -------- normalize + relu + residual; also emit bf16 shadow copy of x for gathers --------

__global__ void k_norm(const float4* __restrict__ h2, float4* __restrict__ x,
                       ushort4* __restrict__ xb,
                       const float* __restrict__ stats_l,
                       const float* __restrict__ gamma, const float* __restrict__ beta){
    int i = blockIdx.x * 256 + threadIdx.x;
    if (i >= N_NODES * 32) return;
    int g = (i & 31);
    float4 sv = ((const float4*)stats_l)[g];
    float4 qv = ((const float4*)(stats_l + 128))[g];
    float4 gm = ((const float4*)gamma)[g];
    float4 bt = ((const float4*)beta)[g];
    float4 ca, cb;
    {
        float mu, var;
        mu = sv.x * (1.f / N_NODES); var = qv.x * (1.f / N_NODES) - mu * mu;
        ca.x = gm.x * rsqrtf(var + BN_EPS); cb.x = bt.x - mu * ca.x;
        mu = sv.y * (1.f / N_NODES); var = qv.y * (1.f / N_NODES) - mu * mu;
        ca.y = gm.y * rsqrtf(var + BN_EPS); cb.y = bt.y - mu * ca.y;
        mu = sv.z * (1.f / N_NODES); var = qv.z * (1.f / N_NODES) - mu * mu;
        ca.z = gm.z * rsqrtf(var + BN_EPS); cb.z = bt.z - mu * ca.z;
        mu = sv.w * (1.f / N_NODES); var = qv.w * (1.f / N_NODES) - mu * mu;
        ca.w = gm.w * rsqrtf(var + BN_EPS); cb.w = bt.w - mu * ca.w;
    }
    float4 h = h2[i];
    float4 xv = x[i];
    float4 r;
    r.x = fmaxf(fmaf(h.x, ca.x, cb.x), 0.f) + xv.x;
    r.y = fmaxf(fmaf(h.y, ca.y, cb.y), 0.f) + xv.y;
    r.z = fmaxf(fmaf(h.z, ca.z, cb.z), 0.f) + xv.z;
    r.w = fmaxf(fmaf(h.w, ca.w, cb.w), 0.f) + xv.w;
    x[i] = r;
    xb[i] = make_ushort4(brne(r.x), brne(r.y), brne(r.z), brne(r.w));
}

// -------- pooling: chunked over nodes (batch sorted), per-run register accumulation --------

__global__ __launch_bounds__(256) void k_pool(const float* __restrict__ x,
                       const int* __restrict__ batch, float* __restrict__ gbuf){
    int c = threadIdx.x & 127;
    int half = threadIdx.x >> 7;
    int n0 = blockIdx.x * 128;
    int nend = min(n0 + 128, N_NODES);
    float acc = 0.f;
    int gcur = -1;
    for (int n = n0 + half; n < nend; n += 2){
        int g = batch[n];
        if (g != gcur){
            if (gcur >= 0) atomicAdd(&gbuf[gcur * NHID + c], acc);
            acc = 0.f; gcur = g;
        }
        acc += x[(size_t)n * NHID + c];
    }
    if (gcur >= 0) atomicAdd(&gbuf[gcur * NHID + c], acc);
}

// ---------------- output head ----------------

__global__ __launch_bounds__(128) void k_head1(const float* __restrict__ gbuf,
                                               const float* __restrict__ w1,
                                               const float* __restrict__ b1,
                                               float* __restrict__ o1){
    __shared__ float gs[128];
    int i = blockIdx.x;
    int j = threadIdx.x;
    gs[j] = gbuf[i * NHID + j];
    __syncthreads();
    float acc = 0.f;
    #pragma unroll 8
    for (int k = 0; k < 128; k++)
        acc = fmaf(gs[k], w1[k * NHID + j], acc);
    o1[i * NHID + j] = acc + b1[j];
}

__global__ __launch_bounds__(128) void k_head2(const float* __restrict__ o1,
                                               const float* __restrict__ gamma,
                                               const float* __restrict__ beta,
                                               const float* __restrict__ w2,
                                               const float* __restrict__ b2,
                                               float* __restrict__ out){
    __shared__ float s_o1[128][129];
    __shared__ float sa[128], sb[128];
    int t = threadIdx.x;
    float s = 0.f, q = 0.f;
    for (int r = 0; r < 128; r++){
        float v = o1[r * NHID + t];
        s_o1[r][t] = v;
        s += v; q += v * v;
    }
    float mu = s * (1.f / 128.f);
    float rs = rsqrtf(q * (1.f / 128.f) - mu * mu + BN_EPS);
    float a = gamma[t] * rs;
    sa[t] = a;
    sb[t] = beta[t] - mu * a;
    __syncthreads();
    float a2 = 0.f;
    #pragma unroll 8
    for (int j = 0; j < 128; j++){
        float v = fmaf(s_o1[t][j], sa[j], sb[j]);
        a2 += fmaxf(v, 0.f) * w2[j];
    }
    out[t] = a2 + b2[0];
}

// ---------------- launch ----------------

extern "C" void kernel_launch(void* const* d_in, const int* in_sizes, int n_in,
                              void* d_out, int out_size, void* d_ws, size_t ws_size,
                              hipStream_t stream){
    const int*   x_idx    = (const int*)d_in[0];
    const int*   eidx     = (const int*)d_in[1];
    const int*   eattr    = (const int*)d_in[2];
    const int*   batch    = (const int*)d_in[3];
    const float* node_emb = (const float*)d_in[4];
    const float* edge_emb = (const float*)d_in[5];
    const float* conv_w1  = (const float*)d_in[6];
    const float* conv_w2  = (const float*)d_in[7];
    const float* bn_gamma = (const float*)d_in[8];
    const float* bn_beta  = (const float*)d_in[9];
    const float* out_w1   = (const float*)d_in[10];
    const float* out_b1   = (const float*)d_in[11];
    const float* out_bng  = (const float*)d_in[12];
    const float* out_bnb  = (const float*)d_in[13];
    const float* out_w2   = (const float*)d_in[14];
    const float* out_b2   = (const float*)d_in[15];
    float* out = (float*)d_out;

    char* base = (char*)d_ws;
    size_t off = 0;
    auto alloc = [&](size_t bytes) -> char* {
        char* r = base + off;
        off = (off + bytes + 255) & ~(size_t)255;
        return r;
    };
    float*          xbuf    = (float*)alloc((size_t)N_NODES * NHID * 4);   // 51.2 MB
    float*          h0buf   = (float*)alloc((size_t)N_NODES * NHID * 4);   // 51.2 MB (h2; tmp aliased)
    unsigned short* h0h     = (unsigned short*)alloc((size_t)N_NODES * NHID * 2); // 25.6 MB
    unsigned short* h0l     = (unsigned short*)alloc((size_t)N_NODES * NHID * 2); // 25.6 MB
    unsigned short* xbf     = (unsigned short*)alloc((size_t)N_NODES * NHID * 2); // 25.6 MB
    int*            row_ptr = (int*)alloc((size_t)(N_NODES + 1) * 4);
    int*            cursor  = (int*)alloc((size_t)N_NODES * 4);
    int*            counts  = (int*)alloc((size_t)N_NODES * 4);
    int*            partial = (int*)alloc(512 * 4);
    int*            bcur    = (int*)alloc((size_t)FILL_NB * 4);
    unsigned*       pack    = (unsigned*)alloc((size_t)N_EDGES * 4);       // 6.4 MB
    float*          combo   = (float*)alloc((size_t)2000 * NHID * 4);      // 1.0 MB
    unsigned short* wth     = (unsigned short*)alloc((size_t)8 * 16384 * 2); // 256 KB
    unsigned short* wtl     = (unsigned short*)alloc((size_t)8 * 16384 * 2); // 256 KB
    float*          stats   = (float*)alloc(NLAYER * 256 * 4);
    float*          gbuf    = (float*)alloc((size_t)N_GRAPHS * NHID * 4);
    float*          o1buf   = (float*)alloc((size_t)N_GRAPHS * NHID * 4);
    uint2*          tmp     = (uint2*)h0buf;   // 12.8 MB alias: CSR-build lifetime only,
                                               // h0buf first written later (k_mlp)
    (void)ws_size; (void)in_sizes; (void)n_in; (void)out_size;

    hipMemsetAsync(counts, 0, (size_t)N_NODES * 4, stream);
    hipMemsetAsync(stats, 0, NLAYER * 256 * 4, stream);
    hipMemsetAsync(gbuf, 0, (size_t)N_GRAPHS * NHID * 4, stream);

    // CSR build (edges grouped by dst): hist -> scan -> two-phase bucketed fill
    k_hist<<<N_EDGES / 256, 256, 0, stream>>>(eidx + N_EDGES, counts);
    k_scan_partial<<<SCAN_NB, 256, 0, stream>>>(counts, partial);
    k_scan_top<<<1, 128, 0, stream>>>(partial, SCAN_NB, row_ptr);
    k_scan_final<<<SCAN_NB, 256, 0, stream>>>(counts, partial, row_ptr);
    hipMemcpyAsync(cursor, row_ptr, (size_t)N_NODES * 4, hipMemcpyDeviceToDevice, stream);
    k_binit<<<(FILL_NB + 255) / 256, 256, 0, stream>>>(row_ptr, bcur);
    k_fillA<<<(N_EDGES + FILL_CHUNK - 1) / FILL_CHUNK, 256, 0, stream>>>(
        eidx, eattr, x_idx, bcur, tmp);
    k_fillB<<<FILL_NB, 256, 0, stream>>>(tmp, row_ptr, cursor, pack);

    // per-call precomputes
    k_combo<<<(2000 * NHID) / 256, 256, 0, stream>>>(node_emb, edge_emb, combo);
    k_wsplit<<<131072 / 256, 256, 0, stream>>>(conv_w1, conv_w2, wth, wtl);
    k_initx<<<(N_NODES * 32) / 256, 256, 0, stream>>>(x_idx, node_emb, (float4*)xbuf);

    const int gemm_grid = (N_NODES + 127) / 128;     // 782
    for (int l = 0; l < NLAYER; l++){
        if (l == 0){
            k_agg0<<<(N_NODES * 64) / 256, 256, 0, stream>>>(
                xbuf, row_ptr, pack, combo, h0h, h0l);
        } else {
            k_agg<<<(N_NODES * 64) / 256, 256, 0, stream>>>(
                xbuf, (const ushort2*)xbf, row_ptr, pack,
                edge_emb + (size_t)l * 20 * NHID, h0h, h0l);
        }
        // h2 = relu(h0@W1)@W2 fused + BN stats
        k_mlp<<<gemm_grid, 256, 0, stream>>>(
            h0h, h0l,
            wth + (size_t)l * 16384, wtl + (size_t)l * 16384,
            wth + (size_t)(4 + l) * 16384, wtl + (size_t)(4 + l) * 16384,
            h0buf, stats + l * 256);
        k_norm<<<(N_NODES * 32) / 256, 256, 0, stream>>>(
            (const float4*)h0buf, (float4*)xbuf, (ushort4*)xbf, stats + l * 256,
            bn_gamma + l * NHID, bn_beta + l * NHID);
    }

    k_pool<<<(N_NODES + 127) / 128, 256, 0, stream>>>(xbuf, batch, gbuf);
    k_head1<<<N_GRAPHS, 128, 0, stream>>>(gbuf, out_w1, out_b1, o1buf);
    k_head2<<<1, 128, 0, stream>>>(o1buf, out_bng, out_bnb, out_w2, out_b2, out);
}